// Round 2
// baseline (2640.385 us; speedup 1.0000x reference)
//
#include <hip/hip_runtime.h>
#include <hip/hip_bf16.h>
#include <math.h>

// ---------------------------------------------------------------------------
// Bidirectional Mamba (bimamba v2), B=2, L=2048, D_MODEL=1024, D_INNER=2048,
// D_STATE=16, DT_RANK=64, D_CONV=4.
//
// Pipeline (all fp32, activations laid out [feature][n], n = b*L + t):
//   K1  gemm  : xz[4096][4096]      = in_proj_w @ hidden^T
//   K2  conv  : xc_f/xc_b[2048][4096] = silu(causal dwconv(x)) in scan order
//   K3  gemm  : x_dbl[96][4096]     = x_proj_w @ xc   (split-K=8, atomic)
//   K4  gemm  : delta[2048][4096]   = softplus(dt_proj_w @ dt_r + bias)
//               (forward delta overwrites the dead x-half of xz)
//   K5  scan  : YG[2048][4096]     += gated scan output (fwd natural order,
//               bwd at reversed positions; atomicAdd, pre-zeroed)
//   K6  gemm  : out[n][1024]        = out_proj_w @ YG, transposed store
//
// Workspace budget: 51,118,080 floats = 195.0 MiB  (was 271.6 MB -> faulted,
// consistent with a 256 MiB ws_size cap).
// ---------------------------------------------------------------------------

#define L_SEQ  2048
#define B_SZ   2
#define DM     1024
#define DI     2048
#define NST    16
#define RTOT   96
#define DTR    64
#define NTOT   (B_SZ * L_SEQ)   // 4096
#define ETOT   (2 * DI)         // 4096

// workspace offsets (in floats)
#define OFF_XZ   ((size_t)0)                        // [4096][4096]; rows 0..2047 become DLF
#define OFF_XCF  (OFF_XZ  + (size_t)ETOT * NTOT)    // [2048][4096]
#define OFF_XCB  (OFF_XCF + (size_t)DI   * NTOT)
#define OFF_DLB  (OFF_XCB + (size_t)DI   * NTOT)    // [2048][4096] delta bwd
#define OFF_XDF  (OFF_DLB + (size_t)DI   * NTOT)    // [96][4096]
#define OFF_XDB  (OFF_XDF + (size_t)RTOT * NTOT)
#define OFF_YG   (OFF_XDB + (size_t)RTOT * NTOT)    // [2048][4096] combined gated y
#define WS_FLOATS (OFF_YG + (size_t)DI * NTOT)      // 51,118,080 floats

__device__ __forceinline__ float silu_f(float x) {
    return x / (1.f + __expf(-x));
}

// ---------------------------------------------------------------------------
// Generic 128x128 fp32 GEMM, 256 threads, 8x8 per thread, KT=16.
// A is [M][K] row-major.
// B_NK:  B is [N][K] (k contiguous) else [K][N] (n contiguous).
// TRANS_STORE: C stored [N][M].  SOFTPLUS: C = softplus(acc + bias[m]).
// ATOMIC: split-K over gridDim.z, atomicAdd stores (C must be pre-zeroed).
// ---------------------------------------------------------------------------
template<bool B_NK, bool TRANS_STORE, bool SOFTPLUS, bool ATOMIC>
__global__ __launch_bounds__(256)
void gemm_k(const float* __restrict__ A, const float* __restrict__ Bm,
            float* __restrict__ C,
            int M, int N, int K, int kbeg, int kend,
            const float* __restrict__ bias)
{
    __shared__ float As[16][132];
    __shared__ float Bs[16][132];
    const int tid = threadIdx.x;
    const int n0 = blockIdx.x * 128;
    const int m0 = blockIdx.y * 128;
    if constexpr (ATOMIC) {
        int ksz = (kend - kbeg) / (int)gridDim.z;
        kbeg += blockIdx.z * ksz;
        kend = kbeg + ksz;
    }
    const int tx = tid & 15, ty = tid >> 4;

    float acc[8][8];
#pragma unroll
    for (int i = 0; i < 8; ++i)
#pragma unroll
        for (int j = 0; j < 8; ++j) acc[i][j] = 0.f;

    for (int k0 = kbeg; k0 < kend; k0 += 16) {
        // stage A tile transposed: As[k][m]
#pragma unroll
        for (int it = 0; it < 2; ++it) {
            int i = tid + it * 256;          // 0..511 float4 slots
            int m = i >> 2, kq = i & 3;
            float4 v = make_float4(0.f, 0.f, 0.f, 0.f);
            int gm = m0 + m;
            if (gm < M) v = *(const float4*)(A + (size_t)gm * K + (k0 + kq * 4));
            As[kq * 4 + 0][m] = v.x; As[kq * 4 + 1][m] = v.y;
            As[kq * 4 + 2][m] = v.z; As[kq * 4 + 3][m] = v.w;
        }
        if constexpr (B_NK) {
#pragma unroll
            for (int it = 0; it < 2; ++it) {
                int i = tid + it * 256;
                int n = i >> 2, kq = i & 3;
                float4 v = *(const float4*)(Bm + (size_t)(n0 + n) * K + (k0 + kq * 4));
                Bs[kq * 4 + 0][n] = v.x; Bs[kq * 4 + 1][n] = v.y;
                Bs[kq * 4 + 2][n] = v.z; Bs[kq * 4 + 3][n] = v.w;
            }
        } else {
#pragma unroll
            for (int it = 0; it < 2; ++it) {
                int i = tid + it * 256;
                int k = i >> 5, nq = i & 31;
                float4 v = *(const float4*)(Bm + (size_t)(k0 + k) * N + n0 + nq * 4);
                *(float4*)&Bs[k][nq * 4] = v;
            }
        }
        __syncthreads();
#pragma unroll
        for (int kk = 0; kk < 16; ++kk) {
            float av[8], bv[8];
            *(float4*)&av[0] = *(const float4*)&As[kk][ty * 8];
            *(float4*)&av[4] = *(const float4*)&As[kk][ty * 8 + 4];
            *(float4*)&bv[0] = *(const float4*)&Bs[kk][tx * 8];
            *(float4*)&bv[4] = *(const float4*)&Bs[kk][tx * 8 + 4];
#pragma unroll
            for (int i = 0; i < 8; ++i)
#pragma unroll
                for (int j = 0; j < 8; ++j)
                    acc[i][j] = fmaf(av[i], bv[j], acc[i][j]);
        }
        __syncthreads();
    }

    if constexpr (TRANS_STORE) {
#pragma unroll
        for (int j = 0; j < 8; ++j) {
            int gn = n0 + tx * 8 + j;
            float4 v0 = make_float4(acc[0][j], acc[1][j], acc[2][j], acc[3][j]);
            float4 v1 = make_float4(acc[4][j], acc[5][j], acc[6][j], acc[7][j]);
            *(float4*)(C + (size_t)gn * M + m0 + ty * 8)     = v0;
            *(float4*)(C + (size_t)gn * M + m0 + ty * 8 + 4) = v1;
        }
    } else {
#pragma unroll
        for (int i = 0; i < 8; ++i) {
            int gm = m0 + ty * 8 + i;
            if (gm < M) {
                float* cp = C + (size_t)gm * N + n0 + tx * 8;
                if constexpr (ATOMIC) {
#pragma unroll
                    for (int j = 0; j < 8; ++j) atomicAdd(cp + j, acc[i][j]);
                } else if constexpr (SOFTPLUS) {
                    float bvl = bias[gm];
                    float o[8];
#pragma unroll
                    for (int j = 0; j < 8; ++j) {
                        float x = acc[i][j] + bvl;
                        o[j] = (x > 20.f) ? x : log1pf(expf(x));
                    }
                    *(float4*)cp       = make_float4(o[0], o[1], o[2], o[3]);
                    *(float4*)(cp + 4) = make_float4(o[4], o[5], o[6], o[7]);
                } else {
                    *(float4*)cp       = make_float4(acc[i][0], acc[i][1], acc[i][2], acc[i][3]);
                    *(float4*)(cp + 4) = make_float4(acc[i][4], acc[i][5], acc[i][6], acc[i][7]);
                }
            }
        }
    }
}

// ---------------------------------------------------------------------------
// Causal depthwise conv (K=4) + silu, both directions, outputs in scan order.
// Tile: 64 d-rows x 64 l-cols, halo 3 each side.
// ---------------------------------------------------------------------------
__global__ __launch_bounds__(256)
void conv_k(const float* __restrict__ xz,
            const float* __restrict__ wf, const float* __restrict__ bf,
            const float* __restrict__ wb, const float* __restrict__ bb,
            float* __restrict__ xcf, float* __restrict__ xcb)
{
    __shared__ float xs[64][72];
    const int tid = threadIdx.x;
    const int d0 = blockIdx.x * 64;
    const int n0 = blockIdx.y * 64;
    const int b  = n0 >> 11;            // n0 / L_SEQ
    const int l0 = n0 & (L_SEQ - 1);
    const size_t bbase = (size_t)b << 11;   // b * L_SEQ

    for (int i = tid; i < 64 * 70; i += 256) {
        int r = i / 70, c = i % 70;
        int l = l0 - 3 + c;
        float v = 0.f;
        if (l >= 0 && l < L_SEQ) v = xz[(size_t)(d0 + r) * NTOT + bbase + l];
        xs[r][c] = v;
    }
    __syncthreads();

    const int c   = tid & 63;
    const int r00 = tid >> 6;           // 0..3
    const int l   = l0 + c;
    for (int rr = 0; rr < 64; rr += 4) {
        int r = rr + r00;
        int d = d0 + r;
        float w0 = wf[d * 4 + 0], w1 = wf[d * 4 + 1];
        float w2 = wf[d * 4 + 2], w3 = wf[d * 4 + 3];
        // forward: out[l] = sum_k w[k] * x[l-3+k]
        float xf = bf[d] + w0 * xs[r][c] + w1 * xs[r][c + 1]
                         + w2 * xs[r][c + 2] + w3 * xs[r][c + 3];
        xcf[(size_t)d * NTOT + bbase + l] = silu_f(xf);
        // backward (conv on reversed seq): out_rev[t] = sum_j wb[3-j]*x[l+j], t=L-1-l
        float v0 = wb[d * 4 + 0], v1 = wb[d * 4 + 1];
        float v2 = wb[d * 4 + 2], v3 = wb[d * 4 + 3];
        float xb = bb[d] + v3 * xs[r][c + 3] + v2 * xs[r][c + 4]
                         + v1 * xs[r][c + 5] + v0 * xs[r][c + 6];
        xcb[(size_t)d * NTOT + bbase + (L_SEQ - 1 - l)] = silu_f(xb);
    }
}

// ---------------------------------------------------------------------------
// Selective scan, one thread per (b, d, branch). 16-state in registers,
// t chunked by 4 with float4 loads; gating by silu(z) fused.
// Both branches atomicAdd into the shared YG buffer (pre-zeroed); the
// backward branch adds at reversed sequence positions.
// ---------------------------------------------------------------------------
__global__ __launch_bounds__(64)
void scan_k(const float* __restrict__ xz,
            const float* __restrict__ xcf, const float* __restrict__ xcb,
            const float* __restrict__ xdf, const float* __restrict__ xdb,
            const float* __restrict__ dlf, const float* __restrict__ dlb,
            float* __restrict__ yg,
            const float* __restrict__ Alog_f, const float* __restrict__ Alog_b,
            const float* __restrict__ Df, const float* __restrict__ Db)
{
    const int d  = blockIdx.x * 64 + threadIdx.x;
    const int b  = blockIdx.y;
    const int br = blockIdx.z;

    const float* xc   = br ? xcb : xcf;
    const float* xdbl = br ? xdb : xdf;
    const float* dl   = br ? dlb : dlf;
    const float* Alog = br ? Alog_b : Alog_f;
    const float* Dv   = br ? Db : Df;

    float Arow[NST], h[NST];
#pragma unroll
    for (int n = 0; n < NST; ++n) {
        Arow[n] = -__expf(Alog[d * NST + n]);
        h[n] = 0.f;
    }
    const float Dp = Dv[d];

    const size_t base = (size_t)b * L_SEQ;
    const float* drow = dl + (size_t)d * NTOT + base;
    const float* urow = xc + (size_t)d * NTOT + base;
    const float* zrow = xz + (size_t)(DI + d) * NTOT + base;
    float*       yrow = yg + (size_t)d * NTOT + base;
    const float* bc   = xdbl + (size_t)DTR * NTOT + base;  // B rows then C rows

    for (int t0 = 0; t0 < L_SEQ; t0 += 4) {
        float4 d4 = *(const float4*)(drow + t0);
        float4 u4 = *(const float4*)(urow + t0);
        float dlt[4] = { d4.x, d4.y, d4.z, d4.w };
        float du[4]  = { d4.x * u4.x, d4.y * u4.y, d4.z * u4.z, d4.w * u4.w };
        float y0 = 0.f, y1 = 0.f, y2 = 0.f, y3 = 0.f;
#pragma unroll
        for (int n = 0; n < NST; ++n) {
            float4 Bn = *(const float4*)(bc + (size_t)n * NTOT + t0);
            float4 Cn = *(const float4*)(bc + (size_t)(NST + n) * NTOT + t0);
            float hn = h[n];
            float An = Arow[n];
            hn = hn * __expf(dlt[0] * An) + du[0] * Bn.x;  y0 = fmaf(hn, Cn.x, y0);
            hn = hn * __expf(dlt[1] * An) + du[1] * Bn.y;  y1 = fmaf(hn, Cn.y, y1);
            hn = hn * __expf(dlt[2] * An) + du[2] * Bn.z;  y2 = fmaf(hn, Cn.z, y2);
            hn = hn * __expf(dlt[3] * An) + du[3] * Bn.w;  y3 = fmaf(hn, Cn.w, y3);
            h[n] = hn;
        }
        float zv[4];
        if (br == 0) {
            float4 z4 = *(const float4*)(zrow + t0);
            zv[0] = z4.x; zv[1] = z4.y; zv[2] = z4.z; zv[3] = z4.w;
        } else {
            float4 z4 = *(const float4*)(zrow + (L_SEQ - 4 - t0));
            zv[0] = z4.w; zv[1] = z4.z; zv[2] = z4.y; zv[3] = z4.x;
        }
        y0 = (y0 + u4.x * Dp) * silu_f(zv[0]);
        y1 = (y1 + u4.y * Dp) * silu_f(zv[1]);
        y2 = (y2 + u4.z * Dp) * silu_f(zv[2]);
        y3 = (y3 + u4.w * Dp) * silu_f(zv[3]);
        if (br == 0) {
            atomicAdd(yrow + t0 + 0, y0);
            atomicAdd(yrow + t0 + 1, y1);
            atomicAdd(yrow + t0 + 2, y2);
            atomicAdd(yrow + t0 + 3, y3);
        } else {
            atomicAdd(yrow + (L_SEQ - 1 - t0), y0);
            atomicAdd(yrow + (L_SEQ - 2 - t0), y1);
            atomicAdd(yrow + (L_SEQ - 3 - t0), y2);
            atomicAdd(yrow + (L_SEQ - 4 - t0), y3);
        }
    }
}

extern "C" void kernel_launch(void* const* d_in, const int* in_sizes, int n_in,
                              void* d_out, int out_size, void* d_ws, size_t ws_size,
                              hipStream_t stream)
{
    const float* hid     = (const float*)d_in[0];
    const float* inw     = (const float*)d_in[1];
    const float* convw   = (const float*)d_in[2];
    const float* convb   = (const float*)d_in[3];
    const float* xpw     = (const float*)d_in[4];
    const float* dtw     = (const float*)d_in[5];
    const float* dtb     = (const float*)d_in[6];
    const float* Alog    = (const float*)d_in[7];
    const float* Dv      = (const float*)d_in[8];
    const float* convw_b = (const float*)d_in[9];
    const float* convb_b = (const float*)d_in[10];
    const float* xpw_b   = (const float*)d_in[11];
    const float* dtw_b   = (const float*)d_in[12];
    const float* dtb_b   = (const float*)d_in[13];
    const float* Alog_b  = (const float*)d_in[14];
    const float* Dv_b    = (const float*)d_in[15];
    const float* outw    = (const float*)d_in[16];
    float* out = (float*)d_out;
    float* ws  = (float*)d_ws;

    // diagnostic guard: undersized workspace -> clean absmax failure, not a fault
    if (ws_size < WS_FLOATS * sizeof(float)) return;

    float* XZ  = ws + OFF_XZ;
    float* XCF = ws + OFF_XCF;
    float* XCB = ws + OFF_XCB;
    float* DLB = ws + OFF_DLB;
    float* XDF = ws + OFF_XDF;
    float* XDB = ws + OFF_XDB;
    float* YG  = ws + OFF_YG;
    float* DLF = XZ;   // overwrites dead x-half of xz (rows 0..DI-1)

    // zero atomic-accumulation targets: XDF+XDB+YG are contiguous
    hipMemsetAsync(XDF, 0, (2 * (size_t)RTOT + (size_t)DI) * NTOT * sizeof(float), stream);

    dim3 blk(256);
    // K1: xz = in_proj_w @ hidden^T   (B as [n][k])
    gemm_k<true, false, false, false><<<dim3(32, 32, 1), blk, 0, stream>>>(
        inw, hid, XZ, ETOT, NTOT, DM, 0, DM, nullptr);
    // K2: conv + silu both directions
    conv_k<<<dim3(32, 64, 1), blk, 0, stream>>>(XZ, convw, convb, convw_b, convb_b, XCF, XCB);
    // K3: x_dbl = x_proj_w @ xc   (B as [k][n], split-K=8, atomic)
    gemm_k<false, false, false, true><<<dim3(32, 1, 8), blk, 0, stream>>>(
        xpw, XCF, XDF, RTOT, NTOT, DI, 0, DI, nullptr);
    gemm_k<false, false, false, true><<<dim3(32, 1, 8), blk, 0, stream>>>(
        xpw_b, XCB, XDB, RTOT, NTOT, DI, 0, DI, nullptr);
    // K4: delta = softplus(dt_proj_w @ dt_r + bias); fwd result into dead x-half of XZ
    gemm_k<false, false, true, false><<<dim3(32, 16, 1), blk, 0, stream>>>(
        dtw, XDF, DLF, DI, NTOT, DTR, 0, DTR, dtb);
    gemm_k<false, false, true, false><<<dim3(32, 16, 1), blk, 0, stream>>>(
        dtw_b, XDB, DLB, DI, NTOT, DTR, 0, DTR, dtb_b);
    // K5: selective scan + gating, both branches accumulate into YG
    scan_k<<<dim3(32, B_SZ, 2), dim3(64), 0, stream>>>(
        XZ, XCF, XCB, XDF, XDB, DLF, DLB, YG, Alog, Alog_b, Dv, Dv_b);
    // K6: out = out_proj_w @ YG, stored [n][m]
    gemm_k<false, true, false, false><<<dim3(32, 8, 1), blk, 0, stream>>>(
        outw, YG, out, DM, NTOT, DI, 0, DI, nullptr);

    (void)in_sizes; (void)n_in; (void)out_size;
}

// Round 3
// 2176.177 us; speedup vs baseline: 1.2133x; 1.2133x over previous
//
#include <hip/hip_runtime.h>
#include <hip/hip_bf16.h>
#include <math.h>

// ---------------------------------------------------------------------------
// Bidirectional Mamba (bimamba v2), B=2, L=2048, D_MODEL=1024, D_INNER=2048,
// D_STATE=16, DT_RANK=64, D_CONV=4.
//
// Pipeline (all fp32, activations laid out [feature][n], n = b*L + t):
//   K1  gemm  : xz[4096][4096]      = in_proj_w @ hidden^T
//   K2  conv  : xc_f/xc_b[2048][4096] = silu(causal dwconv(x)) in scan order
//   K3  gemm  : x_dbl[96][4096]     = x_proj_w @ xc   (split-K=8, atomic)
//   K4  gemm  : delta[2048][4096]   = softplus(dt_proj_w @ dt_r + bias)
//               (forward delta overwrites the dead x-half of xz)
//   K5  scan  : 3-phase chunked parallel scan (32 chunks of 64 steps):
//               part1: local scan per chunk (h0=0) -> hl; S = sum(delta)
//               part2: combine: Hin[c+1] = exp(S_c*A)*Hin[c] + hl_c
//               part3: rerun chunk from Hin, gate, atomicAdd into YG
//   K6  gemm  : out[n][1024]        = out_proj_w @ YG, transposed store
//
// Workspace: 59,768,832 floats = 228.0 MiB (fits the ~256 MiB cap).
// ---------------------------------------------------------------------------

#define L_SEQ  2048
#define B_SZ   2
#define DM     1024
#define DI     2048
#define NST    16
#define RTOT   96
#define DTR    64
#define NTOT   (B_SZ * L_SEQ)   // 4096
#define ETOT   (2 * DI)         // 4096
#define NCH    32               // scan chunks
#define CHT    (L_SEQ / NCH)    // 64 steps per chunk

// workspace offsets (in floats)
#define OFF_XZ   ((size_t)0)                        // [4096][4096]; rows 0..2047 become DLF
#define OFF_XCF  (OFF_XZ  + (size_t)ETOT * NTOT)    // [2048][4096]
#define OFF_XCB  (OFF_XCF + (size_t)DI   * NTOT)
#define OFF_DLB  (OFF_XCB + (size_t)DI   * NTOT)    // [2048][4096] delta bwd
#define OFF_XDF  (OFF_DLB + (size_t)DI   * NTOT)    // [96][4096]
#define OFF_XDB  (OFF_XDF + (size_t)RTOT * NTOT)
#define OFF_YG   (OFF_XDB + (size_t)RTOT * NTOT)    // [2048][4096] combined gated y
#define OFF_SS   (OFF_YG  + (size_t)DI   * NTOT)    // [4][NCH][DI] sum(delta)
#define OFF_HL   (OFF_SS  + (size_t)4 * NCH * DI)   // [4][NCH][NST][DI] local h
#define OFF_HIN  (OFF_HL  + (size_t)4 * NCH * NST * DI)
#define WS_FLOATS (OFF_HIN + (size_t)4 * NCH * NST * DI)   // 59,768,832

__device__ __forceinline__ float silu_f(float x) {
    return x / (1.f + __expf(-x));
}

// ---------------------------------------------------------------------------
// Generic 128x128 fp32 GEMM, 256 threads, 8x8 per thread, KT=16.
// A is [M][K] row-major.
// B_NK:  B is [N][K] (k contiguous) else [K][N] (n contiguous).
// TRANS_STORE: C stored [N][M].  SOFTPLUS: C = softplus(acc + bias[m]).
// ATOMIC: split-K over gridDim.z, atomicAdd stores (C must be pre-zeroed).
// ---------------------------------------------------------------------------
template<bool B_NK, bool TRANS_STORE, bool SOFTPLUS, bool ATOMIC>
__global__ __launch_bounds__(256)
void gemm_k(const float* __restrict__ A, const float* __restrict__ Bm,
            float* __restrict__ C,
            int M, int N, int K, int kbeg, int kend,
            const float* __restrict__ bias)
{
    __shared__ float As[16][132];
    __shared__ float Bs[16][132];
    const int tid = threadIdx.x;
    const int n0 = blockIdx.x * 128;
    const int m0 = blockIdx.y * 128;
    if constexpr (ATOMIC) {
        int ksz = (kend - kbeg) / (int)gridDim.z;
        kbeg += blockIdx.z * ksz;
        kend = kbeg + ksz;
    }
    const int tx = tid & 15, ty = tid >> 4;

    float acc[8][8];
#pragma unroll
    for (int i = 0; i < 8; ++i)
#pragma unroll
        for (int j = 0; j < 8; ++j) acc[i][j] = 0.f;

    for (int k0 = kbeg; k0 < kend; k0 += 16) {
        // stage A tile transposed: As[k][m]
#pragma unroll
        for (int it = 0; it < 2; ++it) {
            int i = tid + it * 256;          // 0..511 float4 slots
            int m = i >> 2, kq = i & 3;
            float4 v = make_float4(0.f, 0.f, 0.f, 0.f);
            int gm = m0 + m;
            if (gm < M) v = *(const float4*)(A + (size_t)gm * K + (k0 + kq * 4));
            As[kq * 4 + 0][m] = v.x; As[kq * 4 + 1][m] = v.y;
            As[kq * 4 + 2][m] = v.z; As[kq * 4 + 3][m] = v.w;
        }
        if constexpr (B_NK) {
#pragma unroll
            for (int it = 0; it < 2; ++it) {
                int i = tid + it * 256;
                int n = i >> 2, kq = i & 3;
                float4 v = *(const float4*)(Bm + (size_t)(n0 + n) * K + (k0 + kq * 4));
                Bs[kq * 4 + 0][n] = v.x; Bs[kq * 4 + 1][n] = v.y;
                Bs[kq * 4 + 2][n] = v.z; Bs[kq * 4 + 3][n] = v.w;
            }
        } else {
#pragma unroll
            for (int it = 0; it < 2; ++it) {
                int i = tid + it * 256;
                int k = i >> 5, nq = i & 31;
                float4 v = *(const float4*)(Bm + (size_t)(k0 + k) * N + n0 + nq * 4);
                *(float4*)&Bs[k][nq * 4] = v;
            }
        }
        __syncthreads();
#pragma unroll
        for (int kk = 0; kk < 16; ++kk) {
            float av[8], bv[8];
            *(float4*)&av[0] = *(const float4*)&As[kk][ty * 8];
            *(float4*)&av[4] = *(const float4*)&As[kk][ty * 8 + 4];
            *(float4*)&bv[0] = *(const float4*)&Bs[kk][tx * 8];
            *(float4*)&bv[4] = *(const float4*)&Bs[kk][tx * 8 + 4];
#pragma unroll
            for (int i = 0; i < 8; ++i)
#pragma unroll
                for (int j = 0; j < 8; ++j)
                    acc[i][j] = fmaf(av[i], bv[j], acc[i][j]);
        }
        __syncthreads();
    }

    if constexpr (TRANS_STORE) {
#pragma unroll
        for (int j = 0; j < 8; ++j) {
            int gn = n0 + tx * 8 + j;
            float4 v0 = make_float4(acc[0][j], acc[1][j], acc[2][j], acc[3][j]);
            float4 v1 = make_float4(acc[4][j], acc[5][j], acc[6][j], acc[7][j]);
            *(float4*)(C + (size_t)gn * M + m0 + ty * 8)     = v0;
            *(float4*)(C + (size_t)gn * M + m0 + ty * 8 + 4) = v1;
        }
    } else {
#pragma unroll
        for (int i = 0; i < 8; ++i) {
            int gm = m0 + ty * 8 + i;
            if (gm < M) {
                float* cp = C + (size_t)gm * N + n0 + tx * 8;
                if constexpr (ATOMIC) {
#pragma unroll
                    for (int j = 0; j < 8; ++j) atomicAdd(cp + j, acc[i][j]);
                } else if constexpr (SOFTPLUS) {
                    float bvl = bias[gm];
                    float o[8];
#pragma unroll
                    for (int j = 0; j < 8; ++j) {
                        float x = acc[i][j] + bvl;
                        o[j] = (x > 20.f) ? x : log1pf(expf(x));
                    }
                    *(float4*)cp       = make_float4(o[0], o[1], o[2], o[3]);
                    *(float4*)(cp + 4) = make_float4(o[4], o[5], o[6], o[7]);
                } else {
                    *(float4*)cp       = make_float4(acc[i][0], acc[i][1], acc[i][2], acc[i][3]);
                    *(float4*)(cp + 4) = make_float4(acc[i][4], acc[i][5], acc[i][6], acc[i][7]);
                }
            }
        }
    }
}

// ---------------------------------------------------------------------------
// Causal depthwise conv (K=4) + silu, both directions, outputs in scan order.
// ---------------------------------------------------------------------------
__global__ __launch_bounds__(256)
void conv_k(const float* __restrict__ xz,
            const float* __restrict__ wf, const float* __restrict__ bf,
            const float* __restrict__ wb, const float* __restrict__ bb,
            float* __restrict__ xcf, float* __restrict__ xcb)
{
    __shared__ float xs[64][72];
    const int tid = threadIdx.x;
    const int d0 = blockIdx.x * 64;
    const int n0 = blockIdx.y * 64;
    const int b  = n0 >> 11;            // n0 / L_SEQ
    const int l0 = n0 & (L_SEQ - 1);
    const size_t bbase = (size_t)b << 11;   // b * L_SEQ

    for (int i = tid; i < 64 * 70; i += 256) {
        int r = i / 70, c = i % 70;
        int l = l0 - 3 + c;
        float v = 0.f;
        if (l >= 0 && l < L_SEQ) v = xz[(size_t)(d0 + r) * NTOT + bbase + l];
        xs[r][c] = v;
    }
    __syncthreads();

    const int c   = tid & 63;
    const int r00 = tid >> 6;           // 0..3
    const int l   = l0 + c;
    for (int rr = 0; rr < 64; rr += 4) {
        int r = rr + r00;
        int d = d0 + r;
        float w0 = wf[d * 4 + 0], w1 = wf[d * 4 + 1];
        float w2 = wf[d * 4 + 2], w3 = wf[d * 4 + 3];
        float xf = bf[d] + w0 * xs[r][c] + w1 * xs[r][c + 1]
                         + w2 * xs[r][c + 2] + w3 * xs[r][c + 3];
        xcf[(size_t)d * NTOT + bbase + l] = silu_f(xf);
        float v0 = wb[d * 4 + 0], v1 = wb[d * 4 + 1];
        float v2 = wb[d * 4 + 2], v3 = wb[d * 4 + 3];
        float xb = bb[d] + v3 * xs[r][c + 3] + v2 * xs[r][c + 4]
                         + v1 * xs[r][c + 5] + v0 * xs[r][c + 6];
        xcb[(size_t)d * NTOT + bbase + (L_SEQ - 1 - l)] = silu_f(xb);
    }
}

// ---------------------------------------------------------------------------
// Chunked selective scan, phase 1: per (d, chunk, b, br) compute the local
// scan hl (h0 = 0) and S = sum(delta) over the chunk (chunk decay =
// exp(S * A[n]) since prod(exp) = exp(sum)).
// ---------------------------------------------------------------------------
__global__ __launch_bounds__(256)
void scan_part1(const float* __restrict__ xcf, const float* __restrict__ xcb,
                const float* __restrict__ xdf, const float* __restrict__ xdb,
                const float* __restrict__ dlf, const float* __restrict__ dlb,
                const float* __restrict__ Alog_f, const float* __restrict__ Alog_b,
                float* __restrict__ SS, float* __restrict__ HL)
{
    const int d  = blockIdx.x * 256 + threadIdx.x;
    const int c  = blockIdx.y;
    const int bb = blockIdx.z;          // br*2 + b
    const int b  = bb & 1;
    const int br = bb >> 1;

    const float* xc   = br ? xcb : xcf;
    const float* xdbl = br ? xdb : xdf;
    const float* dl   = br ? dlb : dlf;
    const float* Alog = br ? Alog_b : Alog_f;

    float Arow[NST], h[NST];
#pragma unroll
    for (int n = 0; n < NST; ++n) {
        Arow[n] = -__expf(Alog[d * NST + n]);
        h[n] = 0.f;
    }
    float S = 0.f;

    const size_t base = (size_t)b * L_SEQ;
    const float* drow = dl + (size_t)d * NTOT + base;
    const float* urow = xc + (size_t)d * NTOT + base;
    const float* bcB  = xdbl + (size_t)DTR * NTOT + base;

    const int t0 = c * CHT;
    for (int t = t0; t < t0 + CHT; t += 4) {
        float4 d4 = *(const float4*)(drow + t);
        float4 u4 = *(const float4*)(urow + t);
        S += (d4.x + d4.y) + (d4.z + d4.w);
        float dlt[4] = { d4.x, d4.y, d4.z, d4.w };
        float du[4]  = { d4.x * u4.x, d4.y * u4.y, d4.z * u4.z, d4.w * u4.w };
#pragma unroll
        for (int n = 0; n < NST; ++n) {
            float4 Bn = *(const float4*)(bcB + (size_t)n * NTOT + t);
            float hn = h[n];
            float An = Arow[n];
            hn = hn * __expf(dlt[0] * An) + du[0] * Bn.x;
            hn = hn * __expf(dlt[1] * An) + du[1] * Bn.y;
            hn = hn * __expf(dlt[2] * An) + du[2] * Bn.z;
            hn = hn * __expf(dlt[3] * An) + du[3] * Bn.w;
            h[n] = hn;
        }
    }
    SS[((size_t)bb * NCH + c) * DI + d] = S;
#pragma unroll
    for (int n = 0; n < NST; ++n)
        HL[(((size_t)bb * NCH + c) * NST + n) * DI + d] = h[n];
}

// ---------------------------------------------------------------------------
// Phase 2: per (d, n, b, br) sequentially combine the 32 chunk summaries:
// Hin[c] = H;  H = exp(S_c * A) * H + hl_c.
// ---------------------------------------------------------------------------
__global__ __launch_bounds__(256)
void scan_part2(const float* __restrict__ SS, const float* __restrict__ HL,
                const float* __restrict__ Alog_f, const float* __restrict__ Alog_b,
                float* __restrict__ HIN)
{
    const int d  = blockIdx.x * 256 + threadIdx.x;
    const int n  = blockIdx.y;
    const int bb = blockIdx.z;
    const int br = bb >> 1;
    const float* Alog = br ? Alog_b : Alog_f;
    const float A = -__expf(Alog[d * NST + n]);

    float H = 0.f;
#pragma unroll
    for (int c = 0; c < NCH; ++c) {
        const size_t si = ((size_t)bb * NCH + c) * DI + d;
        const size_t hi = (((size_t)bb * NCH + c) * NST + n) * DI + d;
        HIN[hi] = H;
        H = __expf(SS[si] * A) * H + HL[hi];
    }
}

// ---------------------------------------------------------------------------
// Phase 3: rerun each chunk from its entry state Hin, compute y, add u*D,
// gate with silu(z), atomicAdd into the shared YG buffer (pre-zeroed).
// Backward branch writes at reversed sequence positions.
// ---------------------------------------------------------------------------
__global__ __launch_bounds__(256)
void scan_part3(const float* __restrict__ xz,
                const float* __restrict__ xcf, const float* __restrict__ xcb,
                const float* __restrict__ xdf, const float* __restrict__ xdb,
                const float* __restrict__ dlf, const float* __restrict__ dlb,
                const float* __restrict__ HIN, float* __restrict__ yg,
                const float* __restrict__ Alog_f, const float* __restrict__ Alog_b,
                const float* __restrict__ Df, const float* __restrict__ Db)
{
    const int d  = blockIdx.x * 256 + threadIdx.x;
    const int c  = blockIdx.y;
    const int bb = blockIdx.z;
    const int b  = bb & 1;
    const int br = bb >> 1;

    const float* xc   = br ? xcb : xcf;
    const float* xdbl = br ? xdb : xdf;
    const float* dl   = br ? dlb : dlf;
    const float* Alog = br ? Alog_b : Alog_f;
    const float* Dv   = br ? Db : Df;

    float Arow[NST], h[NST];
#pragma unroll
    for (int n = 0; n < NST; ++n) {
        Arow[n] = -__expf(Alog[d * NST + n]);
        h[n] = HIN[(((size_t)bb * NCH + c) * NST + n) * DI + d];
    }
    const float Dp = Dv[d];

    const size_t base = (size_t)b * L_SEQ;
    const float* drow = dl + (size_t)d * NTOT + base;
    const float* urow = xc + (size_t)d * NTOT + base;
    const float* zrow = xz + (size_t)(DI + d) * NTOT + base;
    float*       yrow = yg + (size_t)d * NTOT + base;
    const float* bc   = xdbl + (size_t)DTR * NTOT + base;

    const int t0 = c * CHT;
    for (int t = t0; t < t0 + CHT; t += 4) {
        float4 d4 = *(const float4*)(drow + t);
        float4 u4 = *(const float4*)(urow + t);
        float dlt[4] = { d4.x, d4.y, d4.z, d4.w };
        float du[4]  = { d4.x * u4.x, d4.y * u4.y, d4.z * u4.z, d4.w * u4.w };
        float y0 = 0.f, y1 = 0.f, y2 = 0.f, y3 = 0.f;
#pragma unroll
        for (int n = 0; n < NST; ++n) {
            float4 Bn = *(const float4*)(bc + (size_t)n * NTOT + t);
            float4 Cn = *(const float4*)(bc + (size_t)(NST + n) * NTOT + t);
            float hn = h[n];
            float An = Arow[n];
            hn = hn * __expf(dlt[0] * An) + du[0] * Bn.x;  y0 = fmaf(hn, Cn.x, y0);
            hn = hn * __expf(dlt[1] * An) + du[1] * Bn.y;  y1 = fmaf(hn, Cn.y, y1);
            hn = hn * __expf(dlt[2] * An) + du[2] * Bn.z;  y2 = fmaf(hn, Cn.z, y2);
            hn = hn * __expf(dlt[3] * An) + du[3] * Bn.w;  y3 = fmaf(hn, Cn.w, y3);
            h[n] = hn;
        }
        float zv[4];
        if (br == 0) {
            float4 z4 = *(const float4*)(zrow + t);
            zv[0] = z4.x; zv[1] = z4.y; zv[2] = z4.z; zv[3] = z4.w;
        } else {
            float4 z4 = *(const float4*)(zrow + (L_SEQ - 4 - t));
            zv[0] = z4.w; zv[1] = z4.z; zv[2] = z4.y; zv[3] = z4.x;
        }
        y0 = (y0 + u4.x * Dp) * silu_f(zv[0]);
        y1 = (y1 + u4.y * Dp) * silu_f(zv[1]);
        y2 = (y2 + u4.z * Dp) * silu_f(zv[2]);
        y3 = (y3 + u4.w * Dp) * silu_f(zv[3]);
        if (br == 0) {
            atomicAdd(yrow + t + 0, y0);
            atomicAdd(yrow + t + 1, y1);
            atomicAdd(yrow + t + 2, y2);
            atomicAdd(yrow + t + 3, y3);
        } else {
            atomicAdd(yrow + (L_SEQ - 1 - t), y0);
            atomicAdd(yrow + (L_SEQ - 2 - t), y1);
            atomicAdd(yrow + (L_SEQ - 3 - t), y2);
            atomicAdd(yrow + (L_SEQ - 4 - t), y3);
        }
    }
}

extern "C" void kernel_launch(void* const* d_in, const int* in_sizes, int n_in,
                              void* d_out, int out_size, void* d_ws, size_t ws_size,
                              hipStream_t stream)
{
    const float* hid     = (const float*)d_in[0];
    const float* inw     = (const float*)d_in[1];
    const float* convw   = (const float*)d_in[2];
    const float* convb   = (const float*)d_in[3];
    const float* xpw     = (const float*)d_in[4];
    const float* dtw     = (const float*)d_in[5];
    const float* dtb     = (const float*)d_in[6];
    const float* Alog    = (const float*)d_in[7];
    const float* Dv      = (const float*)d_in[8];
    const float* convw_b = (const float*)d_in[9];
    const float* convb_b = (const float*)d_in[10];
    const float* xpw_b   = (const float*)d_in[11];
    const float* dtw_b   = (const float*)d_in[12];
    const float* dtb_b   = (const float*)d_in[13];
    const float* Alog_b  = (const float*)d_in[14];
    const float* Dv_b    = (const float*)d_in[15];
    const float* outw    = (const float*)d_in[16];
    float* out = (float*)d_out;
    float* ws  = (float*)d_ws;

    // diagnostic guard: undersized workspace -> clean absmax failure, not a fault
    if (ws_size < WS_FLOATS * sizeof(float)) return;

    float* XZ  = ws + OFF_XZ;
    float* XCF = ws + OFF_XCF;
    float* XCB = ws + OFF_XCB;
    float* DLB = ws + OFF_DLB;
    float* XDF = ws + OFF_XDF;
    float* XDB = ws + OFF_XDB;
    float* YG  = ws + OFF_YG;
    float* SS  = ws + OFF_SS;
    float* HLb = ws + OFF_HL;
    float* HIN = ws + OFF_HIN;
    float* DLF = XZ;   // overwrites dead x-half of xz (rows 0..DI-1)

    // zero atomic-accumulation targets: XDF+XDB+YG are contiguous
    hipMemsetAsync(XDF, 0, (2 * (size_t)RTOT + (size_t)DI) * NTOT * sizeof(float), stream);

    dim3 blk(256);
    // K1: xz = in_proj_w @ hidden^T   (B as [n][k])
    gemm_k<true, false, false, false><<<dim3(32, 32, 1), blk, 0, stream>>>(
        inw, hid, XZ, ETOT, NTOT, DM, 0, DM, nullptr);
    // K2: conv + silu both directions
    conv_k<<<dim3(32, 64, 1), blk, 0, stream>>>(XZ, convw, convb, convw_b, convb_b, XCF, XCB);
    // K3: x_dbl = x_proj_w @ xc   (B as [k][n], split-K=8, atomic)
    gemm_k<false, false, false, true><<<dim3(32, 1, 8), blk, 0, stream>>>(
        xpw, XCF, XDF, RTOT, NTOT, DI, 0, DI, nullptr);
    gemm_k<false, false, false, true><<<dim3(32, 1, 8), blk, 0, stream>>>(
        xpw_b, XCB, XDB, RTOT, NTOT, DI, 0, DI, nullptr);
    // K4: delta = softplus(dt_proj_w @ dt_r + bias); fwd result into dead x-half of XZ
    gemm_k<false, false, true, false><<<dim3(32, 16, 1), blk, 0, stream>>>(
        dtw, XDF, DLF, DI, NTOT, DTR, 0, DTR, dtb);
    gemm_k<false, false, true, false><<<dim3(32, 16, 1), blk, 0, stream>>>(
        dtw_b, XDB, DLB, DI, NTOT, DTR, 0, DTR, dtb_b);
    // K5: chunked parallel scan (3 phases)
    scan_part1<<<dim3(DI / 256, NCH, 4), blk, 0, stream>>>(
        XCF, XCB, XDF, XDB, DLF, DLB, Alog, Alog_b, SS, HLb);
    scan_part2<<<dim3(DI / 256, NST, 4), blk, 0, stream>>>(
        SS, HLb, Alog, Alog_b, HIN);
    scan_part3<<<dim3(DI / 256, NCH, 4), blk, 0, stream>>>(
        XZ, XCF, XCB, XDF, XDB, DLF, DLB, HIN, YG, Alog, Alog_b, Dv, Dv_b);
    // K6: out = out_proj_w @ YG, stored [n][m]
    gemm_k<false, true, false, false><<<dim3(32, 8, 1), blk, 0, stream>>>(
        outw, YG, out, DM, NTOT, DI, 0, DI, nullptr);

    (void)in_sizes; (void)n_in; (void)out_size;
}

// Round 4
// 1601.315 us; speedup vs baseline: 1.6489x; 1.3590x over previous
//
#include <hip/hip_runtime.h>
#include <hip/hip_bf16.h>
#include <math.h>

// ---------------------------------------------------------------------------
// Bidirectional Mamba (bimamba v2), B=2, L=2048, D_MODEL=1024, D_INNER=2048,
// D_STATE=16, DT_RANK=64, D_CONV=4.
//
// Pipeline (all fp32, activations laid out [feature][n], n = b*L + t):
//   K1  gemm  : xz[4096][4096]      = in_proj_w @ hidden^T
//   K2  conv  : xc_f/xc_b[2048][4096] = silu(causal dwconv(x)) in scan order
//   K3  gemm  : x_dbl[96][4096]     = x_proj_w @ xc   (split-K=8, atomic)
//   K4  gemm  : delta[2048][4096]   = softplus(dt_proj_w @ dt_r + bias)
//               (forward delta overwrites the dead x-half of xz)
//   K5  scan  : 3-phase chunked parallel scan (32 chunks of 64 steps):
//               part1: local scan per chunk (h0=0) -> hl; S = sum(delta)
//               part2: combine: Hin[c+1] = exp(S_c*A)*Hin[c] + hl_c
//               part3: rerun chunk from Hin, gate, write y IN PLACE over u
//               (XCF/XCB become YGF/YGB; no atomics, no extra buffer)
//   K6  gemm  : out[n][1024] = out_proj_w @ (YGF + rev(YGB)), trans store
//
// Workspace: 51,380,224 floats = 196.0 MiB.
// ---------------------------------------------------------------------------

#define L_SEQ  2048
#define B_SZ   2
#define DM     1024
#define DI     2048
#define NST    16
#define RTOT   96
#define DTR    64
#define NTOT   (B_SZ * L_SEQ)   // 4096
#define ETOT   (2 * DI)         // 4096
#define NCH    32               // scan chunks
#define CHT    (L_SEQ / NCH)    // 64 steps per chunk

// workspace offsets (in floats)
#define OFF_XZ   ((size_t)0)                        // [4096][4096]; rows 0..2047 become DLF
#define OFF_XCF  (OFF_XZ  + (size_t)ETOT * NTOT)    // [2048][4096]; becomes YGF after part3
#define OFF_XCB  (OFF_XCF + (size_t)DI   * NTOT)    // [2048][4096]; becomes YGB (scan order)
#define OFF_DLB  (OFF_XCB + (size_t)DI   * NTOT)    // [2048][4096] delta bwd
#define OFF_XDF  (OFF_DLB + (size_t)DI   * NTOT)    // [96][4096]
#define OFF_XDB  (OFF_XDF + (size_t)RTOT * NTOT)
#define OFF_SS   (OFF_XDB + (size_t)RTOT * NTOT)    // [4][NCH][DI] sum(delta)
#define OFF_HL   (OFF_SS  + (size_t)4 * NCH * DI)   // [4][NCH][NST][DI] local h
#define OFF_HIN  (OFF_HL  + (size_t)4 * NCH * NST * DI)
#define WS_FLOATS (OFF_HIN + (size_t)4 * NCH * NST * DI)   // 51,380,224

__device__ __forceinline__ float silu_f(float x) {
    return x / (1.f + __expf(-x));
}

// ---------------------------------------------------------------------------
// Generic 128x128 fp32 GEMM, 256 threads, 8x8 per thread, KT=16.
// A is [M][K] row-major.
// B_NK:  B is [N][K] (k contiguous) else [K][N] (n contiguous).
// DUAL_B: B := Bm + seq-reversed(B2) (only with [K][N] layout).
// TRANS_STORE: C stored [N][M].  SOFTPLUS: C = softplus(acc + bias[m]).
// ATOMIC: split-K over gridDim.z, atomicAdd stores (C must be pre-zeroed).
// ---------------------------------------------------------------------------
template<bool B_NK, bool DUAL_B, bool TRANS_STORE, bool SOFTPLUS, bool ATOMIC>
__global__ __launch_bounds__(256)
void gemm_k(const float* __restrict__ A, const float* __restrict__ Bm,
            const float* __restrict__ B2, float* __restrict__ C,
            int M, int N, int K, int kbeg, int kend,
            const float* __restrict__ bias)
{
    __shared__ float As[16][132];
    __shared__ float Bs[16][132];
    const int tid = threadIdx.x;
    const int n0 = blockIdx.x * 128;
    const int m0 = blockIdx.y * 128;
    if constexpr (ATOMIC) {
        int ksz = (kend - kbeg) / (int)gridDim.z;
        kbeg += blockIdx.z * ksz;
        kend = kbeg + ksz;
    }
    const int tx = tid & 15, ty = tid >> 4;

    float acc[8][8];
#pragma unroll
    for (int i = 0; i < 8; ++i)
#pragma unroll
        for (int j = 0; j < 8; ++j) acc[i][j] = 0.f;

    for (int k0 = kbeg; k0 < kend; k0 += 16) {
        // stage A tile transposed: As[k][m]
#pragma unroll
        for (int it = 0; it < 2; ++it) {
            int i = tid + it * 256;          // 0..511 float4 slots
            int m = i >> 2, kq = i & 3;
            float4 v = make_float4(0.f, 0.f, 0.f, 0.f);
            int gm = m0 + m;
            if (gm < M) v = *(const float4*)(A + (size_t)gm * K + (k0 + kq * 4));
            As[kq * 4 + 0][m] = v.x; As[kq * 4 + 1][m] = v.y;
            As[kq * 4 + 2][m] = v.z; As[kq * 4 + 3][m] = v.w;
        }
        if constexpr (B_NK) {
#pragma unroll
            for (int it = 0; it < 2; ++it) {
                int i = tid + it * 256;
                int n = i >> 2, kq = i & 3;
                float4 v = *(const float4*)(Bm + (size_t)(n0 + n) * K + (k0 + kq * 4));
                Bs[kq * 4 + 0][n] = v.x; Bs[kq * 4 + 1][n] = v.y;
                Bs[kq * 4 + 2][n] = v.z; Bs[kq * 4 + 3][n] = v.w;
            }
        } else {
#pragma unroll
            for (int it = 0; it < 2; ++it) {
                int i = tid + it * 256;
                int k = i >> 5, nq = i & 31;
                float4 v = *(const float4*)(Bm + (size_t)(k0 + k) * N + n0 + nq * 4);
                if constexpr (DUAL_B) {
                    int nb = n0 + nq * 4;
                    int bbv = nb >> 11;              // / L_SEQ
                    int l   = nb & (L_SEQ - 1);
                    const float* r = B2 + (size_t)(k0 + k) * N + ((size_t)bbv << 11);
                    v.x += r[L_SEQ - 1 - l];
                    v.y += r[L_SEQ - 2 - l];
                    v.z += r[L_SEQ - 3 - l];
                    v.w += r[L_SEQ - 4 - l];
                }
                *(float4*)&Bs[k][nq * 4] = v;
            }
        }
        __syncthreads();
#pragma unroll
        for (int kk = 0; kk < 16; ++kk) {
            float av[8], bv[8];
            *(float4*)&av[0] = *(const float4*)&As[kk][ty * 8];
            *(float4*)&av[4] = *(const float4*)&As[kk][ty * 8 + 4];
            *(float4*)&bv[0] = *(const float4*)&Bs[kk][tx * 8];
            *(float4*)&bv[4] = *(const float4*)&Bs[kk][tx * 8 + 4];
#pragma unroll
            for (int i = 0; i < 8; ++i)
#pragma unroll
                for (int j = 0; j < 8; ++j)
                    acc[i][j] = fmaf(av[i], bv[j], acc[i][j]);
        }
        __syncthreads();
    }

    if constexpr (TRANS_STORE) {
#pragma unroll
        for (int j = 0; j < 8; ++j) {
            int gn = n0 + tx * 8 + j;
            float4 v0 = make_float4(acc[0][j], acc[1][j], acc[2][j], acc[3][j]);
            float4 v1 = make_float4(acc[4][j], acc[5][j], acc[6][j], acc[7][j]);
            *(float4*)(C + (size_t)gn * M + m0 + ty * 8)     = v0;
            *(float4*)(C + (size_t)gn * M + m0 + ty * 8 + 4) = v1;
        }
    } else {
#pragma unroll
        for (int i = 0; i < 8; ++i) {
            int gm = m0 + ty * 8 + i;
            if (gm < M) {
                float* cp = C + (size_t)gm * N + n0 + tx * 8;
                if constexpr (ATOMIC) {
#pragma unroll
                    for (int j = 0; j < 8; ++j) atomicAdd(cp + j, acc[i][j]);
                } else if constexpr (SOFTPLUS) {
                    float bvl = bias[gm];
                    float o[8];
#pragma unroll
                    for (int j = 0; j < 8; ++j) {
                        float x = acc[i][j] + bvl;
                        o[j] = (x > 20.f) ? x : log1pf(expf(x));
                    }
                    *(float4*)cp       = make_float4(o[0], o[1], o[2], o[3]);
                    *(float4*)(cp + 4) = make_float4(o[4], o[5], o[6], o[7]);
                } else {
                    *(float4*)cp       = make_float4(acc[i][0], acc[i][1], acc[i][2], acc[i][3]);
                    *(float4*)(cp + 4) = make_float4(acc[i][4], acc[i][5], acc[i][6], acc[i][7]);
                }
            }
        }
    }
}

// ---------------------------------------------------------------------------
// Causal depthwise conv (K=4) + silu, both directions, outputs in scan order.
// ---------------------------------------------------------------------------
__global__ __launch_bounds__(256)
void conv_k(const float* __restrict__ xz,
            const float* __restrict__ wf, const float* __restrict__ bf,
            const float* __restrict__ wb, const float* __restrict__ bb,
            float* __restrict__ xcf, float* __restrict__ xcb)
{
    __shared__ float xs[64][72];
    const int tid = threadIdx.x;
    const int d0 = blockIdx.x * 64;
    const int n0 = blockIdx.y * 64;
    const int b  = n0 >> 11;            // n0 / L_SEQ
    const int l0 = n0 & (L_SEQ - 1);
    const size_t bbase = (size_t)b << 11;   // b * L_SEQ

    for (int i = tid; i < 64 * 70; i += 256) {
        int r = i / 70, c = i % 70;
        int l = l0 - 3 + c;
        float v = 0.f;
        if (l >= 0 && l < L_SEQ) v = xz[(size_t)(d0 + r) * NTOT + bbase + l];
        xs[r][c] = v;
    }
    __syncthreads();

    const int c   = tid & 63;
    const int r00 = tid >> 6;           // 0..3
    const int l   = l0 + c;
    for (int rr = 0; rr < 64; rr += 4) {
        int r = rr + r00;
        int d = d0 + r;
        float w0 = wf[d * 4 + 0], w1 = wf[d * 4 + 1];
        float w2 = wf[d * 4 + 2], w3 = wf[d * 4 + 3];
        float xf = bf[d] + w0 * xs[r][c] + w1 * xs[r][c + 1]
                         + w2 * xs[r][c + 2] + w3 * xs[r][c + 3];
        xcf[(size_t)d * NTOT + bbase + l] = silu_f(xf);
        float v0 = wb[d * 4 + 0], v1 = wb[d * 4 + 1];
        float v2 = wb[d * 4 + 2], v3 = wb[d * 4 + 3];
        float xb = bb[d] + v3 * xs[r][c + 3] + v2 * xs[r][c + 4]
                         + v1 * xs[r][c + 5] + v0 * xs[r][c + 6];
        xcb[(size_t)d * NTOT + bbase + (L_SEQ - 1 - l)] = silu_f(xb);
    }
}

// ---------------------------------------------------------------------------
// Chunked selective scan, phase 1: per (d, chunk, b, br) compute the local
// scan hl (h0 = 0) and S = sum(delta) over the chunk (chunk decay =
// exp(S * A[n]) since prod(exp) = exp(sum)).
// ---------------------------------------------------------------------------
__global__ __launch_bounds__(256)
void scan_part1(const float* __restrict__ xcf, const float* __restrict__ xcb,
                const float* __restrict__ xdf, const float* __restrict__ xdb,
                const float* __restrict__ dlf, const float* __restrict__ dlb,
                const float* __restrict__ Alog_f, const float* __restrict__ Alog_b,
                float* __restrict__ SS, float* __restrict__ HL)
{
    const int d  = blockIdx.x * 256 + threadIdx.x;
    const int c  = blockIdx.y;
    const int bb = blockIdx.z;          // br*2 + b
    const int b  = bb & 1;
    const int br = bb >> 1;

    const float* xc   = br ? xcb : xcf;
    const float* xdbl = br ? xdb : xdf;
    const float* dl   = br ? dlb : dlf;
    const float* Alog = br ? Alog_b : Alog_f;

    float Arow[NST], h[NST];
#pragma unroll
    for (int n = 0; n < NST; ++n) {
        Arow[n] = -__expf(Alog[d * NST + n]);
        h[n] = 0.f;
    }
    float S = 0.f;

    const size_t base = (size_t)b * L_SEQ;
    const float* drow = dl + (size_t)d * NTOT + base;
    const float* urow = xc + (size_t)d * NTOT + base;
    const float* bcB  = xdbl + (size_t)DTR * NTOT + base;

    const int t0 = c * CHT;
    for (int t = t0; t < t0 + CHT; t += 4) {
        float4 d4 = *(const float4*)(drow + t);
        float4 u4 = *(const float4*)(urow + t);
        S += (d4.x + d4.y) + (d4.z + d4.w);
        float dlt[4] = { d4.x, d4.y, d4.z, d4.w };
        float du[4]  = { d4.x * u4.x, d4.y * u4.y, d4.z * u4.z, d4.w * u4.w };
#pragma unroll
        for (int n = 0; n < NST; ++n) {
            float4 Bn = *(const float4*)(bcB + (size_t)n * NTOT + t);
            float hn = h[n];
            float An = Arow[n];
            hn = hn * __expf(dlt[0] * An) + du[0] * Bn.x;
            hn = hn * __expf(dlt[1] * An) + du[1] * Bn.y;
            hn = hn * __expf(dlt[2] * An) + du[2] * Bn.z;
            hn = hn * __expf(dlt[3] * An) + du[3] * Bn.w;
            h[n] = hn;
        }
    }
    SS[((size_t)bb * NCH + c) * DI + d] = S;
#pragma unroll
    for (int n = 0; n < NST; ++n)
        HL[(((size_t)bb * NCH + c) * NST + n) * DI + d] = h[n];
}

// ---------------------------------------------------------------------------
// Phase 2: per (d, n, b, br) sequentially combine the 32 chunk summaries:
// Hin[c] = H;  H = exp(S_c * A) * H + hl_c.
// ---------------------------------------------------------------------------
__global__ __launch_bounds__(256)
void scan_part2(const float* __restrict__ SS, const float* __restrict__ HL,
                const float* __restrict__ Alog_f, const float* __restrict__ Alog_b,
                float* __restrict__ HIN)
{
    const int d  = blockIdx.x * 256 + threadIdx.x;
    const int n  = blockIdx.y;
    const int bb = blockIdx.z;
    const int br = bb >> 1;
    const float* Alog = br ? Alog_b : Alog_f;
    const float A = -__expf(Alog[d * NST + n]);

    float H = 0.f;
#pragma unroll
    for (int c = 0; c < NCH; ++c) {
        const size_t si = ((size_t)bb * NCH + c) * DI + d;
        const size_t hi = (((size_t)bb * NCH + c) * NST + n) * DI + d;
        HIN[hi] = H;
        H = __expf(SS[si] * A) * H + HL[hi];
    }
}

// ---------------------------------------------------------------------------
// Phase 3: rerun each chunk from its entry state Hin, compute y, add u*D,
// gate with silu(z), and write the result IN PLACE over the u buffer
// (xcf for fwd, xcb for bwd — scan order, each element read+written by
// exactly the same thread, data-dependent so no reordering hazard).
// ---------------------------------------------------------------------------
__global__ __launch_bounds__(256)
void scan_part3(const float* __restrict__ xz,
                float* xcf, float* xcb,
                const float* __restrict__ xdf, const float* __restrict__ xdb,
                const float* __restrict__ dlf, const float* __restrict__ dlb,
                const float* __restrict__ HIN,
                const float* __restrict__ Alog_f, const float* __restrict__ Alog_b,
                const float* __restrict__ Df, const float* __restrict__ Db)
{
    const int d  = blockIdx.x * 256 + threadIdx.x;
    const int c  = blockIdx.y;
    const int bb = blockIdx.z;
    const int b  = bb & 1;
    const int br = bb >> 1;

    float*       uy   = br ? xcb : xcf;     // read u, write gated y (same addr)
    const float* xdbl = br ? xdb : xdf;
    const float* dl   = br ? dlb : dlf;
    const float* Alog = br ? Alog_b : Alog_f;
    const float* Dv   = br ? Db : Df;

    float Arow[NST], h[NST];
#pragma unroll
    for (int n = 0; n < NST; ++n) {
        Arow[n] = -__expf(Alog[d * NST + n]);
        h[n] = HIN[(((size_t)bb * NCH + c) * NST + n) * DI + d];
    }
    const float Dp = Dv[d];

    const size_t base = (size_t)b * L_SEQ;
    const float* drow = dl + (size_t)d * NTOT + base;
    float*       uyrw = uy + (size_t)d * NTOT + base;
    const float* zrow = xz + (size_t)(DI + d) * NTOT + base;
    const float* bc   = xdbl + (size_t)DTR * NTOT + base;

    const int t0 = c * CHT;
    for (int t = t0; t < t0 + CHT; t += 4) {
        float4 d4 = *(const float4*)(drow + t);
        float4 u4 = *(const float4*)(uyrw + t);
        float dlt[4] = { d4.x, d4.y, d4.z, d4.w };
        float du[4]  = { d4.x * u4.x, d4.y * u4.y, d4.z * u4.z, d4.w * u4.w };
        float y0 = 0.f, y1 = 0.f, y2 = 0.f, y3 = 0.f;
#pragma unroll
        for (int n = 0; n < NST; ++n) {
            float4 Bn = *(const float4*)(bc + (size_t)n * NTOT + t);
            float4 Cn = *(const float4*)(bc + (size_t)(NST + n) * NTOT + t);
            float hn = h[n];
            float An = Arow[n];
            hn = hn * __expf(dlt[0] * An) + du[0] * Bn.x;  y0 = fmaf(hn, Cn.x, y0);
            hn = hn * __expf(dlt[1] * An) + du[1] * Bn.y;  y1 = fmaf(hn, Cn.y, y1);
            hn = hn * __expf(dlt[2] * An) + du[2] * Bn.z;  y2 = fmaf(hn, Cn.z, y2);
            hn = hn * __expf(dlt[3] * An) + du[3] * Bn.w;  y3 = fmaf(hn, Cn.w, y3);
            h[n] = hn;
        }
        float zv[4];
        if (br == 0) {
            float4 z4 = *(const float4*)(zrow + t);
            zv[0] = z4.x; zv[1] = z4.y; zv[2] = z4.z; zv[3] = z4.w;
        } else {
            float4 z4 = *(const float4*)(zrow + (L_SEQ - 4 - t));
            zv[0] = z4.w; zv[1] = z4.z; zv[2] = z4.y; zv[3] = z4.x;
        }
        y0 = (y0 + u4.x * Dp) * silu_f(zv[0]);
        y1 = (y1 + u4.y * Dp) * silu_f(zv[1]);
        y2 = (y2 + u4.z * Dp) * silu_f(zv[2]);
        y3 = (y3 + u4.w * Dp) * silu_f(zv[3]);
        *(float4*)(uyrw + t) = make_float4(y0, y1, y2, y3);
    }
}

extern "C" void kernel_launch(void* const* d_in, const int* in_sizes, int n_in,
                              void* d_out, int out_size, void* d_ws, size_t ws_size,
                              hipStream_t stream)
{
    const float* hid     = (const float*)d_in[0];
    const float* inw     = (const float*)d_in[1];
    const float* convw   = (const float*)d_in[2];
    const float* convb   = (const float*)d_in[3];
    const float* xpw     = (const float*)d_in[4];
    const float* dtw     = (const float*)d_in[5];
    const float* dtb     = (const float*)d_in[6];
    const float* Alog    = (const float*)d_in[7];
    const float* Dv      = (const float*)d_in[8];
    const float* convw_b = (const float*)d_in[9];
    const float* convb_b = (const float*)d_in[10];
    const float* xpw_b   = (const float*)d_in[11];
    const float* dtw_b   = (const float*)d_in[12];
    const float* dtb_b   = (const float*)d_in[13];
    const float* Alog_b  = (const float*)d_in[14];
    const float* Dv_b    = (const float*)d_in[15];
    const float* outw    = (const float*)d_in[16];
    float* out = (float*)d_out;
    float* ws  = (float*)d_ws;

    // diagnostic guard: undersized workspace -> clean absmax failure, not a fault
    if (ws_size < WS_FLOATS * sizeof(float)) return;

    float* XZ  = ws + OFF_XZ;
    float* XCF = ws + OFF_XCF;
    float* XCB = ws + OFF_XCB;
    float* DLB = ws + OFF_DLB;
    float* XDF = ws + OFF_XDF;
    float* XDB = ws + OFF_XDB;
    float* SS  = ws + OFF_SS;
    float* HLb = ws + OFF_HL;
    float* HIN = ws + OFF_HIN;
    float* DLF = XZ;   // overwrites dead x-half of xz (rows 0..DI-1)

    // zero atomic-accumulation targets (split-K x_dbl): XDF+XDB contiguous
    hipMemsetAsync(XDF, 0, 2 * (size_t)RTOT * NTOT * sizeof(float), stream);

    dim3 blk(256);
    // K1: xz = in_proj_w @ hidden^T   (B as [n][k])
    gemm_k<true, false, false, false, false><<<dim3(32, 32, 1), blk, 0, stream>>>(
        inw, hid, nullptr, XZ, ETOT, NTOT, DM, 0, DM, nullptr);
    // K2: conv + silu both directions
    conv_k<<<dim3(32, 64, 1), blk, 0, stream>>>(XZ, convw, convb, convw_b, convb_b, XCF, XCB);
    // K3: x_dbl = x_proj_w @ xc   (B as [k][n], split-K=8, atomic)
    gemm_k<false, false, false, false, true><<<dim3(32, 1, 8), blk, 0, stream>>>(
        xpw, XCF, nullptr, XDF, RTOT, NTOT, DI, 0, DI, nullptr);
    gemm_k<false, false, false, false, true><<<dim3(32, 1, 8), blk, 0, stream>>>(
        xpw_b, XCB, nullptr, XDB, RTOT, NTOT, DI, 0, DI, nullptr);
    // K4: delta = softplus(dt_proj_w @ dt_r + bias); fwd result into dead x-half of XZ
    gemm_k<false, false, false, true, false><<<dim3(32, 16, 1), blk, 0, stream>>>(
        dtw, XDF, nullptr, DLF, DI, NTOT, DTR, 0, DTR, dtb);
    gemm_k<false, false, false, true, false><<<dim3(32, 16, 1), blk, 0, stream>>>(
        dtw_b, XDB, nullptr, DLB, DI, NTOT, DTR, 0, DTR, dtb_b);
    // K5: chunked parallel scan (3 phases); part3 overwrites XCF/XCB with gated y
    scan_part1<<<dim3(DI / 256, NCH, 4), blk, 0, stream>>>(
        XCF, XCB, XDF, XDB, DLF, DLB, Alog, Alog_b, SS, HLb);
    scan_part2<<<dim3(DI / 256, NST, 4), blk, 0, stream>>>(
        SS, HLb, Alog, Alog_b, HIN);
    scan_part3<<<dim3(DI / 256, NCH, 4), blk, 0, stream>>>(
        XZ, XCF, XCB, XDF, XDB, DLF, DLB, HIN, Alog, Alog_b, Dv, Dv_b);
    // K6: out = out_proj_w @ (YGF + rev(YGB)), stored [n][m]
    gemm_k<false, true, true, false, false><<<dim3(32, 8, 1), blk, 0, stream>>>(
        outw, XCF, XCB, out, DM, NTOT, DI, 0, DI, nullptr);

    (void)in_sizes; (void)n_in; (void)out_size;
}

// Round 5
// 1029.089 us; speedup vs baseline: 2.5658x; 1.5561x over previous
//
#include <hip/hip_runtime.h>
#include <hip/hip_bf16.h>
#include <math.h>

// ---------------------------------------------------------------------------
// Bidirectional Mamba (bimamba v2), B=2, L=2048, D_MODEL=1024, D_INNER=2048,
// D_STATE=16, DT_RANK=64, D_CONV=4.
//
// Pipeline (activations [feature][n], n = b*L + t, unless noted):
//   K1  mfma  : xz[4096][4096]      = in_proj_w @ hidden^T   (bf16 MFMA)
//   K2  conv  : xc_f/xc_b[2048][4096] = silu(causal dwconv(x)) in scan order
//   K3  gemm  : x_dbl[96][4096]     = x_proj_w @ xc   (fp32, split-K=8, atomic)
//   K4  gemm  : delta[2048][4096]   = softplus(dt_proj_w @ dt_r + bias) (fp32)
//               (forward delta overwrites the dead x-half of xz)
//   K5  scan  : 3-phase chunked parallel scan (32 chunks of 64 steps);
//               part3 writes gated y as bf16, TRANSPOSED [n][d], bwd branch
//               pre-reversed -> K6 needs no reversal or transpose.
//   K6  mfma  : out[n][1024] = out_proj_w @ (ygt_f + ygt_b)  (bf16 MFMA,
//               transposed store)
//
// Workspace: 55,574,528 floats = 212.0 MiB.
// ---------------------------------------------------------------------------

#define L_SEQ  2048
#define B_SZ   2
#define DM     1024
#define DI     2048
#define NST    16
#define RTOT   96
#define DTR    64
#define NTOT   (B_SZ * L_SEQ)   // 4096
#define ETOT   (2 * DI)         // 4096
#define NCH    32               // scan chunks
#define CHT    (L_SEQ / NCH)    // 64 steps per chunk

// workspace offsets (in floats)
#define OFF_XZ   ((size_t)0)                        // [4096][4096]; rows 0..2047 become DLF
#define OFF_XCF  (OFF_XZ  + (size_t)ETOT * NTOT)    // [2048][4096] u fwd
#define OFF_XCB  (OFF_XCF + (size_t)DI   * NTOT)    // [2048][4096] u bwd (scan order)
#define OFF_DLB  (OFF_XCB + (size_t)DI   * NTOT)    // [2048][4096] delta bwd
#define OFF_XDF  (OFF_DLB + (size_t)DI   * NTOT)    // [96][4096]
#define OFF_XDB  (OFF_XDF + (size_t)RTOT * NTOT)
#define OFF_SS   (OFF_XDB + (size_t)RTOT * NTOT)    // [4][NCH][DI] sum(delta)
#define OFF_HL   (OFF_SS  + (size_t)4 * NCH * DI)   // [4][NCH][NST][DI] local h -> Hin (in place)
#define OFF_YGTF (OFF_HL  + (size_t)4 * NCH * NST * DI)   // bf16 [NTOT][DI]
#define OFF_YGTB (OFF_YGTF + (size_t)NTOT * DI / 2)       // bf16 [NTOT][DI]
#define WS_FLOATS (OFF_YGTB + (size_t)NTOT * DI / 2)      // 55,574,528

typedef __bf16 bf16x8 __attribute__((ext_vector_type(8)));
typedef float  floatx4 __attribute__((ext_vector_type(4)));
#define LDK 40   // LDS row stride in bf16 elements (32 + 8 pad -> <=2-way conflicts)

__device__ __forceinline__ float silu_f(float x) {
    return x / (1.f + __expf(-x));
}

// ---------------------------------------------------------------------------
// bf16 MFMA GEMM: C[M][N] (fp32) = A[M][K] @ B[N][K]^T.
// A: fp32 global, converted to bf16 during staging.
// B: if DUALB, B = B1 + B2 (both bf16 [N][K]); else Bf (fp32 [N][K]).
// TRANS: C stored [N][M] (out layout), else [M][N].
// 128x128 tile, 256 threads = 4 waves (2x2), each wave 64x64 via 4x4
// mfma_f32_16x16x32_bf16; BK = 32.
// ---------------------------------------------------------------------------
template<bool DUALB, bool TRANS>
__global__ __launch_bounds__(256)
void gemm_mfma(const float* __restrict__ A, const float* __restrict__ Bf,
               const __bf16* __restrict__ B1, const __bf16* __restrict__ B2,
               float* __restrict__ C, int M, int N, int K)
{
    __shared__ __bf16 As[128 * LDK];
    __shared__ __bf16 Bs[128 * LDK];
    const int tid  = threadIdx.x;
    const int m0   = blockIdx.y * 128;
    const int n0   = blockIdx.x * 128;
    const int lane = tid & 63;
    const int wave = tid >> 6;
    const int wy   = wave >> 1, wx = wave & 1;    // 2x2 waves of 64x64
    const int lr   = lane & 15;                   // row-in-16 (A) / col (B,D)
    const int q    = lane >> 4;                   // quad 0..3

    floatx4 acc[4][4];
#pragma unroll
    for (int i = 0; i < 4; ++i)
#pragma unroll
        for (int j = 0; j < 4; ++j) acc[i][j] = (floatx4)(0.0f);

    // staging: each thread covers 16 k-elements of one row of A and of B
    const int srow = tid >> 1;
    const int kh   = (tid & 1) * 16;
    const float* ga = A + (size_t)(m0 + srow) * K + kh;
    __bf16* wa = &As[srow * LDK + kh];
    __bf16* wb = &Bs[srow * LDK + kh];

    for (int k0 = 0; k0 < K; k0 += 32) {
        // ---- stage A (fp32 -> bf16) ----
        {
            float4 a0 = *(const float4*)(ga + k0);
            float4 a1 = *(const float4*)(ga + k0 + 4);
            float4 a2 = *(const float4*)(ga + k0 + 8);
            float4 a3 = *(const float4*)(ga + k0 + 12);
            bf16x8 p0, p1;
            p0[0]=(__bf16)a0.x; p0[1]=(__bf16)a0.y; p0[2]=(__bf16)a0.z; p0[3]=(__bf16)a0.w;
            p0[4]=(__bf16)a1.x; p0[5]=(__bf16)a1.y; p0[6]=(__bf16)a1.z; p0[7]=(__bf16)a1.w;
            p1[0]=(__bf16)a2.x; p1[1]=(__bf16)a2.y; p1[2]=(__bf16)a2.z; p1[3]=(__bf16)a2.w;
            p1[4]=(__bf16)a3.x; p1[5]=(__bf16)a3.y; p1[6]=(__bf16)a3.z; p1[7]=(__bf16)a3.w;
            *(bf16x8*)wa = p0; *(bf16x8*)(wa + 8) = p1;
        }
        // ---- stage B ----
        if constexpr (DUALB) {
            const __bf16* gb1 = B1 + (size_t)(n0 + srow) * K + kh + k0;
            const __bf16* gb2 = B2 + (size_t)(n0 + srow) * K + kh + k0;
            bf16x8 u0 = *(const bf16x8*)gb1;
            bf16x8 u1 = *(const bf16x8*)(gb1 + 8);
            bf16x8 v0 = *(const bf16x8*)gb2;
            bf16x8 v1 = *(const bf16x8*)(gb2 + 8);
            bf16x8 s0, s1;
#pragma unroll
            for (int e = 0; e < 8; ++e) {
                s0[e] = (__bf16)((float)u0[e] + (float)v0[e]);
                s1[e] = (__bf16)((float)u1[e] + (float)v1[e]);
            }
            *(bf16x8*)wb = s0; *(bf16x8*)(wb + 8) = s1;
        } else {
            const float* gb = Bf + (size_t)(n0 + srow) * K + kh + k0;
            float4 b0 = *(const float4*)(gb);
            float4 b1v = *(const float4*)(gb + 4);
            float4 b2v = *(const float4*)(gb + 8);
            float4 b3 = *(const float4*)(gb + 12);
            bf16x8 p0, p1;
            p0[0]=(__bf16)b0.x; p0[1]=(__bf16)b0.y; p0[2]=(__bf16)b0.z; p0[3]=(__bf16)b0.w;
            p0[4]=(__bf16)b1v.x; p0[5]=(__bf16)b1v.y; p0[6]=(__bf16)b1v.z; p0[7]=(__bf16)b1v.w;
            p1[0]=(__bf16)b2v.x; p1[1]=(__bf16)b2v.y; p1[2]=(__bf16)b2v.z; p1[3]=(__bf16)b2v.w;
            p1[4]=(__bf16)b3.x; p1[5]=(__bf16)b3.y; p1[6]=(__bf16)b3.z; p1[7]=(__bf16)b3.w;
            *(bf16x8*)wb = p0; *(bf16x8*)(wb + 8) = p1;
        }
        __syncthreads();

        // ---- fragments + 16 MFMA ----
        bf16x8 af[4], bfr[4];
#pragma unroll
        for (int i = 0; i < 4; ++i)
            af[i] = *(const bf16x8*)&As[(wy * 64 + i * 16 + lr) * LDK + q * 8];
#pragma unroll
        for (int j = 0; j < 4; ++j)
            bfr[j] = *(const bf16x8*)&Bs[(wx * 64 + j * 16 + lr) * LDK + q * 8];
#pragma unroll
        for (int i = 0; i < 4; ++i)
#pragma unroll
            for (int j = 0; j < 4; ++j)
                acc[i][j] = __builtin_amdgcn_mfma_f32_16x16x32_bf16(
                    af[i], bfr[j], acc[i][j], 0, 0, 0);
        __syncthreads();
    }

    // epilogue: D[row=q*4+r][col=lr] per 16x16 tile
    const int mb = m0 + wy * 64;
    const int nb = n0 + wx * 64;
#pragma unroll
    for (int i = 0; i < 4; ++i) {
#pragma unroll
        for (int r = 0; r < 4; ++r) {
            int gm = mb + i * 16 + q * 4 + r;
#pragma unroll
            for (int j = 0; j < 4; ++j) {
                int gn = nb + j * 16 + lr;
                if constexpr (TRANS) C[(size_t)gn * M + gm] = acc[i][j][r];
                else                 C[(size_t)gm * N + gn] = acc[i][j][r];
            }
        }
    }
}

// ---------------------------------------------------------------------------
// Generic 128x128 fp32 GEMM (kept for K3 split-K and K4 softplus).
// A is [M][K] row-major; B is [K][N] (n contiguous).
// SOFTPLUS: C = softplus(acc + bias[m]).  ATOMIC: split-K atomicAdd.
// ---------------------------------------------------------------------------
template<bool SOFTPLUS, bool ATOMIC>
__global__ __launch_bounds__(256)
void gemm_k(const float* __restrict__ A, const float* __restrict__ Bm,
            float* __restrict__ C,
            int M, int N, int K, int kbeg, int kend,
            const float* __restrict__ bias)
{
    __shared__ float As[16][132];
    __shared__ float Bs[16][132];
    const int tid = threadIdx.x;
    const int n0 = blockIdx.x * 128;
    const int m0 = blockIdx.y * 128;
    if constexpr (ATOMIC) {
        int ksz = (kend - kbeg) / (int)gridDim.z;
        kbeg += blockIdx.z * ksz;
        kend = kbeg + ksz;
    }
    const int tx = tid & 15, ty = tid >> 4;

    float acc[8][8];
#pragma unroll
    for (int i = 0; i < 8; ++i)
#pragma unroll
        for (int j = 0; j < 8; ++j) acc[i][j] = 0.f;

    for (int k0 = kbeg; k0 < kend; k0 += 16) {
#pragma unroll
        for (int it = 0; it < 2; ++it) {
            int i = tid + it * 256;
            int m = i >> 2, kq = i & 3;
            float4 v = make_float4(0.f, 0.f, 0.f, 0.f);
            int gm = m0 + m;
            if (gm < M) v = *(const float4*)(A + (size_t)gm * K + (k0 + kq * 4));
            As[kq * 4 + 0][m] = v.x; As[kq * 4 + 1][m] = v.y;
            As[kq * 4 + 2][m] = v.z; As[kq * 4 + 3][m] = v.w;
        }
#pragma unroll
        for (int it = 0; it < 2; ++it) {
            int i = tid + it * 256;
            int k = i >> 5, nq = i & 31;
            float4 v = *(const float4*)(Bm + (size_t)(k0 + k) * N + n0 + nq * 4);
            *(float4*)&Bs[k][nq * 4] = v;
        }
        __syncthreads();
#pragma unroll
        for (int kk = 0; kk < 16; ++kk) {
            float av[8], bv[8];
            *(float4*)&av[0] = *(const float4*)&As[kk][ty * 8];
            *(float4*)&av[4] = *(const float4*)&As[kk][ty * 8 + 4];
            *(float4*)&bv[0] = *(const float4*)&Bs[kk][tx * 8];
            *(float4*)&bv[4] = *(const float4*)&Bs[kk][tx * 8 + 4];
#pragma unroll
            for (int i = 0; i < 8; ++i)
#pragma unroll
                for (int j = 0; j < 8; ++j)
                    acc[i][j] = fmaf(av[i], bv[j], acc[i][j]);
        }
        __syncthreads();
    }

#pragma unroll
    for (int i = 0; i < 8; ++i) {
        int gm = m0 + ty * 8 + i;
        if (gm < M) {
            float* cp = C + (size_t)gm * N + n0 + tx * 8;
            if constexpr (ATOMIC) {
#pragma unroll
                for (int j = 0; j < 8; ++j) atomicAdd(cp + j, acc[i][j]);
            } else if constexpr (SOFTPLUS) {
                float bvl = bias[gm];
                float o[8];
#pragma unroll
                for (int j = 0; j < 8; ++j) {
                    float x = acc[i][j] + bvl;
                    o[j] = (x > 20.f) ? x : log1pf(expf(x));
                }
                *(float4*)cp       = make_float4(o[0], o[1], o[2], o[3]);
                *(float4*)(cp + 4) = make_float4(o[4], o[5], o[6], o[7]);
            } else {
                *(float4*)cp       = make_float4(acc[i][0], acc[i][1], acc[i][2], acc[i][3]);
                *(float4*)(cp + 4) = make_float4(acc[i][4], acc[i][5], acc[i][6], acc[i][7]);
            }
        }
    }
}

// ---------------------------------------------------------------------------
// Causal depthwise conv (K=4) + silu, both directions, outputs in scan order.
// ---------------------------------------------------------------------------
__global__ __launch_bounds__(256)
void conv_k(const float* __restrict__ xz,
            const float* __restrict__ wf, const float* __restrict__ bf,
            const float* __restrict__ wb, const float* __restrict__ bb,
            float* __restrict__ xcf, float* __restrict__ xcb)
{
    __shared__ float xs[64][72];
    const int tid = threadIdx.x;
    const int d0 = blockIdx.x * 64;
    const int n0 = blockIdx.y * 64;
    const int b  = n0 >> 11;
    const int l0 = n0 & (L_SEQ - 1);
    const size_t bbase = (size_t)b << 11;

    for (int i = tid; i < 64 * 70; i += 256) {
        int r = i / 70, c = i % 70;
        int l = l0 - 3 + c;
        float v = 0.f;
        if (l >= 0 && l < L_SEQ) v = xz[(size_t)(d0 + r) * NTOT + bbase + l];
        xs[r][c] = v;
    }
    __syncthreads();

    const int c   = tid & 63;
    const int r00 = tid >> 6;
    const int l   = l0 + c;
    for (int rr = 0; rr < 64; rr += 4) {
        int r = rr + r00;
        int d = d0 + r;
        float w0 = wf[d * 4 + 0], w1 = wf[d * 4 + 1];
        float w2 = wf[d * 4 + 2], w3 = wf[d * 4 + 3];
        float xf = bf[d] + w0 * xs[r][c] + w1 * xs[r][c + 1]
                         + w2 * xs[r][c + 2] + w3 * xs[r][c + 3];
        xcf[(size_t)d * NTOT + bbase + l] = silu_f(xf);
        float v0 = wb[d * 4 + 0], v1 = wb[d * 4 + 1];
        float v2 = wb[d * 4 + 2], v3 = wb[d * 4 + 3];
        float xb = bb[d] + v3 * xs[r][c + 3] + v2 * xs[r][c + 4]
                         + v1 * xs[r][c + 5] + v0 * xs[r][c + 6];
        xcb[(size_t)d * NTOT + bbase + (L_SEQ - 1 - l)] = silu_f(xb);
    }
}

// ---------------------------------------------------------------------------
// Chunked selective scan, phase 1: local scan per chunk + S = sum(delta).
// ---------------------------------------------------------------------------
__global__ __launch_bounds__(256)
void scan_part1(const float* __restrict__ xcf, const float* __restrict__ xcb,
                const float* __restrict__ xdf, const float* __restrict__ xdb,
                const float* __restrict__ dlf, const float* __restrict__ dlb,
                const float* __restrict__ Alog_f, const float* __restrict__ Alog_b,
                float* __restrict__ SS, float* __restrict__ HL)
{
    const int d  = blockIdx.x * 256 + threadIdx.x;
    const int c  = blockIdx.y;
    const int bb = blockIdx.z;
    const int b  = bb & 1;
    const int br = bb >> 1;

    const float* xc   = br ? xcb : xcf;
    const float* xdbl = br ? xdb : xdf;
    const float* dl   = br ? dlb : dlf;
    const float* Alog = br ? Alog_b : Alog_f;

    float Arow[NST], h[NST];
#pragma unroll
    for (int n = 0; n < NST; ++n) {
        Arow[n] = -__expf(Alog[d * NST + n]);
        h[n] = 0.f;
    }
    float S = 0.f;

    const size_t base = (size_t)b * L_SEQ;
    const float* drow = dl + (size_t)d * NTOT + base;
    const float* urow = xc + (size_t)d * NTOT + base;
    const float* bcB  = xdbl + (size_t)DTR * NTOT + base;

    const int t0 = c * CHT;
    for (int t = t0; t < t0 + CHT; t += 4) {
        float4 d4 = *(const float4*)(drow + t);
        float4 u4 = *(const float4*)(urow + t);
        S += (d4.x + d4.y) + (d4.z + d4.w);
        float dlt[4] = { d4.x, d4.y, d4.z, d4.w };
        float du[4]  = { d4.x * u4.x, d4.y * u4.y, d4.z * u4.z, d4.w * u4.w };
#pragma unroll
        for (int n = 0; n < NST; ++n) {
            float4 Bn = *(const float4*)(bcB + (size_t)n * NTOT + t);
            float hn = h[n];
            float An = Arow[n];
            hn = hn * __expf(dlt[0] * An) + du[0] * Bn.x;
            hn = hn * __expf(dlt[1] * An) + du[1] * Bn.y;
            hn = hn * __expf(dlt[2] * An) + du[2] * Bn.z;
            hn = hn * __expf(dlt[3] * An) + du[3] * Bn.w;
            h[n] = hn;
        }
    }
    SS[((size_t)bb * NCH + c) * DI + d] = S;
#pragma unroll
    for (int n = 0; n < NST; ++n)
        HL[(((size_t)bb * NCH + c) * NST + n) * DI + d] = h[n];
}

// ---------------------------------------------------------------------------
// Phase 2 (in place): HL[c] is replaced by the chunk ENTRY state Hin[c]:
//   tmp = HL[c]; HL[c] = H; H = exp(S_c*A)*H + tmp.
// ---------------------------------------------------------------------------
__global__ __launch_bounds__(256)
void scan_part2(const float* __restrict__ SS, float* HL,
                const float* __restrict__ Alog_f, const float* __restrict__ Alog_b)
{
    const int d  = blockIdx.x * 256 + threadIdx.x;
    const int n  = blockIdx.y;
    const int bb = blockIdx.z;
    const int br = bb >> 1;
    const float* Alog = br ? Alog_b : Alog_f;
    const float A = -__expf(Alog[d * NST + n]);

    float H = 0.f;
#pragma unroll
    for (int c = 0; c < NCH; ++c) {
        const size_t si = ((size_t)bb * NCH + c) * DI + d;
        const size_t hi = (((size_t)bb * NCH + c) * NST + n) * DI + d;
        float hl = HL[hi];
        HL[hi] = H;
        H = __expf(SS[si] * A) * H + hl;
    }
}

// ---------------------------------------------------------------------------
// Phase 3: rerun each chunk from its entry state (now in HL), compute y,
// add u*D, gate with silu(z), write bf16 TRANSPOSED [n][d]; backward branch
// stores at pre-reversed positions so K6 reads both buffers identically.
// ---------------------------------------------------------------------------
__global__ __launch_bounds__(256)
void scan_part3(const float* __restrict__ xz,
                const float* __restrict__ xcf, const float* __restrict__ xcb,
                const float* __restrict__ xdf, const float* __restrict__ xdb,
                const float* __restrict__ dlf, const float* __restrict__ dlb,
                const float* __restrict__ HIN,
                __bf16* __restrict__ ygtf, __bf16* __restrict__ ygtb,
                const float* __restrict__ Alog_f, const float* __restrict__ Alog_b,
                const float* __restrict__ Df, const float* __restrict__ Db)
{
    const int d  = blockIdx.x * 256 + threadIdx.x;
    const int c  = blockIdx.y;
    const int bb = blockIdx.z;
    const int b  = bb & 1;
    const int br = bb >> 1;

    const float* xc   = br ? xcb : xcf;
    const float* xdbl = br ? xdb : xdf;
    const float* dl   = br ? dlb : dlf;
    const float* Alog = br ? Alog_b : Alog_f;
    const float* Dv   = br ? Db : Df;
    __bf16*      ygt  = br ? ygtb : ygtf;

    float Arow[NST], h[NST];
#pragma unroll
    for (int n = 0; n < NST; ++n) {
        Arow[n] = -__expf(Alog[d * NST + n]);
        h[n] = HIN[(((size_t)bb * NCH + c) * NST + n) * DI + d];
    }
    const float Dp = Dv[d];

    const size_t base = (size_t)b * L_SEQ;
    const float* drow = dl + (size_t)d * NTOT + base;
    const float* urow = xc + (size_t)d * NTOT + base;
    const float* zrow = xz + (size_t)(DI + d) * NTOT + base;
    const float* bc   = xdbl + (size_t)DTR * NTOT + base;

    const int t0 = c * CHT;
    for (int t = t0; t < t0 + CHT; t += 4) {
        float4 d4 = *(const float4*)(drow + t);
        float4 u4 = *(const float4*)(urow + t);
        float dlt[4] = { d4.x, d4.y, d4.z, d4.w };
        float du[4]  = { d4.x * u4.x, d4.y * u4.y, d4.z * u4.z, d4.w * u4.w };
        float y0 = 0.f, y1 = 0.f, y2 = 0.f, y3 = 0.f;
#pragma unroll
        for (int n = 0; n < NST; ++n) {
            float4 Bn = *(const float4*)(bc + (size_t)n * NTOT + t);
            float4 Cn = *(const float4*)(bc + (size_t)(NST + n) * NTOT + t);
            float hn = h[n];
            float An = Arow[n];
            hn = hn * __expf(dlt[0] * An) + du[0] * Bn.x;  y0 = fmaf(hn, Cn.x, y0);
            hn = hn * __expf(dlt[1] * An) + du[1] * Bn.y;  y1 = fmaf(hn, Cn.y, y1);
            hn = hn * __expf(dlt[2] * An) + du[2] * Bn.z;  y2 = fmaf(hn, Cn.z, y2);
            hn = hn * __expf(dlt[3] * An) + du[3] * Bn.w;  y3 = fmaf(hn, Cn.w, y3);
            h[n] = hn;
        }
        float zv[4];
        if (br == 0) {
            float4 z4 = *(const float4*)(zrow + t);
            zv[0] = z4.x; zv[1] = z4.y; zv[2] = z4.z; zv[3] = z4.w;
        } else {
            float4 z4 = *(const float4*)(zrow + (L_SEQ - 4 - t));
            zv[0] = z4.w; zv[1] = z4.z; zv[2] = z4.y; zv[3] = z4.x;
        }
        y0 = (y0 + u4.x * Dp) * silu_f(zv[0]);
        y1 = (y1 + u4.y * Dp) * silu_f(zv[1]);
        y2 = (y2 + u4.z * Dp) * silu_f(zv[2]);
        y3 = (y3 + u4.w * Dp) * silu_f(zv[3]);
        if (br == 0) {
            size_t p = (base + (size_t)t) * DI + d;      // n = b*L + t
            ygt[p]          = (__bf16)y0;
            ygt[p + DI]     = (__bf16)y1;
            ygt[p + 2 * DI] = (__bf16)y2;
            ygt[p + 3 * DI] = (__bf16)y3;
        } else {
            size_t p = (base + (size_t)(L_SEQ - 1 - t)) * DI + d;
            ygt[p]          = (__bf16)y0;
            ygt[p - DI]     = (__bf16)y1;
            ygt[p - 2 * DI] = (__bf16)y2;
            ygt[p - 3 * DI] = (__bf16)y3;
        }
    }
}

extern "C" void kernel_launch(void* const* d_in, const int* in_sizes, int n_in,
                              void* d_out, int out_size, void* d_ws, size_t ws_size,
                              hipStream_t stream)
{
    const float* hid     = (const float*)d_in[0];
    const float* inw     = (const float*)d_in[1];
    const float* convw   = (const float*)d_in[2];
    const float* convb   = (const float*)d_in[3];
    const float* xpw     = (const float*)d_in[4];
    const float* dtw     = (const float*)d_in[5];
    const float* dtb     = (const float*)d_in[6];
    const float* Alog    = (const float*)d_in[7];
    const float* Dv      = (const float*)d_in[8];
    const float* convw_b = (const float*)d_in[9];
    const float* convb_b = (const float*)d_in[10];
    const float* xpw_b   = (const float*)d_in[11];
    const float* dtw_b   = (const float*)d_in[12];
    const float* dtb_b   = (const float*)d_in[13];
    const float* Alog_b  = (const float*)d_in[14];
    const float* Dv_b    = (const float*)d_in[15];
    const float* outw    = (const float*)d_in[16];
    float* out = (float*)d_out;
    float* ws  = (float*)d_ws;

    // diagnostic guard: undersized workspace -> clean absmax failure, not a fault
    if (ws_size < WS_FLOATS * sizeof(float)) return;

    float*  XZ   = ws + OFF_XZ;
    float*  XCF  = ws + OFF_XCF;
    float*  XCB  = ws + OFF_XCB;
    float*  DLB  = ws + OFF_DLB;
    float*  XDF  = ws + OFF_XDF;
    float*  XDB  = ws + OFF_XDB;
    float*  SS   = ws + OFF_SS;
    float*  HLb  = ws + OFF_HL;
    __bf16* YGTF = (__bf16*)(ws + OFF_YGTF);
    __bf16* YGTB = (__bf16*)(ws + OFF_YGTB);
    float*  DLF  = XZ;   // overwrites dead x-half of xz (rows 0..DI-1)

    // zero split-K atomic targets: XDF+XDB contiguous
    hipMemsetAsync(XDF, 0, 2 * (size_t)RTOT * NTOT * sizeof(float), stream);

    dim3 blk(256);
    // K1: xz = in_proj_w @ hidden^T  (bf16 MFMA; A=inw [4096][1024], B=hid [4096][1024])
    gemm_mfma<false, false><<<dim3(32, 32), blk, 0, stream>>>(
        inw, hid, nullptr, nullptr, XZ, ETOT, NTOT, DM);
    // K2: conv + silu both directions
    conv_k<<<dim3(32, 64, 1), blk, 0, stream>>>(XZ, convw, convb, convw_b, convb_b, XCF, XCB);
    // K3: x_dbl = x_proj_w @ xc   (fp32, split-K=8, atomic)
    gemm_k<false, true><<<dim3(32, 1, 8), blk, 0, stream>>>(
        xpw, XCF, XDF, RTOT, NTOT, DI, 0, DI, nullptr);
    gemm_k<false, true><<<dim3(32, 1, 8), blk, 0, stream>>>(
        xpw_b, XCB, XDB, RTOT, NTOT, DI, 0, DI, nullptr);
    // K4: delta = softplus(dt_proj_w @ dt_r + bias); fwd result into dead x-half of XZ
    gemm_k<true, false><<<dim3(32, 16, 1), blk, 0, stream>>>(
        dtw, XDF, DLF, DI, NTOT, DTR, 0, DTR, dtb);
    gemm_k<true, false><<<dim3(32, 16, 1), blk, 0, stream>>>(
        dtw_b, XDB, DLB, DI, NTOT, DTR, 0, DTR, dtb_b);
    // K5: chunked parallel scan (3 phases); part3 emits bf16 transposed y
    scan_part1<<<dim3(DI / 256, NCH, 4), blk, 0, stream>>>(
        XCF, XCB, XDF, XDB, DLF, DLB, Alog, Alog_b, SS, HLb);
    scan_part2<<<dim3(DI / 256, NST, 4), blk, 0, stream>>>(
        SS, HLb, Alog, Alog_b);
    scan_part3<<<dim3(DI / 256, NCH, 4), blk, 0, stream>>>(
        XZ, XCF, XCB, XDF, XDB, DLF, DLB, HLb, YGTF, YGTB, Alog, Alog_b, Dv, Dv_b);
    // K6: out[n][m] = out_proj_w @ (ygt_f + ygt_b)  (bf16 MFMA, trans store)
    gemm_mfma<true, true><<<dim3(32, 8), blk, 0, stream>>>(
        outw, nullptr, YGTF, YGTB, out, DM, NTOT, DI);

    (void)in_sizes; (void)n_in; (void)out_size;
}

// Round 6
// 944.324 us; speedup vs baseline: 2.7961x; 1.0898x over previous
//
#include <hip/hip_runtime.h>
#include <hip/hip_bf16.h>
#include <math.h>

// ---------------------------------------------------------------------------
// Bidirectional Mamba (bimamba v2), B=2, L=2048, D_MODEL=1024, D_INNER=2048,
// D_STATE=16, DT_RANK=64, D_CONV=4.
//
// Layouts: scan-facing activations are [n][d] (d contiguous, n = b*L + t in
// scan order for u/delta; natural order for z). x (conv input) is [d][n];
// x_dbl is [r][n].
//   K1  mfma  : x[d][n] + zt[n][d]  = in_proj_w @ hidden^T  (SPLITZ epilogue)
//   K2  conv  : xcf/xcb[n][d]       = silu(causal dwconv(x)), LDS transpose
//   K3  gemm  : x_dbl[96][n]        = x_proj_w @ xc^T  (fp32, B=[N][K], split-K)
//   K4  gemm  : dlt[n][d]           = softplus(dt_proj @ dt_r + bias)^T
//               (forward dlt overwrites the dead x buffer)
//   K5  scan  : 3-phase chunked scan (32 chunks x 64); all streams coalesced
//               (lane -> d); part3 emits bf16 y [n][d], bwd pre-reversed
//   K6  mfma  : out[n][m] = out_proj_w @ (ygt_f + ygt_b)
//
// Workspace: 55,574,528 floats = 212.0 MiB.
// ---------------------------------------------------------------------------

#define L_SEQ  2048
#define B_SZ   2
#define DM     1024
#define DI     2048
#define NST    16
#define RTOT   96
#define DTR    64
#define NTOT   (B_SZ * L_SEQ)   // 4096
#define ETOT   (2 * DI)         // 4096
#define NCH    32               // scan chunks
#define CHT    (L_SEQ / NCH)    // 64 steps per chunk

// workspace offsets (in floats)
#define OFF_X    ((size_t)0)                        // [DI][NTOT] x; later DLTF [NTOT][DI]
#define OFF_ZT   (OFF_X   + (size_t)DI * NTOT)      // [NTOT][DI] z transposed
#define OFF_XCF  (OFF_ZT  + (size_t)DI * NTOT)      // [NTOT][DI] u fwd (scan order)
#define OFF_XCB  (OFF_XCF + (size_t)DI * NTOT)      // [NTOT][DI] u bwd (scan order)
#define OFF_DLTB (OFF_XCB + (size_t)DI * NTOT)      // [NTOT][DI] delta bwd
#define OFF_XDF  (OFF_DLTB + (size_t)DI * NTOT)     // [96][NTOT]
#define OFF_XDB  (OFF_XDF + (size_t)RTOT * NTOT)
#define OFF_SS   (OFF_XDB + (size_t)RTOT * NTOT)    // [4][NCH][DI]
#define OFF_HL   (OFF_SS  + (size_t)4 * NCH * DI)   // [4][NCH][NST][DI] local h -> Hin
#define OFF_YGTF (OFF_HL  + (size_t)4 * NCH * NST * DI)   // bf16 [NTOT][DI]
#define OFF_YGTB (OFF_YGTF + (size_t)NTOT * DI / 2)
#define WS_FLOATS (OFF_YGTB + (size_t)NTOT * DI / 2)      // 55,574,528

typedef __bf16 bf16x8 __attribute__((ext_vector_type(8)));
typedef float  floatx4 __attribute__((ext_vector_type(4)));
#define LDK 40   // MFMA LDS row stride in bf16 (32 + 8 pad)

__device__ __forceinline__ float silu_f(float x) {
    return x / (1.f + __expf(-x));
}

// ---------------------------------------------------------------------------
// bf16 MFMA GEMM: C = A[M][K] @ B[N][K]^T (fp32 out).
// DUALB: B = B1 + B2 (bf16). TRANS: C stored [N][M].
// SPLITZ: rows gm<DI -> C[d][n]; rows gm>=DI -> C2[(n)][gm-DI] (transposed).
// 128x128 tile, 4 waves, 16x16x32 MFMA, BK=32.
// ---------------------------------------------------------------------------
template<bool DUALB, bool TRANS, bool SPLITZ>
__global__ __launch_bounds__(256)
void gemm_mfma(const float* __restrict__ A, const float* __restrict__ Bf,
               const __bf16* __restrict__ B1, const __bf16* __restrict__ B2,
               float* __restrict__ C, float* __restrict__ C2,
               int M, int N, int K)
{
    __shared__ __bf16 As[128 * LDK];
    __shared__ __bf16 Bs[128 * LDK];
    const int tid  = threadIdx.x;
    const int m0   = blockIdx.y * 128;
    const int n0   = blockIdx.x * 128;
    const int lane = tid & 63;
    const int wave = tid >> 6;
    const int wy   = wave >> 1, wx = wave & 1;
    const int lr   = lane & 15;
    const int q    = lane >> 4;

    floatx4 acc[4][4];
#pragma unroll
    for (int i = 0; i < 4; ++i)
#pragma unroll
        for (int j = 0; j < 4; ++j) acc[i][j] = (floatx4)(0.0f);

    const int srow = tid >> 1;
    const int kh   = (tid & 1) * 16;
    const float* ga = A + (size_t)(m0 + srow) * K + kh;
    __bf16* wa = &As[srow * LDK + kh];
    __bf16* wb = &Bs[srow * LDK + kh];

    for (int k0 = 0; k0 < K; k0 += 32) {
        {
            float4 a0 = *(const float4*)(ga + k0);
            float4 a1 = *(const float4*)(ga + k0 + 4);
            float4 a2 = *(const float4*)(ga + k0 + 8);
            float4 a3 = *(const float4*)(ga + k0 + 12);
            bf16x8 p0, p1;
            p0[0]=(__bf16)a0.x; p0[1]=(__bf16)a0.y; p0[2]=(__bf16)a0.z; p0[3]=(__bf16)a0.w;
            p0[4]=(__bf16)a1.x; p0[5]=(__bf16)a1.y; p0[6]=(__bf16)a1.z; p0[7]=(__bf16)a1.w;
            p1[0]=(__bf16)a2.x; p1[1]=(__bf16)a2.y; p1[2]=(__bf16)a2.z; p1[3]=(__bf16)a2.w;
            p1[4]=(__bf16)a3.x; p1[5]=(__bf16)a3.y; p1[6]=(__bf16)a3.z; p1[7]=(__bf16)a3.w;
            *(bf16x8*)wa = p0; *(bf16x8*)(wa + 8) = p1;
        }
        if constexpr (DUALB) {
            const __bf16* gb1 = B1 + (size_t)(n0 + srow) * K + kh + k0;
            const __bf16* gb2 = B2 + (size_t)(n0 + srow) * K + kh + k0;
            bf16x8 u0 = *(const bf16x8*)gb1;
            bf16x8 u1 = *(const bf16x8*)(gb1 + 8);
            bf16x8 v0 = *(const bf16x8*)gb2;
            bf16x8 v1 = *(const bf16x8*)(gb2 + 8);
            bf16x8 s0, s1;
#pragma unroll
            for (int e = 0; e < 8; ++e) {
                s0[e] = (__bf16)((float)u0[e] + (float)v0[e]);
                s1[e] = (__bf16)((float)u1[e] + (float)v1[e]);
            }
            *(bf16x8*)wb = s0; *(bf16x8*)(wb + 8) = s1;
        } else {
            const float* gb = Bf + (size_t)(n0 + srow) * K + kh + k0;
            float4 b0 = *(const float4*)(gb);
            float4 b1v = *(const float4*)(gb + 4);
            float4 b2v = *(const float4*)(gb + 8);
            float4 b3 = *(const float4*)(gb + 12);
            bf16x8 p0, p1;
            p0[0]=(__bf16)b0.x; p0[1]=(__bf16)b0.y; p0[2]=(__bf16)b0.z; p0[3]=(__bf16)b0.w;
            p0[4]=(__bf16)b1v.x; p0[5]=(__bf16)b1v.y; p0[6]=(__bf16)b1v.z; p0[7]=(__bf16)b1v.w;
            p1[0]=(__bf16)b2v.x; p1[1]=(__bf16)b2v.y; p1[2]=(__bf16)b2v.z; p1[3]=(__bf16)b2v.w;
            p1[4]=(__bf16)b3.x; p1[5]=(__bf16)b3.y; p1[6]=(__bf16)b3.z; p1[7]=(__bf16)b3.w;
            *(bf16x8*)wb = p0; *(bf16x8*)(wb + 8) = p1;
        }
        __syncthreads();

        bf16x8 af[4], bfr[4];
#pragma unroll
        for (int i = 0; i < 4; ++i)
            af[i] = *(const bf16x8*)&As[(wy * 64 + i * 16 + lr) * LDK + q * 8];
#pragma unroll
        for (int j = 0; j < 4; ++j)
            bfr[j] = *(const bf16x8*)&Bs[(wx * 64 + j * 16 + lr) * LDK + q * 8];
#pragma unroll
        for (int i = 0; i < 4; ++i)
#pragma unroll
            for (int j = 0; j < 4; ++j)
                acc[i][j] = __builtin_amdgcn_mfma_f32_16x16x32_bf16(
                    af[i], bfr[j], acc[i][j], 0, 0, 0);
        __syncthreads();
    }

    const int mb = m0 + wy * 64;
    const int nb = n0 + wx * 64;
#pragma unroll
    for (int i = 0; i < 4; ++i) {
#pragma unroll
        for (int r = 0; r < 4; ++r) {
            int gm = mb + i * 16 + q * 4 + r;
#pragma unroll
            for (int j = 0; j < 4; ++j) {
                int gn = nb + j * 16 + lr;
                float val = acc[i][j][r];
                if constexpr (SPLITZ) {
                    if (m0 < DI) C[(size_t)gm * N + gn] = val;           // x [d][n]
                    else         C2[(size_t)gn * DI + (gm - DI)] = val;  // z [n][d]
                } else if constexpr (TRANS) {
                    C[(size_t)gn * M + gm] = val;
                } else {
                    C[(size_t)gm * N + gn] = val;
                }
            }
        }
    }
}

// ---------------------------------------------------------------------------
// fp32 SIMT GEMM 128x128, KT=16. A[M][K].
// B_NK: B is [N][K] (k contiguous) else [K][N] (n contiguous).
// TRANS: C stored [N][M] (with optional softplus). ATOMIC: split-K atomicAdd.
// ---------------------------------------------------------------------------
template<bool B_NK, bool TRANS, bool SOFTPLUS, bool ATOMIC>
__global__ __launch_bounds__(256)
void gemm_k(const float* __restrict__ A, const float* __restrict__ Bm,
            float* __restrict__ C,
            int M, int N, int K, int kbeg, int kend,
            const float* __restrict__ bias)
{
    __shared__ float As[16][132];
    __shared__ float Bs[16][132];
    const int tid = threadIdx.x;
    const int n0 = blockIdx.x * 128;
    const int m0 = blockIdx.y * 128;
    if constexpr (ATOMIC) {
        int ksz = (kend - kbeg) / (int)gridDim.z;
        kbeg += blockIdx.z * ksz;
        kend = kbeg + ksz;
    }
    const int tx = tid & 15, ty = tid >> 4;

    float acc[8][8];
#pragma unroll
    for (int i = 0; i < 8; ++i)
#pragma unroll
        for (int j = 0; j < 8; ++j) acc[i][j] = 0.f;

    for (int k0 = kbeg; k0 < kend; k0 += 16) {
#pragma unroll
        for (int it = 0; it < 2; ++it) {
            int i = tid + it * 256;
            int m = i >> 2, kq = i & 3;
            float4 v = make_float4(0.f, 0.f, 0.f, 0.f);
            int gm = m0 + m;
            if (gm < M) v = *(const float4*)(A + (size_t)gm * K + (k0 + kq * 4));
            As[kq * 4 + 0][m] = v.x; As[kq * 4 + 1][m] = v.y;
            As[kq * 4 + 2][m] = v.z; As[kq * 4 + 3][m] = v.w;
        }
        if constexpr (B_NK) {
#pragma unroll
            for (int it = 0; it < 2; ++it) {
                int i = tid + it * 256;
                int n = i >> 2, kq = i & 3;
                float4 v = *(const float4*)(Bm + (size_t)(n0 + n) * K + (k0 + kq * 4));
                Bs[kq * 4 + 0][n] = v.x; Bs[kq * 4 + 1][n] = v.y;
                Bs[kq * 4 + 2][n] = v.z; Bs[kq * 4 + 3][n] = v.w;
            }
        } else {
#pragma unroll
            for (int it = 0; it < 2; ++it) {
                int i = tid + it * 256;
                int k = i >> 5, nq = i & 31;
                float4 v = *(const float4*)(Bm + (size_t)(k0 + k) * N + n0 + nq * 4);
                *(float4*)&Bs[k][nq * 4] = v;
            }
        }
        __syncthreads();
#pragma unroll
        for (int kk = 0; kk < 16; ++kk) {
            float av[8], bv[8];
            *(float4*)&av[0] = *(const float4*)&As[kk][ty * 8];
            *(float4*)&av[4] = *(const float4*)&As[kk][ty * 8 + 4];
            *(float4*)&bv[0] = *(const float4*)&Bs[kk][tx * 8];
            *(float4*)&bv[4] = *(const float4*)&Bs[kk][tx * 8 + 4];
#pragma unroll
            for (int i = 0; i < 8; ++i)
#pragma unroll
                for (int j = 0; j < 8; ++j)
                    acc[i][j] = fmaf(av[i], bv[j], acc[i][j]);
        }
        __syncthreads();
    }

    if constexpr (TRANS) {
#pragma unroll
        for (int j = 0; j < 8; ++j) {
            int gn = n0 + tx * 8 + j;
            float o[8];
#pragma unroll
            for (int i = 0; i < 8; ++i) {
                float x = acc[i][j];
                if constexpr (SOFTPLUS) {
                    x += bias[m0 + ty * 8 + i];
                    x = (x > 20.f) ? x : log1pf(expf(x));
                }
                o[i] = x;
            }
            *(float4*)(C + (size_t)gn * M + m0 + ty * 8)     = make_float4(o[0], o[1], o[2], o[3]);
            *(float4*)(C + (size_t)gn * M + m0 + ty * 8 + 4) = make_float4(o[4], o[5], o[6], o[7]);
        }
    } else {
#pragma unroll
        for (int i = 0; i < 8; ++i) {
            int gm = m0 + ty * 8 + i;
            if (gm < M) {
                float* cp = C + (size_t)gm * N + n0 + tx * 8;
                if constexpr (ATOMIC) {
#pragma unroll
                    for (int j = 0; j < 8; ++j) atomicAdd(cp + j, acc[i][j]);
                } else {
                    *(float4*)cp       = make_float4(acc[i][0], acc[i][1], acc[i][2], acc[i][3]);
                    *(float4*)(cp + 4) = make_float4(acc[i][4], acc[i][5], acc[i][6], acc[i][7]);
                }
            }
        }
    }
}

// ---------------------------------------------------------------------------
// Causal depthwise conv (K=4) + silu, both directions. Input x [d][n];
// outputs xcf/xcb [n_scan][d] (coalesced: lane -> d). LDS transpose tile.
// ---------------------------------------------------------------------------
__global__ __launch_bounds__(256)
void conv_k(const float* __restrict__ x,
            const float* __restrict__ wf, const float* __restrict__ bf,
            const float* __restrict__ wb, const float* __restrict__ bb,
            float* __restrict__ xcf, float* __restrict__ xcb)
{
    __shared__ float xs[70 * 65];            // [l-halo][d], pad 65
    const int tid = threadIdx.x;
    const int d0 = blockIdx.x * 64;
    const int n0 = blockIdx.y * 64;
    const int b  = n0 >> 11;
    const int l0 = n0 & (L_SEQ - 1);
    const size_t bbase = (size_t)b << 11;

    for (int i = tid; i < 64 * 70; i += 256) {
        int r = i / 70, c = i % 70;          // r = d-off, c = l-off (l = l0-3+c)
        int l = l0 - 3 + c;
        float v = 0.f;
        if (l >= 0 && l < L_SEQ) v = x[(size_t)(d0 + r) * NTOT + bbase + l];
        xs[c * 65 + r] = v;
    }
    __syncthreads();

    const int dd = tid & 63;
    const int lq = tid >> 6;                 // 0..3
    const int d  = d0 + dd;
    const float w0 = wf[d * 4 + 0], w1 = wf[d * 4 + 1];
    const float w2 = wf[d * 4 + 2], w3 = wf[d * 4 + 3];
    const float v0 = wb[d * 4 + 0], v1 = wb[d * 4 + 1];
    const float v2 = wb[d * 4 + 2], v3 = wb[d * 4 + 3];
    const float bfv = bf[d], bbv = bb[d];

    for (int lr = 0; lr < 64; lr += 4) {
        const int lo = lr + lq;              // l-offset within tile
        const int l  = l0 + lo;
        float x0 = xs[(lo + 0) * 65 + dd];
        float x1 = xs[(lo + 1) * 65 + dd];
        float x2 = xs[(lo + 2) * 65 + dd];
        float x3 = xs[(lo + 3) * 65 + dd];
        float x4 = xs[(lo + 4) * 65 + dd];
        float x5 = xs[(lo + 5) * 65 + dd];
        float x6 = xs[(lo + 6) * 65 + dd];
        // fwd: out[l] = sum_k wf[k] * x[l-3+k]
        float xf = bfv + w0 * x0 + w1 * x1 + w2 * x2 + w3 * x3;
        xcf[((size_t)bbase + l) * DI + d] = silu_f(xf);
        // bwd (conv on reversed seq) at scan pos t = L-1-l: uses x[l..l+3]
        float xb = bbv + v3 * x3 + v2 * x4 + v1 * x5 + v0 * x6;
        xcb[((size_t)bbase + (L_SEQ - 1 - l)) * DI + d] = silu_f(xb);
    }
}

// ---------------------------------------------------------------------------
// Chunked scan phase 1: local scan per chunk (h0=0) + S = sum(delta).
// delta/u are [n][d] (coalesced); B rows are [r][n] (wave-broadcast float4).
// ---------------------------------------------------------------------------
__global__ __launch_bounds__(256)
void scan_part1(const float* __restrict__ xcf, const float* __restrict__ xcb,
                const float* __restrict__ xdf, const float* __restrict__ xdb,
                const float* __restrict__ dltf, const float* __restrict__ dltb,
                const float* __restrict__ Alog_f, const float* __restrict__ Alog_b,
                float* __restrict__ SS, float* __restrict__ HL)
{
    const int d  = blockIdx.x * 256 + threadIdx.x;
    const int c  = blockIdx.y;
    const int bb = blockIdx.z;
    const int b  = bb & 1;
    const int br = bb >> 1;

    const float* u    = br ? xcb : xcf;
    const float* dl   = br ? dltb : dltf;
    const float* xd   = br ? xdb : xdf;
    const float* Alog = br ? Alog_b : Alog_f;

    float Arow[NST], h[NST];
#pragma unroll
    for (int n = 0; n < NST; ++n) {
        Arow[n] = -__expf(Alog[d * NST + n]);
        h[n] = 0.f;
    }
    float S = 0.f;

    const size_t nbase = (size_t)b * L_SEQ + (size_t)c * CHT;
    const float* up  = u  + nbase * DI + d;
    const float* dp  = dl + nbase * DI + d;
    const float* bcB = xd + (size_t)DTR * NTOT + nbase;

    for (int tr = 0; tr < CHT; tr += 4) {
        float dv[4], uv[4];
#pragma unroll
        for (int k = 0; k < 4; ++k) {
            dv[k] = dp[(size_t)(tr + k) * DI];
            uv[k] = up[(size_t)(tr + k) * DI];
        }
        S += (dv[0] + dv[1]) + (dv[2] + dv[3]);
        float du[4] = { dv[0]*uv[0], dv[1]*uv[1], dv[2]*uv[2], dv[3]*uv[3] };
#pragma unroll
        for (int n = 0; n < NST; ++n) {
            float4 Bn = *(const float4*)(bcB + (size_t)n * NTOT + tr);
            float hn = h[n];
            float An = Arow[n];
            hn = hn * __expf(dv[0] * An) + du[0] * Bn.x;
            hn = hn * __expf(dv[1] * An) + du[1] * Bn.y;
            hn = hn * __expf(dv[2] * An) + du[2] * Bn.z;
            hn = hn * __expf(dv[3] * An) + du[3] * Bn.w;
            h[n] = hn;
        }
    }
    SS[((size_t)bb * NCH + c) * DI + d] = S;
#pragma unroll
    for (int n = 0; n < NST; ++n)
        HL[(((size_t)bb * NCH + c) * NST + n) * DI + d] = h[n];
}

// ---------------------------------------------------------------------------
// Phase 2 (in place): HL[c] replaced by chunk ENTRY state Hin[c].
// ---------------------------------------------------------------------------
__global__ __launch_bounds__(256)
void scan_part2(const float* __restrict__ SS, float* HL,
                const float* __restrict__ Alog_f, const float* __restrict__ Alog_b)
{
    const int d  = blockIdx.x * 256 + threadIdx.x;
    const int n  = blockIdx.y;
    const int bb = blockIdx.z;
    const int br = bb >> 1;
    const float* Alog = br ? Alog_b : Alog_f;
    const float A = -__expf(Alog[d * NST + n]);

    float H = 0.f;
#pragma unroll
    for (int c = 0; c < NCH; ++c) {
        const size_t si = ((size_t)bb * NCH + c) * DI + d;
        const size_t hi = (((size_t)bb * NCH + c) * NST + n) * DI + d;
        float hl = HL[hi];
        HL[hi] = H;
        H = __expf(SS[si] * A) * H + hl;
    }
}

// ---------------------------------------------------------------------------
// Phase 3: rerun chunk from entry state, y = C.h + u*D, gate silu(z),
// write bf16 [n][d] (bwd at pre-reversed n). All streams coalesced.
// ---------------------------------------------------------------------------
__global__ __launch_bounds__(256)
void scan_part3(const float* __restrict__ zt,
                const float* __restrict__ xcf, const float* __restrict__ xcb,
                const float* __restrict__ xdf, const float* __restrict__ xdb,
                const float* __restrict__ dltf, const float* __restrict__ dltb,
                const float* __restrict__ HIN,
                __bf16* __restrict__ ygtf, __bf16* __restrict__ ygtb,
                const float* __restrict__ Alog_f, const float* __restrict__ Alog_b,
                const float* __restrict__ Df, const float* __restrict__ Db)
{
    const int d  = blockIdx.x * 256 + threadIdx.x;
    const int c  = blockIdx.y;
    const int bb = blockIdx.z;
    const int b  = bb & 1;
    const int br = bb >> 1;

    const float* u    = br ? xcb : xcf;
    const float* dl   = br ? dltb : dltf;
    const float* xd   = br ? xdb : xdf;
    const float* Alog = br ? Alog_b : Alog_f;
    const float* Dv   = br ? Db : Df;
    __bf16*      ygt  = br ? ygtb : ygtf;

    float Arow[NST], h[NST];
#pragma unroll
    for (int n = 0; n < NST; ++n) {
        Arow[n] = -__expf(Alog[d * NST + n]);
        h[n] = HIN[(((size_t)bb * NCH + c) * NST + n) * DI + d];
    }
    const float Dp = Dv[d];

    const size_t nbase = (size_t)b * L_SEQ + (size_t)c * CHT;   // scan order
    const float* up  = u  + nbase * DI + d;
    const float* dp  = dl + nbase * DI + d;
    const float* bcB = xd + (size_t)DTR * NTOT + nbase;
    // natural-order base for z / ygt-bwd: n_nat = b*L + (L-1 - (c*CHT + tr))
    const size_t bL = (size_t)b * L_SEQ;
    const int    t0 = c * CHT;

    for (int tr = 0; tr < CHT; tr += 4) {
        float dv[4], uv[4];
#pragma unroll
        for (int k = 0; k < 4; ++k) {
            dv[k] = dp[(size_t)(tr + k) * DI];
            uv[k] = up[(size_t)(tr + k) * DI];
        }
        float du[4] = { dv[0]*uv[0], dv[1]*uv[1], dv[2]*uv[2], dv[3]*uv[3] };
        float y[4] = { 0.f, 0.f, 0.f, 0.f };
#pragma unroll
        for (int n = 0; n < NST; ++n) {
            float4 Bn = *(const float4*)(bcB + (size_t)n * NTOT + tr);
            float4 Cn = *(const float4*)(bcB + (size_t)(NST + n) * NTOT + tr);
            float hn = h[n];
            float An = Arow[n];
            hn = hn * __expf(dv[0] * An) + du[0] * Bn.x;  y[0] = fmaf(hn, Cn.x, y[0]);
            hn = hn * __expf(dv[1] * An) + du[1] * Bn.y;  y[1] = fmaf(hn, Cn.y, y[1]);
            hn = hn * __expf(dv[2] * An) + du[2] * Bn.z;  y[2] = fmaf(hn, Cn.z, y[2]);
            hn = hn * __expf(dv[3] * An) + du[3] * Bn.w;  y[3] = fmaf(hn, Cn.w, y[3]);
            h[n] = hn;
        }
#pragma unroll
        for (int k = 0; k < 4; ++k) {
            int t = t0 + tr + k;
            size_t nn = br ? (bL + (L_SEQ - 1 - t)) : (bL + t);  // natural pos
            float zv = zt[nn * DI + d];
            float yo = (y[k] + uv[k] * Dp) * silu_f(zv);
            ygt[nn * DI + d] = (__bf16)yo;
        }
    }
}

extern "C" void kernel_launch(void* const* d_in, const int* in_sizes, int n_in,
                              void* d_out, int out_size, void* d_ws, size_t ws_size,
                              hipStream_t stream)
{
    const float* hid     = (const float*)d_in[0];
    const float* inw     = (const float*)d_in[1];
    const float* convw   = (const float*)d_in[2];
    const float* convb   = (const float*)d_in[3];
    const float* xpw     = (const float*)d_in[4];
    const float* dtw     = (const float*)d_in[5];
    const float* dtb     = (const float*)d_in[6];
    const float* Alog    = (const float*)d_in[7];
    const float* Dv      = (const float*)d_in[8];
    const float* convw_b = (const float*)d_in[9];
    const float* convb_b = (const float*)d_in[10];
    const float* xpw_b   = (const float*)d_in[11];
    const float* dtw_b   = (const float*)d_in[12];
    const float* dtb_b   = (const float*)d_in[13];
    const float* Alog_b  = (const float*)d_in[14];
    const float* Dv_b    = (const float*)d_in[15];
    const float* outw    = (const float*)d_in[16];
    float* out = (float*)d_out;
    float* ws  = (float*)d_ws;

    if (ws_size < WS_FLOATS * sizeof(float)) return;

    float*  X    = ws + OFF_X;
    float*  ZT   = ws + OFF_ZT;
    float*  XCF  = ws + OFF_XCF;
    float*  XCB  = ws + OFF_XCB;
    float*  DLTB = ws + OFF_DLTB;
    float*  XDF  = ws + OFF_XDF;
    float*  XDB  = ws + OFF_XDB;
    float*  SS   = ws + OFF_SS;
    float*  HLb  = ws + OFF_HL;
    __bf16* YGTF = (__bf16*)(ws + OFF_YGTF);
    __bf16* YGTB = (__bf16*)(ws + OFF_YGTB);
    float*  DLTF = X;   // overwrites dead x after conv

    hipMemsetAsync(XDF, 0, 2 * (size_t)RTOT * NTOT * sizeof(float), stream);

    dim3 blk(256);
    // K1: x[d][n] (rows<DI) + zt[n][d] (rows>=DI) = in_proj_w @ hidden^T
    gemm_mfma<false, false, true><<<dim3(32, 32), blk, 0, stream>>>(
        inw, hid, nullptr, nullptr, X, ZT, ETOT, NTOT, DM);
    // K2: conv + silu both directions -> [n][d]
    conv_k<<<dim3(32, 64), blk, 0, stream>>>(X, convw, convb, convw_b, convb_b, XCF, XCB);
    // K3: x_dbl[r][n] = x_proj_w @ xc^T  (B = xc [N][K] k-contig, split-K=8)
    gemm_k<true, false, false, true><<<dim3(32, 1, 8), blk, 0, stream>>>(
        xpw, XCF, XDF, RTOT, NTOT, DI, 0, DI, nullptr);
    gemm_k<true, false, false, true><<<dim3(32, 1, 8), blk, 0, stream>>>(
        xpw_b, XCB, XDB, RTOT, NTOT, DI, 0, DI, nullptr);
    // K4: dlt[n][d] = softplus(dt_proj @ dt_r + bias)^T; fwd over dead X
    gemm_k<false, true, true, false><<<dim3(32, 16), blk, 0, stream>>>(
        dtw, XDF, DLTF, DI, NTOT, DTR, 0, DTR, dtb);
    gemm_k<false, true, true, false><<<dim3(32, 16), blk, 0, stream>>>(
        dtw_b, XDB, DLTB, DI, NTOT, DTR, 0, DTR, dtb_b);
    // K5: chunked parallel scan
    scan_part1<<<dim3(DI / 256, NCH, 4), blk, 0, stream>>>(
        XCF, XCB, XDF, XDB, DLTF, DLTB, Alog, Alog_b, SS, HLb);
    scan_part2<<<dim3(DI / 256, NST, 4), blk, 0, stream>>>(
        SS, HLb, Alog, Alog_b);
    scan_part3<<<dim3(DI / 256, NCH, 4), blk, 0, stream>>>(
        ZT, XCF, XCB, XDF, XDB, DLTF, DLTB, HLb, YGTF, YGTB, Alog, Alog_b, Dv, Dv_b);
    // K6: out[n][m] = out_proj_w @ (ygt_f + ygt_b)
    gemm_mfma<true, true, false><<<dim3(32, 8), blk, 0, stream>>>(
        outw, nullptr, YGTF, YGTB, out, nullptr, DM, NTOT, DI);

    (void)in_sizes; (void)n_in; (void)out_size;
}

// Round 7
// 790.964 us; speedup vs baseline: 3.3382x; 1.1939x over previous
//
#include <hip/hip_runtime.h>
#include <hip/hip_bf16.h>
#include <math.h>

// ---------------------------------------------------------------------------
// Bidirectional Mamba (bimamba v2), B=2, L=2048, D_MODEL=1024, D_INNER=2048,
// D_STATE=16, DT_RANK=64, D_CONV=4.
//
// Layouts: scan-facing activations are [n][d] (d contiguous, n = b*L + t in
// scan order for u/delta; natural order for z). x (conv input) is [d][n];
// x_dbl is [r][n].
//   K1  mfma  : x[d][n] + zt[n][d]  = in_proj_w @ hidden^T  (SPLITZ epilogue)
//   K2  conv  : xcf/xcb[n][d]       = silu(causal dwconv(x)), LDS transpose
//   K3  gemm  : P[z][96][n] partials = x_proj_w @ xc^T  (split-K=8, plain
//               stores into scratch; NO atomics), then reduce8_k sums z.
//   K4  gemm  : dlt[n][d]           = softplus(dt_proj @ dt_r + bias)^T
//               (forward dlt overwrites the dead x buffer)
//   K5  scan  : 3-phase chunked scan (32 chunks x 64); all streams coalesced
//   K6  mfma  : out[n][m] = out_proj_w @ (ygt_f + ygt_b)
//
// Workspace: 55,574,528 floats = 212.0 MiB. Split-K partials live in the
// YGTF/YGTB regions (dead until scan_part3, reduced immediately after K3).
// ---------------------------------------------------------------------------

#define L_SEQ  2048
#define B_SZ   2
#define DM     1024
#define DI     2048
#define NST    16
#define RTOT   96
#define DTR    64
#define NTOT   (B_SZ * L_SEQ)   // 4096
#define ETOT   (2 * DI)         // 4096
#define NCH    32               // scan chunks
#define CHT    (L_SEQ / NCH)    // 64 steps per chunk
#define SPLK   8                // K3 split-K factor

// workspace offsets (in floats)
#define OFF_X    ((size_t)0)                        // [DI][NTOT] x; later DLTF [NTOT][DI]
#define OFF_ZT   (OFF_X   + (size_t)DI * NTOT)      // [NTOT][DI] z transposed
#define OFF_XCF  (OFF_ZT  + (size_t)DI * NTOT)      // [NTOT][DI] u fwd (scan order)
#define OFF_XCB  (OFF_XCF + (size_t)DI * NTOT)      // [NTOT][DI] u bwd (scan order)
#define OFF_DLTB (OFF_XCB + (size_t)DI * NTOT)      // [NTOT][DI] delta bwd
#define OFF_XDF  (OFF_DLTB + (size_t)DI * NTOT)     // [96][NTOT]
#define OFF_XDB  (OFF_XDF + (size_t)RTOT * NTOT)
#define OFF_SS   (OFF_XDB + (size_t)RTOT * NTOT)    // [4][NCH][DI]
#define OFF_HL   (OFF_SS  + (size_t)4 * NCH * DI)   // [4][NCH][NST][DI] local h -> Hin
#define OFF_YGTF (OFF_HL  + (size_t)4 * NCH * NST * DI)   // bf16 [NTOT][DI]; K3 scratch
#define OFF_YGTB (OFF_YGTF + (size_t)NTOT * DI / 2)
#define WS_FLOATS (OFF_YGTB + (size_t)NTOT * DI / 2)      // 55,574,528

typedef __bf16 bf16x8 __attribute__((ext_vector_type(8)));
typedef float  floatx4 __attribute__((ext_vector_type(4)));
#define LDK 40   // MFMA LDS row stride in bf16 (32 + 8 pad)

__device__ __forceinline__ float silu_f(float x) {
    return x / (1.f + __expf(-x));
}

// ---------------------------------------------------------------------------
// bf16 MFMA GEMM: C = A[M][K] @ B[N][K]^T (fp32 out).
// DUALB: B = B1 + B2 (bf16). TRANS: C stored [N][M].
// SPLITZ: rows gm<DI -> C[d][n]; rows gm>=DI -> C2[(n)][gm-DI] (transposed).
// 128x128 tile, 4 waves, 16x16x32 MFMA, BK=32.
// ---------------------------------------------------------------------------
template<bool DUALB, bool TRANS, bool SPLITZ>
__global__ __launch_bounds__(256)
void gemm_mfma(const float* __restrict__ A, const float* __restrict__ Bf,
               const __bf16* __restrict__ B1, const __bf16* __restrict__ B2,
               float* __restrict__ C, float* __restrict__ C2,
               int M, int N, int K)
{
    __shared__ __bf16 As[128 * LDK];
    __shared__ __bf16 Bs[128 * LDK];
    const int tid  = threadIdx.x;
    const int m0   = blockIdx.y * 128;
    const int n0   = blockIdx.x * 128;
    const int lane = tid & 63;
    const int wave = tid >> 6;
    const int wy   = wave >> 1, wx = wave & 1;
    const int lr   = lane & 15;
    const int q    = lane >> 4;

    floatx4 acc[4][4];
#pragma unroll
    for (int i = 0; i < 4; ++i)
#pragma unroll
        for (int j = 0; j < 4; ++j) acc[i][j] = (floatx4)(0.0f);

    const int srow = tid >> 1;
    const int kh   = (tid & 1) * 16;
    const float* ga = A + (size_t)(m0 + srow) * K + kh;
    __bf16* wa = &As[srow * LDK + kh];
    __bf16* wb = &Bs[srow * LDK + kh];

    for (int k0 = 0; k0 < K; k0 += 32) {
        {
            float4 a0 = *(const float4*)(ga + k0);
            float4 a1 = *(const float4*)(ga + k0 + 4);
            float4 a2 = *(const float4*)(ga + k0 + 8);
            float4 a3 = *(const float4*)(ga + k0 + 12);
            bf16x8 p0, p1;
            p0[0]=(__bf16)a0.x; p0[1]=(__bf16)a0.y; p0[2]=(__bf16)a0.z; p0[3]=(__bf16)a0.w;
            p0[4]=(__bf16)a1.x; p0[5]=(__bf16)a1.y; p0[6]=(__bf16)a1.z; p0[7]=(__bf16)a1.w;
            p1[0]=(__bf16)a2.x; p1[1]=(__bf16)a2.y; p1[2]=(__bf16)a2.z; p1[3]=(__bf16)a2.w;
            p1[4]=(__bf16)a3.x; p1[5]=(__bf16)a3.y; p1[6]=(__bf16)a3.z; p1[7]=(__bf16)a3.w;
            *(bf16x8*)wa = p0; *(bf16x8*)(wa + 8) = p1;
        }
        if constexpr (DUALB) {
            const __bf16* gb1 = B1 + (size_t)(n0 + srow) * K + kh + k0;
            const __bf16* gb2 = B2 + (size_t)(n0 + srow) * K + kh + k0;
            bf16x8 u0 = *(const bf16x8*)gb1;
            bf16x8 u1 = *(const bf16x8*)(gb1 + 8);
            bf16x8 v0 = *(const bf16x8*)gb2;
            bf16x8 v1 = *(const bf16x8*)(gb2 + 8);
            bf16x8 s0, s1;
#pragma unroll
            for (int e = 0; e < 8; ++e) {
                s0[e] = (__bf16)((float)u0[e] + (float)v0[e]);
                s1[e] = (__bf16)((float)u1[e] + (float)v1[e]);
            }
            *(bf16x8*)wb = s0; *(bf16x8*)(wb + 8) = s1;
        } else {
            const float* gb = Bf + (size_t)(n0 + srow) * K + kh + k0;
            float4 b0 = *(const float4*)(gb);
            float4 b1v = *(const float4*)(gb + 4);
            float4 b2v = *(const float4*)(gb + 8);
            float4 b3 = *(const float4*)(gb + 12);
            bf16x8 p0, p1;
            p0[0]=(__bf16)b0.x; p0[1]=(__bf16)b0.y; p0[2]=(__bf16)b0.z; p0[3]=(__bf16)b0.w;
            p0[4]=(__bf16)b1v.x; p0[5]=(__bf16)b1v.y; p0[6]=(__bf16)b1v.z; p0[7]=(__bf16)b1v.w;
            p1[0]=(__bf16)b2v.x; p1[1]=(__bf16)b2v.y; p1[2]=(__bf16)b2v.z; p1[3]=(__bf16)b2v.w;
            p1[4]=(__bf16)b3.x; p1[5]=(__bf16)b3.y; p1[6]=(__bf16)b3.z; p1[7]=(__bf16)b3.w;
            *(bf16x8*)wb = p0; *(bf16x8*)(wb + 8) = p1;
        }
        __syncthreads();

        bf16x8 af[4], bfr[4];
#pragma unroll
        for (int i = 0; i < 4; ++i)
            af[i] = *(const bf16x8*)&As[(wy * 64 + i * 16 + lr) * LDK + q * 8];
#pragma unroll
        for (int j = 0; j < 4; ++j)
            bfr[j] = *(const bf16x8*)&Bs[(wx * 64 + j * 16 + lr) * LDK + q * 8];
#pragma unroll
        for (int i = 0; i < 4; ++i)
#pragma unroll
            for (int j = 0; j < 4; ++j)
                acc[i][j] = __builtin_amdgcn_mfma_f32_16x16x32_bf16(
                    af[i], bfr[j], acc[i][j], 0, 0, 0);
        __syncthreads();
    }

    const int mb = m0 + wy * 64;
    const int nb = n0 + wx * 64;
#pragma unroll
    for (int i = 0; i < 4; ++i) {
#pragma unroll
        for (int r = 0; r < 4; ++r) {
            int gm = mb + i * 16 + q * 4 + r;
#pragma unroll
            for (int j = 0; j < 4; ++j) {
                int gn = nb + j * 16 + lr;
                float val = acc[i][j][r];
                if constexpr (SPLITZ) {
                    if (m0 < DI) C[(size_t)gm * N + gn] = val;           // x [d][n]
                    else         C2[(size_t)gn * DI + (gm - DI)] = val;  // z [n][d]
                } else if constexpr (TRANS) {
                    C[(size_t)gn * M + gm] = val;
                } else {
                    C[(size_t)gm * N + gn] = val;
                }
            }
        }
    }
}

// ---------------------------------------------------------------------------
// fp32 SIMT GEMM 128x128, KT=16. A[M][K].
// B_NK: B is [N][K] (k contiguous) else [K][N] (n contiguous).
// TRANS: C stored [N][M] (with optional softplus).
// SPLITP: split-K over gridDim.z; each z writes plain stores into its own
//         partial slab C + z*M*N (reduced afterwards by reduce8_k).
// ---------------------------------------------------------------------------
template<bool B_NK, bool TRANS, bool SOFTPLUS, bool SPLITP>
__global__ __launch_bounds__(256)
void gemm_k(const float* __restrict__ A, const float* __restrict__ Bm,
            float* __restrict__ C,
            int M, int N, int K, int kbeg, int kend,
            const float* __restrict__ bias)
{
    __shared__ float As[16][132];
    __shared__ float Bs[16][132];
    const int tid = threadIdx.x;
    const int n0 = blockIdx.x * 128;
    const int m0 = blockIdx.y * 128;
    if constexpr (SPLITP) {
        int ksz = (kend - kbeg) / (int)gridDim.z;
        kbeg += blockIdx.z * ksz;
        kend = kbeg + ksz;
        C += (size_t)blockIdx.z * M * N;
    }
    const int tx = tid & 15, ty = tid >> 4;

    float acc[8][8];
#pragma unroll
    for (int i = 0; i < 8; ++i)
#pragma unroll
        for (int j = 0; j < 8; ++j) acc[i][j] = 0.f;

    for (int k0 = kbeg; k0 < kend; k0 += 16) {
#pragma unroll
        for (int it = 0; it < 2; ++it) {
            int i = tid + it * 256;
            int m = i >> 2, kq = i & 3;
            float4 v = make_float4(0.f, 0.f, 0.f, 0.f);
            int gm = m0 + m;
            if (gm < M) v = *(const float4*)(A + (size_t)gm * K + (k0 + kq * 4));
            As[kq * 4 + 0][m] = v.x; As[kq * 4 + 1][m] = v.y;
            As[kq * 4 + 2][m] = v.z; As[kq * 4 + 3][m] = v.w;
        }
        if constexpr (B_NK) {
#pragma unroll
            for (int it = 0; it < 2; ++it) {
                int i = tid + it * 256;
                int n = i >> 2, kq = i & 3;
                float4 v = *(const float4*)(Bm + (size_t)(n0 + n) * K + (k0 + kq * 4));
                Bs[kq * 4 + 0][n] = v.x; Bs[kq * 4 + 1][n] = v.y;
                Bs[kq * 4 + 2][n] = v.z; Bs[kq * 4 + 3][n] = v.w;
            }
        } else {
#pragma unroll
            for (int it = 0; it < 2; ++it) {
                int i = tid + it * 256;
                int k = i >> 5, nq = i & 31;
                float4 v = *(const float4*)(Bm + (size_t)(k0 + k) * N + n0 + nq * 4);
                *(float4*)&Bs[k][nq * 4] = v;
            }
        }
        __syncthreads();
#pragma unroll
        for (int kk = 0; kk < 16; ++kk) {
            float av[8], bv[8];
            *(float4*)&av[0] = *(const float4*)&As[kk][ty * 8];
            *(float4*)&av[4] = *(const float4*)&As[kk][ty * 8 + 4];
            *(float4*)&bv[0] = *(const float4*)&Bs[kk][tx * 8];
            *(float4*)&bv[4] = *(const float4*)&Bs[kk][tx * 8 + 4];
#pragma unroll
            for (int i = 0; i < 8; ++i)
#pragma unroll
                for (int j = 0; j < 8; ++j)
                    acc[i][j] = fmaf(av[i], bv[j], acc[i][j]);
        }
        __syncthreads();
    }

    if constexpr (TRANS) {
#pragma unroll
        for (int j = 0; j < 8; ++j) {
            int gn = n0 + tx * 8 + j;
            float o[8];
#pragma unroll
            for (int i = 0; i < 8; ++i) {
                float x = acc[i][j];
                if constexpr (SOFTPLUS) {
                    x += bias[m0 + ty * 8 + i];
                    x = (x > 20.f) ? x : log1pf(expf(x));
                }
                o[i] = x;
            }
            *(float4*)(C + (size_t)gn * M + m0 + ty * 8)     = make_float4(o[0], o[1], o[2], o[3]);
            *(float4*)(C + (size_t)gn * M + m0 + ty * 8 + 4) = make_float4(o[4], o[5], o[6], o[7]);
        }
    } else {
#pragma unroll
        for (int i = 0; i < 8; ++i) {
            int gm = m0 + ty * 8 + i;
            if (gm < M) {
                float* cp = C + (size_t)gm * N + n0 + tx * 8;
                *(float4*)cp       = make_float4(acc[i][0], acc[i][1], acc[i][2], acc[i][3]);
                *(float4*)(cp + 4) = make_float4(acc[i][4], acc[i][5], acc[i][6], acc[i][7]);
            }
        }
    }
}

// ---------------------------------------------------------------------------
// reduce8_k: out[i] = sum_{z<SPLK} P[z*stride + i], float4-vectorized.
// ---------------------------------------------------------------------------
__global__ __launch_bounds__(256)
void reduce8_k(const float* __restrict__ P, float* __restrict__ out, size_t stride)
{
    const size_t i4 = ((size_t)blockIdx.x * 256 + threadIdx.x) * 4;
    float4 s = *(const float4*)(P + i4);
#pragma unroll
    for (int z = 1; z < SPLK; ++z) {
        float4 v = *(const float4*)(P + (size_t)z * stride + i4);
        s.x += v.x; s.y += v.y; s.z += v.z; s.w += v.w;
    }
    *(float4*)(out + i4) = s;
}

// ---------------------------------------------------------------------------
// Causal depthwise conv (K=4) + silu, both directions. Input x [d][n];
// outputs xcf/xcb [n_scan][d] (coalesced: lane -> d). LDS transpose tile.
// ---------------------------------------------------------------------------
__global__ __launch_bounds__(256)
void conv_k(const float* __restrict__ x,
            const float* __restrict__ wf, const float* __restrict__ bf,
            const float* __restrict__ wb, const float* __restrict__ bb,
            float* __restrict__ xcf, float* __restrict__ xcb)
{
    __shared__ float xs[70 * 65];            // [l-halo][d], pad 65
    const int tid = threadIdx.x;
    const int d0 = blockIdx.x * 64;
    const int n0 = blockIdx.y * 64;
    const int b  = n0 >> 11;
    const int l0 = n0 & (L_SEQ - 1);
    const size_t bbase = (size_t)b << 11;

    for (int i = tid; i < 64 * 70; i += 256) {
        int r = i / 70, c = i % 70;          // r = d-off, c = l-off (l = l0-3+c)
        int l = l0 - 3 + c;
        float v = 0.f;
        if (l >= 0 && l < L_SEQ) v = x[(size_t)(d0 + r) * NTOT + bbase + l];
        xs[c * 65 + r] = v;
    }
    __syncthreads();

    const int dd = tid & 63;
    const int lq = tid >> 6;                 // 0..3
    const int d  = d0 + dd;
    const float w0 = wf[d * 4 + 0], w1 = wf[d * 4 + 1];
    const float w2 = wf[d * 4 + 2], w3 = wf[d * 4 + 3];
    const float v0 = wb[d * 4 + 0], v1 = wb[d * 4 + 1];
    const float v2 = wb[d * 4 + 2], v3 = wb[d * 4 + 3];
    const float bfv = bf[d], bbv = bb[d];

    for (int lr = 0; lr < 64; lr += 4) {
        const int lo = lr + lq;
        const int l  = l0 + lo;
        float x0 = xs[(lo + 0) * 65 + dd];
        float x1 = xs[(lo + 1) * 65 + dd];
        float x2 = xs[(lo + 2) * 65 + dd];
        float x3 = xs[(lo + 3) * 65 + dd];
        float x4 = xs[(lo + 4) * 65 + dd];
        float x5 = xs[(lo + 5) * 65 + dd];
        float x6 = xs[(lo + 6) * 65 + dd];
        float xf = bfv + w0 * x0 + w1 * x1 + w2 * x2 + w3 * x3;
        xcf[((size_t)bbase + l) * DI + d] = silu_f(xf);
        float xb = bbv + v3 * x3 + v2 * x4 + v1 * x5 + v0 * x6;
        xcb[((size_t)bbase + (L_SEQ - 1 - l)) * DI + d] = silu_f(xb);
    }
}

// ---------------------------------------------------------------------------
// Chunked scan phase 1: local scan per chunk (h0=0) + S = sum(delta).
// ---------------------------------------------------------------------------
__global__ __launch_bounds__(256)
void scan_part1(const float* __restrict__ xcf, const float* __restrict__ xcb,
                const float* __restrict__ xdf, const float* __restrict__ xdb,
                const float* __restrict__ dltf, const float* __restrict__ dltb,
                const float* __restrict__ Alog_f, const float* __restrict__ Alog_b,
                float* __restrict__ SS, float* __restrict__ HL)
{
    const int d  = blockIdx.x * 256 + threadIdx.x;
    const int c  = blockIdx.y;
    const int bb = blockIdx.z;
    const int b  = bb & 1;
    const int br = bb >> 1;

    const float* u    = br ? xcb : xcf;
    const float* dl   = br ? dltb : dltf;
    const float* xd   = br ? xdb : xdf;
    const float* Alog = br ? Alog_b : Alog_f;

    float Arow[NST], h[NST];
#pragma unroll
    for (int n = 0; n < NST; ++n) {
        Arow[n] = -__expf(Alog[d * NST + n]);
        h[n] = 0.f;
    }
    float S = 0.f;

    const size_t nbase = (size_t)b * L_SEQ + (size_t)c * CHT;
    const float* up  = u  + nbase * DI + d;
    const float* dp  = dl + nbase * DI + d;
    const float* bcB = xd + (size_t)DTR * NTOT + nbase;

    for (int tr = 0; tr < CHT; tr += 4) {
        float dv[4], uv[4];
#pragma unroll
        for (int k = 0; k < 4; ++k) {
            dv[k] = dp[(size_t)(tr + k) * DI];
            uv[k] = up[(size_t)(tr + k) * DI];
        }
        S += (dv[0] + dv[1]) + (dv[2] + dv[3]);
        float du[4] = { dv[0]*uv[0], dv[1]*uv[1], dv[2]*uv[2], dv[3]*uv[3] };
#pragma unroll
        for (int n = 0; n < NST; ++n) {
            float4 Bn = *(const float4*)(bcB + (size_t)n * NTOT + tr);
            float hn = h[n];
            float An = Arow[n];
            hn = hn * __expf(dv[0] * An) + du[0] * Bn.x;
            hn = hn * __expf(dv[1] * An) + du[1] * Bn.y;
            hn = hn * __expf(dv[2] * An) + du[2] * Bn.z;
            hn = hn * __expf(dv[3] * An) + du[3] * Bn.w;
            h[n] = hn;
        }
    }
    SS[((size_t)bb * NCH + c) * DI + d] = S;
#pragma unroll
    for (int n = 0; n < NST; ++n)
        HL[(((size_t)bb * NCH + c) * NST + n) * DI + d] = h[n];
}

// ---------------------------------------------------------------------------
// Phase 2 (in place): HL[c] replaced by chunk ENTRY state Hin[c].
// ---------------------------------------------------------------------------
__global__ __launch_bounds__(256)
void scan_part2(const float* __restrict__ SS, float* HL,
                const float* __restrict__ Alog_f, const float* __restrict__ Alog_b)
{
    const int d  = blockIdx.x * 256 + threadIdx.x;
    const int n  = blockIdx.y;
    const int bb = blockIdx.z;
    const int br = bb >> 1;
    const float* Alog = br ? Alog_b : Alog_f;
    const float A = -__expf(Alog[d * NST + n]);

    float H = 0.f;
#pragma unroll
    for (int c = 0; c < NCH; ++c) {
        const size_t si = ((size_t)bb * NCH + c) * DI + d;
        const size_t hi = (((size_t)bb * NCH + c) * NST + n) * DI + d;
        float hl = HL[hi];
        HL[hi] = H;
        H = __expf(SS[si] * A) * H + hl;
    }
}

// ---------------------------------------------------------------------------
// Phase 3: rerun chunk from entry state, y = C.h + u*D, gate silu(z),
// write bf16 [n][d] (bwd at pre-reversed n). All streams coalesced.
// ---------------------------------------------------------------------------
__global__ __launch_bounds__(256)
void scan_part3(const float* __restrict__ zt,
                const float* __restrict__ xcf, const float* __restrict__ xcb,
                const float* __restrict__ xdf, const float* __restrict__ xdb,
                const float* __restrict__ dltf, const float* __restrict__ dltb,
                const float* __restrict__ HIN,
                __bf16* __restrict__ ygtf, __bf16* __restrict__ ygtb,
                const float* __restrict__ Alog_f, const float* __restrict__ Alog_b,
                const float* __restrict__ Df, const float* __restrict__ Db)
{
    const int d  = blockIdx.x * 256 + threadIdx.x;
    const int c  = blockIdx.y;
    const int bb = blockIdx.z;
    const int b  = bb & 1;
    const int br = bb >> 1;

    const float* u    = br ? xcb : xcf;
    const float* dl   = br ? dltb : dltf;
    const float* xd   = br ? xdb : xdf;
    const float* Alog = br ? Alog_b : Alog_f;
    const float* Dv   = br ? Db : Df;
    __bf16*      ygt  = br ? ygtb : ygtf;

    float Arow[NST], h[NST];
#pragma unroll
    for (int n = 0; n < NST; ++n) {
        Arow[n] = -__expf(Alog[d * NST + n]);
        h[n] = HIN[(((size_t)bb * NCH + c) * NST + n) * DI + d];
    }
    const float Dp = Dv[d];

    const size_t nbase = (size_t)b * L_SEQ + (size_t)c * CHT;
    const float* up  = u  + nbase * DI + d;
    const float* dp  = dl + nbase * DI + d;
    const float* bcB = xd + (size_t)DTR * NTOT + nbase;
    const size_t bL = (size_t)b * L_SEQ;
    const int    t0 = c * CHT;

    for (int tr = 0; tr < CHT; tr += 4) {
        float dv[4], uv[4];
#pragma unroll
        for (int k = 0; k < 4; ++k) {
            dv[k] = dp[(size_t)(tr + k) * DI];
            uv[k] = up[(size_t)(tr + k) * DI];
        }
        float du[4] = { dv[0]*uv[0], dv[1]*uv[1], dv[2]*uv[2], dv[3]*uv[3] };
        float y[4] = { 0.f, 0.f, 0.f, 0.f };
#pragma unroll
        for (int n = 0; n < NST; ++n) {
            float4 Bn = *(const float4*)(bcB + (size_t)n * NTOT + tr);
            float4 Cn = *(const float4*)(bcB + (size_t)(NST + n) * NTOT + tr);
            float hn = h[n];
            float An = Arow[n];
            hn = hn * __expf(dv[0] * An) + du[0] * Bn.x;  y[0] = fmaf(hn, Cn.x, y[0]);
            hn = hn * __expf(dv[1] * An) + du[1] * Bn.y;  y[1] = fmaf(hn, Cn.y, y[1]);
            hn = hn * __expf(dv[2] * An) + du[2] * Bn.z;  y[2] = fmaf(hn, Cn.z, y[2]);
            hn = hn * __expf(dv[3] * An) + du[3] * Bn.w;  y[3] = fmaf(hn, Cn.w, y[3]);
            h[n] = hn;
        }
#pragma unroll
        for (int k = 0; k < 4; ++k) {
            int t = t0 + tr + k;
            size_t nn = br ? (bL + (L_SEQ - 1 - t)) : (bL + t);
            float zv = zt[nn * DI + d];
            float yo = (y[k] + uv[k] * Dp) * silu_f(zv);
            ygt[nn * DI + d] = (__bf16)yo;
        }
    }
}

extern "C" void kernel_launch(void* const* d_in, const int* in_sizes, int n_in,
                              void* d_out, int out_size, void* d_ws, size_t ws_size,
                              hipStream_t stream)
{
    const float* hid     = (const float*)d_in[0];
    const float* inw     = (const float*)d_in[1];
    const float* convw   = (const float*)d_in[2];
    const float* convb   = (const float*)d_in[3];
    const float* xpw     = (const float*)d_in[4];
    const float* dtw     = (const float*)d_in[5];
    const float* dtb     = (const float*)d_in[6];
    const float* Alog    = (const float*)d_in[7];
    const float* Dv      = (const float*)d_in[8];
    const float* convw_b = (const float*)d_in[9];
    const float* convb_b = (const float*)d_in[10];
    const float* xpw_b   = (const float*)d_in[11];
    const float* dtw_b   = (const float*)d_in[12];
    const float* dtb_b   = (const float*)d_in[13];
    const float* Alog_b  = (const float*)d_in[14];
    const float* Dv_b    = (const float*)d_in[15];
    const float* outw    = (const float*)d_in[16];
    float* out = (float*)d_out;
    float* ws  = (float*)d_ws;

    if (ws_size < WS_FLOATS * sizeof(float)) return;

    float*  X    = ws + OFF_X;
    float*  ZT   = ws + OFF_ZT;
    float*  XCF  = ws + OFF_XCF;
    float*  XCB  = ws + OFF_XCB;
    float*  DLTB = ws + OFF_DLTB;
    float*  XDF  = ws + OFF_XDF;
    float*  XDB  = ws + OFF_XDB;
    float*  SS   = ws + OFF_SS;
    float*  HLb  = ws + OFF_HL;
    __bf16* YGTF = (__bf16*)(ws + OFF_YGTF);
    __bf16* YGTB = (__bf16*)(ws + OFF_YGTB);
    float*  PF   = ws + OFF_YGTF;   // K3 split-K partials (dead region until part3)
    float*  PB   = ws + OFF_YGTB;
    float*  DLTF = X;               // overwrites dead x after conv

    dim3 blk(256);
    // K1: x[d][n] (rows<DI) + zt[n][d] (rows>=DI) = in_proj_w @ hidden^T
    gemm_mfma<false, false, true><<<dim3(32, 32), blk, 0, stream>>>(
        inw, hid, nullptr, nullptr, X, ZT, ETOT, NTOT, DM);
    // K2: conv + silu both directions -> [n][d]
    conv_k<<<dim3(32, 64), blk, 0, stream>>>(X, convw, convb, convw_b, convb_b, XCF, XCB);
    // K3: split-K partials (plain stores, no atomics), then reduce
    gemm_k<true, false, false, true><<<dim3(32, 1, SPLK), blk, 0, stream>>>(
        xpw, XCF, PF, RTOT, NTOT, DI, 0, DI, nullptr);
    gemm_k<true, false, false, true><<<dim3(32, 1, SPLK), blk, 0, stream>>>(
        xpw_b, XCB, PB, RTOT, NTOT, DI, 0, DI, nullptr);
    reduce8_k<<<dim3(RTOT * NTOT / 1024), blk, 0, stream>>>(PF, XDF, (size_t)RTOT * NTOT);
    reduce8_k<<<dim3(RTOT * NTOT / 1024), blk, 0, stream>>>(PB, XDB, (size_t)RTOT * NTOT);
    // K4: dlt[n][d] = softplus(dt_proj @ dt_r + bias)^T; fwd over dead X
    gemm_k<false, true, true, false><<<dim3(32, 16), blk, 0, stream>>>(
        dtw, XDF, DLTF, DI, NTOT, DTR, 0, DTR, dtb);
    gemm_k<false, true, true, false><<<dim3(32, 16), blk, 0, stream>>>(
        dtw_b, XDB, DLTB, DI, NTOT, DTR, 0, DTR, dtb_b);
    // K5: chunked parallel scan
    scan_part1<<<dim3(DI / 256, NCH, 4), blk, 0, stream>>>(
        XCF, XCB, XDF, XDB, DLTF, DLTB, Alog, Alog_b, SS, HLb);
    scan_part2<<<dim3(DI / 256, NST, 4), blk, 0, stream>>>(
        SS, HLb, Alog, Alog_b);
    scan_part3<<<dim3(DI / 256, NCH, 4), blk, 0, stream>>>(
        ZT, XCF, XCB, XDF, XDB, DLTF, DLTB, HLb, YGTF, YGTB, Alog, Alog_b, Dv, Dv_b);
    // K6: out[n][m] = out_proj_w @ (ygt_f + ygt_b)
    gemm_mfma<true, true, false><<<dim3(32, 8), blk, 0, stream>>>(
        outw, nullptr, YGTF, YGTB, out, nullptr, DM, NTOT, DI);

    (void)in_sizes; (void)n_in; (void)out_size;
}

// Round 8
// 644.431 us; speedup vs baseline: 4.0972x; 1.2274x over previous
//
#include <hip/hip_runtime.h>
#include <hip/hip_bf16.h>
#include <math.h>

// ---------------------------------------------------------------------------
// Bidirectional Mamba (bimamba v2), B=2, L=2048, D_MODEL=1024, D_INNER=2048,
// D_STATE=16, DT_RANK=64, D_CONV=4.
//
// Layouts: scan-facing activations are [n][d] (d contiguous, n = b*L + t in
// scan order for u/delta; natural order for z). x (conv input) is [d][n];
// x_dbl is [r][n].
//   K1  mfma  : x[d][n] + zt[n][d]  = in_proj_w @ hidden^T  (SPLITZ epilogue)
//   K2  conv  : xcf/xcb[n][d]       = silu(causal dwconv(x)), LDS transpose
//   K3  gemm  : P[z][96][n] partials = x_proj_w @ xc^T  (split-K=8, plain
//               stores into scratch; NO atomics), then reduce8_k sums z.
//   K4  dtproj: dlt[n][d] = softplus(dt_proj @ dt_r + bias)^T — dedicated
//               small-K kernel, 64x64 tiles, both branches in one launch
//               (forward dlt overwrites the dead x buffer)
//   K5  scan  : 3-phase chunked scan (32 chunks x 64); all streams coalesced
//   K6  mfma  : out[n][m] = out_proj_w @ (ygt_f + ygt_b)
//
// Workspace: 55,574,528 floats = 212.0 MiB. Split-K partials live in the
// YGTF/YGTB regions (dead until scan_part3, reduced immediately after K3).
// ---------------------------------------------------------------------------

#define L_SEQ  2048
#define B_SZ   2
#define DM     1024
#define DI     2048
#define NST    16
#define RTOT   96
#define DTR    64
#define NTOT   (B_SZ * L_SEQ)   // 4096
#define ETOT   (2 * DI)         // 4096
#define NCH    32               // scan chunks
#define CHT    (L_SEQ / NCH)    // 64 steps per chunk
#define SPLK   8                // K3 split-K factor

// workspace offsets (in floats)
#define OFF_X    ((size_t)0)                        // [DI][NTOT] x; later DLTF [NTOT][DI]
#define OFF_ZT   (OFF_X   + (size_t)DI * NTOT)      // [NTOT][DI] z transposed
#define OFF_XCF  (OFF_ZT  + (size_t)DI * NTOT)      // [NTOT][DI] u fwd (scan order)
#define OFF_XCB  (OFF_XCF + (size_t)DI * NTOT)      // [NTOT][DI] u bwd (scan order)
#define OFF_DLTB (OFF_XCB + (size_t)DI * NTOT)      // [NTOT][DI] delta bwd
#define OFF_XDF  (OFF_DLTB + (size_t)DI * NTOT)     // [96][NTOT]
#define OFF_XDB  (OFF_XDF + (size_t)RTOT * NTOT)
#define OFF_SS   (OFF_XDB + (size_t)RTOT * NTOT)    // [4][NCH][DI]
#define OFF_HL   (OFF_SS  + (size_t)4 * NCH * DI)   // [4][NCH][NST][DI] local h -> Hin
#define OFF_YGTF (OFF_HL  + (size_t)4 * NCH * NST * DI)   // bf16 [NTOT][DI]; K3 scratch
#define OFF_YGTB (OFF_YGTF + (size_t)NTOT * DI / 2)
#define WS_FLOATS (OFF_YGTB + (size_t)NTOT * DI / 2)      // 55,574,528

typedef __bf16 bf16x8 __attribute__((ext_vector_type(8)));
typedef float  floatx4 __attribute__((ext_vector_type(4)));
#define LDK 40   // MFMA LDS row stride in bf16 (32 + 8 pad)

__device__ __forceinline__ float silu_f(float x) {
    return x / (1.f + __expf(-x));
}

// ---------------------------------------------------------------------------
// bf16 MFMA GEMM: C = A[M][K] @ B[N][K]^T (fp32 out).
// DUALB: B = B1 + B2 (bf16). TRANS: C stored [N][M].
// SPLITZ: rows gm<DI -> C[d][n]; rows gm>=DI -> C2[(n)][gm-DI] (transposed).
// 128x128 tile, 4 waves, 16x16x32 MFMA, BK=32.
// ---------------------------------------------------------------------------
template<bool DUALB, bool TRANS, bool SPLITZ>
__global__ __launch_bounds__(256)
void gemm_mfma(const float* __restrict__ A, const float* __restrict__ Bf,
               const __bf16* __restrict__ B1, const __bf16* __restrict__ B2,
               float* __restrict__ C, float* __restrict__ C2,
               int M, int N, int K)
{
    __shared__ __bf16 As[128 * LDK];
    __shared__ __bf16 Bs[128 * LDK];
    const int tid  = threadIdx.x;
    const int m0   = blockIdx.y * 128;
    const int n0   = blockIdx.x * 128;
    const int lane = tid & 63;
    const int wave = tid >> 6;
    const int wy   = wave >> 1, wx = wave & 1;
    const int lr   = lane & 15;
    const int q    = lane >> 4;

    floatx4 acc[4][4];
#pragma unroll
    for (int i = 0; i < 4; ++i)
#pragma unroll
        for (int j = 0; j < 4; ++j) acc[i][j] = (floatx4)(0.0f);

    const int srow = tid >> 1;
    const int kh   = (tid & 1) * 16;
    const float* ga = A + (size_t)(m0 + srow) * K + kh;
    __bf16* wa = &As[srow * LDK + kh];
    __bf16* wb = &Bs[srow * LDK + kh];

    for (int k0 = 0; k0 < K; k0 += 32) {
        {
            float4 a0 = *(const float4*)(ga + k0);
            float4 a1 = *(const float4*)(ga + k0 + 4);
            float4 a2 = *(const float4*)(ga + k0 + 8);
            float4 a3 = *(const float4*)(ga + k0 + 12);
            bf16x8 p0, p1;
            p0[0]=(__bf16)a0.x; p0[1]=(__bf16)a0.y; p0[2]=(__bf16)a0.z; p0[3]=(__bf16)a0.w;
            p0[4]=(__bf16)a1.x; p0[5]=(__bf16)a1.y; p0[6]=(__bf16)a1.z; p0[7]=(__bf16)a1.w;
            p1[0]=(__bf16)a2.x; p1[1]=(__bf16)a2.y; p1[2]=(__bf16)a2.z; p1[3]=(__bf16)a2.w;
            p1[4]=(__bf16)a3.x; p1[5]=(__bf16)a3.y; p1[6]=(__bf16)a3.z; p1[7]=(__bf16)a3.w;
            *(bf16x8*)wa = p0; *(bf16x8*)(wa + 8) = p1;
        }
        if constexpr (DUALB) {
            const __bf16* gb1 = B1 + (size_t)(n0 + srow) * K + kh + k0;
            const __bf16* gb2 = B2 + (size_t)(n0 + srow) * K + kh + k0;
            bf16x8 u0 = *(const bf16x8*)gb1;
            bf16x8 u1 = *(const bf16x8*)(gb1 + 8);
            bf16x8 v0 = *(const bf16x8*)gb2;
            bf16x8 v1 = *(const bf16x8*)(gb2 + 8);
            bf16x8 s0, s1;
#pragma unroll
            for (int e = 0; e < 8; ++e) {
                s0[e] = (__bf16)((float)u0[e] + (float)v0[e]);
                s1[e] = (__bf16)((float)u1[e] + (float)v1[e]);
            }
            *(bf16x8*)wb = s0; *(bf16x8*)(wb + 8) = s1;
        } else {
            const float* gb = Bf + (size_t)(n0 + srow) * K + kh + k0;
            float4 b0 = *(const float4*)(gb);
            float4 b1v = *(const float4*)(gb + 4);
            float4 b2v = *(const float4*)(gb + 8);
            float4 b3 = *(const float4*)(gb + 12);
            bf16x8 p0, p1;
            p0[0]=(__bf16)b0.x; p0[1]=(__bf16)b0.y; p0[2]=(__bf16)b0.z; p0[3]=(__bf16)b0.w;
            p0[4]=(__bf16)b1v.x; p0[5]=(__bf16)b1v.y; p0[6]=(__bf16)b1v.z; p0[7]=(__bf16)b1v.w;
            p1[0]=(__bf16)b2v.x; p1[1]=(__bf16)b2v.y; p1[2]=(__bf16)b2v.z; p1[3]=(__bf16)b2v.w;
            p1[4]=(__bf16)b3.x; p1[5]=(__bf16)b3.y; p1[6]=(__bf16)b3.z; p1[7]=(__bf16)b3.w;
            *(bf16x8*)wb = p0; *(bf16x8*)(wb + 8) = p1;
        }
        __syncthreads();

        bf16x8 af[4], bfr[4];
#pragma unroll
        for (int i = 0; i < 4; ++i)
            af[i] = *(const bf16x8*)&As[(wy * 64 + i * 16 + lr) * LDK + q * 8];
#pragma unroll
        for (int j = 0; j < 4; ++j)
            bfr[j] = *(const bf16x8*)&Bs[(wx * 64 + j * 16 + lr) * LDK + q * 8];
#pragma unroll
        for (int i = 0; i < 4; ++i)
#pragma unroll
            for (int j = 0; j < 4; ++j)
                acc[i][j] = __builtin_amdgcn_mfma_f32_16x16x32_bf16(
                    af[i], bfr[j], acc[i][j], 0, 0, 0);
        __syncthreads();
    }

    const int mb = m0 + wy * 64;
    const int nb = n0 + wx * 64;
#pragma unroll
    for (int i = 0; i < 4; ++i) {
#pragma unroll
        for (int r = 0; r < 4; ++r) {
            int gm = mb + i * 16 + q * 4 + r;
#pragma unroll
            for (int j = 0; j < 4; ++j) {
                int gn = nb + j * 16 + lr;
                float val = acc[i][j][r];
                if constexpr (SPLITZ) {
                    if (m0 < DI) C[(size_t)gm * N + gn] = val;           // x [d][n]
                    else         C2[(size_t)gn * DI + (gm - DI)] = val;  // z [n][d]
                } else if constexpr (TRANS) {
                    C[(size_t)gn * M + gm] = val;
                } else {
                    C[(size_t)gm * N + gn] = val;
                }
            }
        }
    }
}

// ---------------------------------------------------------------------------
// fp32 SIMT GEMM 128x128, KT=16 (used for K3 split-K only).
// B is [N][K] (k contiguous). SPLITP: split-K over gridDim.z; each z writes
// plain stores into its own partial slab C + z*M*N (reduced by reduce8_k).
// ---------------------------------------------------------------------------
__global__ __launch_bounds__(256)
void gemm_k3(const float* __restrict__ A, const float* __restrict__ Bm,
             float* __restrict__ C, int M, int N, int K)
{
    __shared__ float As[16][132];
    __shared__ float Bs[16][132];
    const int tid = threadIdx.x;
    const int n0 = blockIdx.x * 128;
    const int m0 = blockIdx.y * 128;
    int ksz  = K / (int)gridDim.z;
    int kbeg = blockIdx.z * ksz;
    int kend = kbeg + ksz;
    C += (size_t)blockIdx.z * M * N;
    const int tx = tid & 15, ty = tid >> 4;

    float acc[8][8];
#pragma unroll
    for (int i = 0; i < 8; ++i)
#pragma unroll
        for (int j = 0; j < 8; ++j) acc[i][j] = 0.f;

    for (int k0 = kbeg; k0 < kend; k0 += 16) {
#pragma unroll
        for (int it = 0; it < 2; ++it) {
            int i = tid + it * 256;
            int m = i >> 2, kq = i & 3;
            float4 v = make_float4(0.f, 0.f, 0.f, 0.f);
            int gm = m0 + m;
            if (gm < M) v = *(const float4*)(A + (size_t)gm * K + (k0 + kq * 4));
            As[kq * 4 + 0][m] = v.x; As[kq * 4 + 1][m] = v.y;
            As[kq * 4 + 2][m] = v.z; As[kq * 4 + 3][m] = v.w;
        }
#pragma unroll
        for (int it = 0; it < 2; ++it) {
            int i = tid + it * 256;
            int n = i >> 2, kq = i & 3;
            float4 v = *(const float4*)(Bm + (size_t)(n0 + n) * K + (k0 + kq * 4));
            Bs[kq * 4 + 0][n] = v.x; Bs[kq * 4 + 1][n] = v.y;
            Bs[kq * 4 + 2][n] = v.z; Bs[kq * 4 + 3][n] = v.w;
        }
        __syncthreads();
#pragma unroll
        for (int kk = 0; kk < 16; ++kk) {
            float av[8], bv[8];
            *(float4*)&av[0] = *(const float4*)&As[kk][ty * 8];
            *(float4*)&av[4] = *(const float4*)&As[kk][ty * 8 + 4];
            *(float4*)&bv[0] = *(const float4*)&Bs[kk][tx * 8];
            *(float4*)&bv[4] = *(const float4*)&Bs[kk][tx * 8 + 4];
#pragma unroll
            for (int i = 0; i < 8; ++i)
#pragma unroll
                for (int j = 0; j < 8; ++j)
                    acc[i][j] = fmaf(av[i], bv[j], acc[i][j]);
        }
        __syncthreads();
    }

#pragma unroll
    for (int i = 0; i < 8; ++i) {
        int gm = m0 + ty * 8 + i;
        if (gm < M) {
            float* cp = C + (size_t)gm * N + n0 + tx * 8;
            *(float4*)cp       = make_float4(acc[i][0], acc[i][1], acc[i][2], acc[i][3]);
            *(float4*)(cp + 4) = make_float4(acc[i][4], acc[i][5], acc[i][6], acc[i][7]);
        }
    }
}

// ---------------------------------------------------------------------------
// reduce8_k: out[i] = sum_{z<SPLK} P[z*stride + i], float4-vectorized.
// ---------------------------------------------------------------------------
__global__ __launch_bounds__(256)
void reduce8_k(const float* __restrict__ P, float* __restrict__ out, size_t stride)
{
    const size_t i4 = ((size_t)blockIdx.x * 256 + threadIdx.x) * 4;
    float4 s = *(const float4*)(P + i4);
#pragma unroll
    for (int z = 1; z < SPLK; ++z) {
        float4 v = *(const float4*)(P + (size_t)z * stride + i4);
        s.x += v.x; s.y += v.y; s.z += v.z; s.w += v.w;
    }
    *(float4*)(out + i4) = s;
}

// ---------------------------------------------------------------------------
// K4: dlt[n][d] = softplus(dt_proj_w[d][r] @ x_dbl[r][n] + bias[d]).
// Tiny-K (64) fat-output GEMM: 64x64 tiles, 4096 blocks, both branches in z.
// A staged transposed [r][d] (pad 68), B [r][n] (pad 68); 4d x 4n per thread;
// stores coalesced along d.
// ---------------------------------------------------------------------------
__global__ __launch_bounds__(256)
void dtproj_k(const float* __restrict__ dtw_f, const float* __restrict__ dtw_b,
              const float* __restrict__ xdf, const float* __restrict__ xdb,
              const float* __restrict__ dtb_f, const float* __restrict__ dtb_b,
              float* __restrict__ dltf, float* __restrict__ dltb)
{
    __shared__ float As[DTR * 68];    // [r][d]
    __shared__ float Bs[DTR * 68];    // [r][n]
    const int br = blockIdx.z;
    const float* A  = br ? dtw_b : dtw_f;   // [DI][DTR]
    const float* Bx = br ? xdb  : xdf;      // [RTOT][NTOT], rows 0..DTR-1
    const float* bi = br ? dtb_b : dtb_f;
    float* out      = br ? dltb : dltf;     // [NTOT][DI]

    const int tid = threadIdx.x;
    const int n0 = blockIdx.x * 64;
    const int d0 = blockIdx.y * 64;

    // stage A transposed: As[r][d] <- A[(d0+d)*DTR + r]; coalesced global.
#pragma unroll
    for (int it = 0; it < 4; ++it) {
        int s = tid + it * 256;          // 0..1023
        int d = s >> 4, rq = s & 15;
        float4 v = *(const float4*)(A + (size_t)(d0 + d) * DTR + rq * 4);
        As[(rq * 4 + 0) * 68 + d] = v.x;
        As[(rq * 4 + 1) * 68 + d] = v.y;
        As[(rq * 4 + 2) * 68 + d] = v.z;
        As[(rq * 4 + 3) * 68 + d] = v.w;
    }
    // stage B: Bs[r][n] <- Bx[r][n0+n]; coalesced global, aligned LDS float4.
#pragma unroll
    for (int it = 0; it < 4; ++it) {
        int s = tid + it * 256;
        int r = s >> 4, nq = s & 15;
        float4 v = *(const float4*)(Bx + (size_t)r * NTOT + n0 + nq * 4);
        *(float4*)&Bs[r * 68 + nq * 4] = v;
    }
    __syncthreads();

    const int tx = tid & 15;             // d-group (d = tx*4)
    const int ty = tid >> 4;             // n-group (n = ty*4)
    float acc[4][4];
#pragma unroll
    for (int i = 0; i < 4; ++i)
#pragma unroll
        for (int j = 0; j < 4; ++j) acc[i][j] = 0.f;

#pragma unroll 8
    for (int r = 0; r < DTR; ++r) {
        float4 a  = *(const float4*)&As[r * 68 + tx * 4];
        float4 bv = *(const float4*)&Bs[r * 68 + ty * 4];
        float av[4] = { a.x, a.y, a.z, a.w };
        float bb[4] = { bv.x, bv.y, bv.z, bv.w };
#pragma unroll
        for (int i = 0; i < 4; ++i)
#pragma unroll
            for (int j = 0; j < 4; ++j)
                acc[i][j] = fmaf(av[i], bb[j], acc[i][j]);
    }

    const float4 bia = *(const float4*)(bi + d0 + tx * 4);
    const float bv4[4] = { bia.x, bia.y, bia.z, bia.w };
#pragma unroll
    for (int j = 0; j < 4; ++j) {
        int gn = n0 + ty * 4 + j;
        float o[4];
#pragma unroll
        for (int i = 0; i < 4; ++i) {
            float x = acc[i][j] + bv4[i];
            o[i] = (x > 20.f) ? x : log1pf(expf(x));
        }
        *(float4*)(out + (size_t)gn * DI + d0 + tx * 4) = make_float4(o[0], o[1], o[2], o[3]);
    }
}

// ---------------------------------------------------------------------------
// Causal depthwise conv (K=4) + silu, both directions. Input x [d][n];
// outputs xcf/xcb [n_scan][d] (coalesced: lane -> d). LDS transpose tile.
// ---------------------------------------------------------------------------
__global__ __launch_bounds__(256)
void conv_k(const float* __restrict__ x,
            const float* __restrict__ wf, const float* __restrict__ bf,
            const float* __restrict__ wb, const float* __restrict__ bb,
            float* __restrict__ xcf, float* __restrict__ xcb)
{
    __shared__ float xs[70 * 65];            // [l-halo][d], pad 65
    const int tid = threadIdx.x;
    const int d0 = blockIdx.x * 64;
    const int n0 = blockIdx.y * 64;
    const int b  = n0 >> 11;
    const int l0 = n0 & (L_SEQ - 1);
    const size_t bbase = (size_t)b << 11;

    for (int i = tid; i < 64 * 70; i += 256) {
        int r = i / 70, c = i % 70;          // r = d-off, c = l-off (l = l0-3+c)
        int l = l0 - 3 + c;
        float v = 0.f;
        if (l >= 0 && l < L_SEQ) v = x[(size_t)(d0 + r) * NTOT + bbase + l];
        xs[c * 65 + r] = v;
    }
    __syncthreads();

    const int dd = tid & 63;
    const int lq = tid >> 6;                 // 0..3
    const int d  = d0 + dd;
    const float w0 = wf[d * 4 + 0], w1 = wf[d * 4 + 1];
    const float w2 = wf[d * 4 + 2], w3 = wf[d * 4 + 3];
    const float v0 = wb[d * 4 + 0], v1 = wb[d * 4 + 1];
    const float v2 = wb[d * 4 + 2], v3 = wb[d * 4 + 3];
    const float bfv = bf[d], bbv = bb[d];

    for (int lr = 0; lr < 64; lr += 4) {
        const int lo = lr + lq;
        const int l  = l0 + lo;
        float x0 = xs[(lo + 0) * 65 + dd];
        float x1 = xs[(lo + 1) * 65 + dd];
        float x2 = xs[(lo + 2) * 65 + dd];
        float x3 = xs[(lo + 3) * 65 + dd];
        float x4 = xs[(lo + 4) * 65 + dd];
        float x5 = xs[(lo + 5) * 65 + dd];
        float x6 = xs[(lo + 6) * 65 + dd];
        float xf = bfv + w0 * x0 + w1 * x1 + w2 * x2 + w3 * x3;
        xcf[((size_t)bbase + l) * DI + d] = silu_f(xf);
        float xb = bbv + v3 * x3 + v2 * x4 + v1 * x5 + v0 * x6;
        xcb[((size_t)bbase + (L_SEQ - 1 - l)) * DI + d] = silu_f(xb);
    }
}

// ---------------------------------------------------------------------------
// Chunked scan phase 1: local scan per chunk (h0=0) + S = sum(delta).
// ---------------------------------------------------------------------------
__global__ __launch_bounds__(256)
void scan_part1(const float* __restrict__ xcf, const float* __restrict__ xcb,
                const float* __restrict__ xdf, const float* __restrict__ xdb,
                const float* __restrict__ dltf, const float* __restrict__ dltb,
                const float* __restrict__ Alog_f, const float* __restrict__ Alog_b,
                float* __restrict__ SS, float* __restrict__ HL)
{
    const int d  = blockIdx.x * 256 + threadIdx.x;
    const int c  = blockIdx.y;
    const int bb = blockIdx.z;
    const int b  = bb & 1;
    const int br = bb >> 1;

    const float* u    = br ? xcb : xcf;
    const float* dl   = br ? dltb : dltf;
    const float* xd   = br ? xdb : xdf;
    const float* Alog = br ? Alog_b : Alog_f;

    float Arow[NST], h[NST];
#pragma unroll
    for (int n = 0; n < NST; ++n) {
        Arow[n] = -__expf(Alog[d * NST + n]);
        h[n] = 0.f;
    }
    float S = 0.f;

    const size_t nbase = (size_t)b * L_SEQ + (size_t)c * CHT;
    const float* up  = u  + nbase * DI + d;
    const float* dp  = dl + nbase * DI + d;
    const float* bcB = xd + (size_t)DTR * NTOT + nbase;

    for (int tr = 0; tr < CHT; tr += 4) {
        float dv[4], uv[4];
#pragma unroll
        for (int k = 0; k < 4; ++k) {
            dv[k] = dp[(size_t)(tr + k) * DI];
            uv[k] = up[(size_t)(tr + k) * DI];
        }
        S += (dv[0] + dv[1]) + (dv[2] + dv[3]);
        float du[4] = { dv[0]*uv[0], dv[1]*uv[1], dv[2]*uv[2], dv[3]*uv[3] };
#pragma unroll
        for (int n = 0; n < NST; ++n) {
            float4 Bn = *(const float4*)(bcB + (size_t)n * NTOT + tr);
            float hn = h[n];
            float An = Arow[n];
            hn = hn * __expf(dv[0] * An) + du[0] * Bn.x;
            hn = hn * __expf(dv[1] * An) + du[1] * Bn.y;
            hn = hn * __expf(dv[2] * An) + du[2] * Bn.z;
            hn = hn * __expf(dv[3] * An) + du[3] * Bn.w;
            h[n] = hn;
        }
    }
    SS[((size_t)bb * NCH + c) * DI + d] = S;
#pragma unroll
    for (int n = 0; n < NST; ++n)
        HL[(((size_t)bb * NCH + c) * NST + n) * DI + d] = h[n];
}

// ---------------------------------------------------------------------------
// Phase 2 (in place): HL[c] replaced by chunk ENTRY state Hin[c].
// ---------------------------------------------------------------------------
__global__ __launch_bounds__(256)
void scan_part2(const float* __restrict__ SS, float* HL,
                const float* __restrict__ Alog_f, const float* __restrict__ Alog_b)
{
    const int d  = blockIdx.x * 256 + threadIdx.x;
    const int n  = blockIdx.y;
    const int bb = blockIdx.z;
    const int br = bb >> 1;
    const float* Alog = br ? Alog_b : Alog_f;
    const float A = -__expf(Alog[d * NST + n]);

    float H = 0.f;
#pragma unroll
    for (int c = 0; c < NCH; ++c) {
        const size_t si = ((size_t)bb * NCH + c) * DI + d;
        const size_t hi = (((size_t)bb * NCH + c) * NST + n) * DI + d;
        float hl = HL[hi];
        HL[hi] = H;
        H = __expf(SS[si] * A) * H + hl;
    }
}

// ---------------------------------------------------------------------------
// Phase 3: rerun chunk from entry state, y = C.h + u*D, gate silu(z),
// write bf16 [n][d] (bwd at pre-reversed n). All streams coalesced.
// ---------------------------------------------------------------------------
__global__ __launch_bounds__(256)
void scan_part3(const float* __restrict__ zt,
                const float* __restrict__ xcf, const float* __restrict__ xcb,
                const float* __restrict__ xdf, const float* __restrict__ xdb,
                const float* __restrict__ dltf, const float* __restrict__ dltb,
                const float* __restrict__ HIN,
                __bf16* __restrict__ ygtf, __bf16* __restrict__ ygtb,
                const float* __restrict__ Alog_f, const float* __restrict__ Alog_b,
                const float* __restrict__ Df, const float* __restrict__ Db)
{
    const int d  = blockIdx.x * 256 + threadIdx.x;
    const int c  = blockIdx.y;
    const int bb = blockIdx.z;
    const int b  = bb & 1;
    const int br = bb >> 1;

    const float* u    = br ? xcb : xcf;
    const float* dl   = br ? dltb : dltf;
    const float* xd   = br ? xdb : xdf;
    const float* Alog = br ? Alog_b : Alog_f;
    const float* Dv   = br ? Db : Df;
    __bf16*      ygt  = br ? ygtb : ygtf;

    float Arow[NST], h[NST];
#pragma unroll
    for (int n = 0; n < NST; ++n) {
        Arow[n] = -__expf(Alog[d * NST + n]);
        h[n] = HIN[(((size_t)bb * NCH + c) * NST + n) * DI + d];
    }
    const float Dp = Dv[d];

    const size_t nbase = (size_t)b * L_SEQ + (size_t)c * CHT;
    const float* up  = u  + nbase * DI + d;
    const float* dp  = dl + nbase * DI + d;
    const float* bcB = xd + (size_t)DTR * NTOT + nbase;
    const size_t bL = (size_t)b * L_SEQ;
    const int    t0 = c * CHT;

    for (int tr = 0; tr < CHT; tr += 4) {
        float dv[4], uv[4];
#pragma unroll
        for (int k = 0; k < 4; ++k) {
            dv[k] = dp[(size_t)(tr + k) * DI];
            uv[k] = up[(size_t)(tr + k) * DI];
        }
        float du[4] = { dv[0]*uv[0], dv[1]*uv[1], dv[2]*uv[2], dv[3]*uv[3] };
        float y[4] = { 0.f, 0.f, 0.f, 0.f };
#pragma unroll
        for (int n = 0; n < NST; ++n) {
            float4 Bn = *(const float4*)(bcB + (size_t)n * NTOT + tr);
            float4 Cn = *(const float4*)(bcB + (size_t)(NST + n) * NTOT + tr);
            float hn = h[n];
            float An = Arow[n];
            hn = hn * __expf(dv[0] * An) + du[0] * Bn.x;  y[0] = fmaf(hn, Cn.x, y[0]);
            hn = hn * __expf(dv[1] * An) + du[1] * Bn.y;  y[1] = fmaf(hn, Cn.y, y[1]);
            hn = hn * __expf(dv[2] * An) + du[2] * Bn.z;  y[2] = fmaf(hn, Cn.z, y[2]);
            hn = hn * __expf(dv[3] * An) + du[3] * Bn.w;  y[3] = fmaf(hn, Cn.w, y[3]);
            h[n] = hn;
        }
#pragma unroll
        for (int k = 0; k < 4; ++k) {
            int t = t0 + tr + k;
            size_t nn = br ? (bL + (L_SEQ - 1 - t)) : (bL + t);
            float zv = zt[nn * DI + d];
            float yo = (y[k] + uv[k] * Dp) * silu_f(zv);
            ygt[nn * DI + d] = (__bf16)yo;
        }
    }
}

extern "C" void kernel_launch(void* const* d_in, const int* in_sizes, int n_in,
                              void* d_out, int out_size, void* d_ws, size_t ws_size,
                              hipStream_t stream)
{
    const float* hid     = (const float*)d_in[0];
    const float* inw     = (const float*)d_in[1];
    const float* convw   = (const float*)d_in[2];
    const float* convb   = (const float*)d_in[3];
    const float* xpw     = (const float*)d_in[4];
    const float* dtw     = (const float*)d_in[5];
    const float* dtb     = (const float*)d_in[6];
    const float* Alog    = (const float*)d_in[7];
    const float* Dv      = (const float*)d_in[8];
    const float* convw_b = (const float*)d_in[9];
    const float* convb_b = (const float*)d_in[10];
    const float* xpw_b   = (const float*)d_in[11];
    const float* dtw_b   = (const float*)d_in[12];
    const float* dtb_b   = (const float*)d_in[13];
    const float* Alog_b  = (const float*)d_in[14];
    const float* Dv_b    = (const float*)d_in[15];
    const float* outw    = (const float*)d_in[16];
    float* out = (float*)d_out;
    float* ws  = (float*)d_ws;

    if (ws_size < WS_FLOATS * sizeof(float)) return;

    float*  X    = ws + OFF_X;
    float*  ZT   = ws + OFF_ZT;
    float*  XCF  = ws + OFF_XCF;
    float*  XCB  = ws + OFF_XCB;
    float*  DLTB = ws + OFF_DLTB;
    float*  XDF  = ws + OFF_XDF;
    float*  XDB  = ws + OFF_XDB;
    float*  SS   = ws + OFF_SS;
    float*  HLb  = ws + OFF_HL;
    __bf16* YGTF = (__bf16*)(ws + OFF_YGTF);
    __bf16* YGTB = (__bf16*)(ws + OFF_YGTB);
    float*  PF   = ws + OFF_YGTF;   // K3 split-K partials (dead region until part3)
    float*  PB   = ws + OFF_YGTB;
    float*  DLTF = X;               // overwrites dead x after conv

    dim3 blk(256);
    // K1: x[d][n] (rows<DI) + zt[n][d] (rows>=DI) = in_proj_w @ hidden^T
    gemm_mfma<false, false, true><<<dim3(32, 32), blk, 0, stream>>>(
        inw, hid, nullptr, nullptr, X, ZT, ETOT, NTOT, DM);
    // K2: conv + silu both directions -> [n][d]
    conv_k<<<dim3(32, 64), blk, 0, stream>>>(X, convw, convb, convw_b, convb_b, XCF, XCB);
    // K3: split-K partials (plain stores, no atomics), then reduce
    gemm_k3<<<dim3(32, 1, SPLK), blk, 0, stream>>>(xpw, XCF, PF, RTOT, NTOT, DI);
    gemm_k3<<<dim3(32, 1, SPLK), blk, 0, stream>>>(xpw_b, XCB, PB, RTOT, NTOT, DI);
    reduce8_k<<<dim3(RTOT * NTOT / 1024), blk, 0, stream>>>(PF, XDF, (size_t)RTOT * NTOT);
    reduce8_k<<<dim3(RTOT * NTOT / 1024), blk, 0, stream>>>(PB, XDB, (size_t)RTOT * NTOT);
    // K4: dlt[n][d] = softplus(dt_proj @ dt_r + bias)^T, both branches
    dtproj_k<<<dim3(NTOT / 64, DI / 64, 2), blk, 0, stream>>>(
        dtw, dtw_b, XDF, XDB, dtb, dtb_b, DLTF, DLTB);
    // K5: chunked parallel scan
    scan_part1<<<dim3(DI / 256, NCH, 4), blk, 0, stream>>>(
        XCF, XCB, XDF, XDB, DLTF, DLTB, Alog, Alog_b, SS, HLb);
    scan_part2<<<dim3(DI / 256, NST, 4), blk, 0, stream>>>(
        SS, HLb, Alog, Alog_b);
    scan_part3<<<dim3(DI / 256, NCH, 4), blk, 0, stream>>>(
        ZT, XCF, XCB, XDF, XDB, DLTF, DLTB, HLb, YGTF, YGTB, Alog, Alog_b, Dv, Dv_b);
    // K6: out[n][m] = out_proj_w @ (ygt_f + ygt_b)
    gemm_mfma<true, true, false><<<dim3(32, 8), blk, 0, stream>>>(
        outw, nullptr, YGTF, YGTB, out, nullptr, DM, NTOT, DI);

    (void)in_sizes; (void)n_in; (void)out_size;
}

// Round 9
// 575.230 us; speedup vs baseline: 4.5901x; 1.1203x over previous
//
#include <hip/hip_runtime.h>
#include <hip/hip_bf16.h>
#include <math.h>

// ---------------------------------------------------------------------------
// Bidirectional Mamba (bimamba v2), B=2, L=2048, D_MODEL=1024, D_INNER=2048,
// D_STATE=16, DT_RANK=64, D_CONV=4.
//
//   K0  cvt   : inw/hid -> bf16 copies (once, not per-tile)
//   K1  mfma  : x[d][n] + zt[n][d] = in_proj_w @ hidden^T   (async bf16 GEMM)
//   K2  conv  : xcf/xcb[n][d] = silu(causal dwconv(x)), LDS transpose
//   K3  gemm  : split-K=8 partials (plain stores) + reduce8_k
//   K4  dtproj: dlt[n][d] = softplus(dt_proj @ dt_r + bias)^T
//   K5  scan  : 3-phase chunked scan (32 chunks x 64)
//   K5b cvt/add: outw -> bf16; ygsum = ygt_f + ygt_b (bf16)
//   K6  mfma  : out[n][m] = out_proj_w @ ygsum  (async bf16 GEMM, MT=64)
//
// gemm_bf16: m97-style — global_load_lds width=16 staging, unpadded 64B LDS
// rows with XOR-block swizzle (swizzle folded into the GLOBAL address at
// stage time; inverted at ds_read_b128 time) -> 2-way bank access only.
//
// Workspace: 55,574,528 floats = 212.0 MiB (bf16 copies live in dead regions).
// ---------------------------------------------------------------------------

#define L_SEQ  2048
#define B_SZ   2
#define DM     1024
#define DI     2048
#define NST    16
#define RTOT   96
#define DTR    64
#define NTOT   (B_SZ * L_SEQ)   // 4096
#define ETOT   (2 * DI)         // 4096
#define NCH    32
#define CHT    (L_SEQ / NCH)
#define SPLK   8

// workspace offsets (in floats)
#define OFF_X    ((size_t)0)                        // [DI][NTOT] x; later DLTF [NTOT][DI]
#define OFF_ZT   (OFF_X   + (size_t)DI * NTOT)      // [NTOT][DI] z transposed
#define OFF_XCF  (OFF_ZT  + (size_t)DI * NTOT)      // [NTOT][DI] u fwd; later ygsum (bf16)
#define OFF_XCB  (OFF_XCF + (size_t)DI * NTOT)      // [NTOT][DI] u bwd; later outw bf16
#define OFF_DLTB (OFF_XCB + (size_t)DI * NTOT)      // [NTOT][DI] delta bwd
#define OFF_XDF  (OFF_DLTB + (size_t)DI * NTOT)     // [96][NTOT]
#define OFF_XDB  (OFF_XDF + (size_t)RTOT * NTOT)
#define OFF_SS   (OFF_XDB + (size_t)RTOT * NTOT)    // [4][NCH][DI]; pre-K1: inw/hid bf16
#define OFF_HL   (OFF_SS  + (size_t)4 * NCH * DI)   // [4][NCH][NST][DI]
#define OFF_YGTF (OFF_HL  + (size_t)4 * NCH * NST * DI)   // bf16 [NTOT][DI]; K3 scratch
#define OFF_YGTB (OFF_YGTF + (size_t)NTOT * DI / 2)
#define WS_FLOATS (OFF_YGTB + (size_t)NTOT * DI / 2)      // 55,574,528

typedef __bf16 bf16x8 __attribute__((ext_vector_type(8)));
typedef float  floatx4 __attribute__((ext_vector_type(4)));

__device__ __forceinline__ float silu_f(float x) {
    return x / (1.f + __expf(-x));
}

// async global(16B/lane) -> LDS; dest = wave-uniform base + lane*16
__device__ __forceinline__ void gl2lds16(const __bf16* g, __bf16* l) {
    __builtin_amdgcn_global_load_lds(
        (const __attribute__((address_space(1))) unsigned int*)g,
        (__attribute__((address_space(3))) unsigned int*)l, 16, 0, 0);
}

// ---------------------------------------------------------------------------
// Async bf16 MFMA GEMM: C[M][N] (fp32) = A[M][K] @ B[N][K]^T, MT x 128 tile,
// 4 waves (2x2), BK=32. LDS rows are 32 bf16 (64 B), XOR-swizzled blocks.
// TRANS: C stored [N][M]. SPLITZ: gm<DI -> C[d][n]; gm>=DI -> C2[n][gm-DI].
// ---------------------------------------------------------------------------
template<int MT, bool TRANS, bool SPLITZ>
__global__ __launch_bounds__(256)
void gemm_bf16(const __bf16* __restrict__ A, const __bf16* __restrict__ B,
               float* __restrict__ C, float* __restrict__ C2,
               int M, int N, int K)
{
    __shared__ __attribute__((aligned(16))) __bf16 As[MT * 32];
    __shared__ __attribute__((aligned(16))) __bf16 Bs[128 * 32];
    const int tid  = threadIdx.x;
    const int m0   = blockIdx.y * MT;
    const int n0   = blockIdx.x * 128;
    const int lane = tid & 63;
    const int wave = tid >> 6;
    const int wy   = wave >> 1, wx = wave & 1;
    const int lr   = lane & 15;
    const int q    = lane >> 4;
    constexpr int MF = MT / 32;              // A fragments per wave

    floatx4 acc[MF][4];
#pragma unroll
    for (int i = 0; i < MF; ++i)
#pragma unroll
        for (int j = 0; j < 4; ++j) acc[i][j] = (floatx4)(0.0f);

    const int rl = lane >> 2;                // row within a 16-row issue
    const int cp = lane & 3;                 // physical 16B block
    const int sw = (q ^ ((lr >> 2) & 3)) * 8;   // read-side swizzle offset

    for (int k0 = 0; k0 < K; k0 += 32) {
        // stage A: MT/64 issues per wave, 16 rows each
#pragma unroll
        for (int is = 0; is < MT / 64; ++is) {
            int r0  = wave * (MT / 4) + is * 16;
            int row = r0 + rl;
            int c   = cp ^ ((row >> 2) & 3);
            gl2lds16(A + (size_t)(m0 + row) * K + k0 + c * 8, &As[r0 * 32]);
        }
        // stage B: 2 issues per wave
#pragma unroll
        for (int is = 0; is < 2; ++is) {
            int r0  = wave * 32 + is * 16;
            int row = r0 + rl;
            int c   = cp ^ ((row >> 2) & 3);
            gl2lds16(B + (size_t)(n0 + row) * K + k0 + c * 8, &Bs[r0 * 32]);
        }
        __syncthreads();

        bf16x8 af[MF], bfr[4];
#pragma unroll
        for (int i = 0; i < MF; ++i)
            af[i] = *(const bf16x8*)&As[(wy * (MT / 2) + i * 16 + lr) * 32 + sw];
#pragma unroll
        for (int j = 0; j < 4; ++j)
            bfr[j] = *(const bf16x8*)&Bs[(wx * 64 + j * 16 + lr) * 32 + sw];
#pragma unroll
        for (int i = 0; i < MF; ++i)
#pragma unroll
            for (int j = 0; j < 4; ++j)
                acc[i][j] = __builtin_amdgcn_mfma_f32_16x16x32_bf16(
                    af[i], bfr[j], acc[i][j], 0, 0, 0);
        __syncthreads();
    }

    const int mb = m0 + wy * (MT / 2);
    const int nb = n0 + wx * 64;
#pragma unroll
    for (int i = 0; i < MF; ++i) {
#pragma unroll
        for (int r = 0; r < 4; ++r) {
            int gm = mb + i * 16 + q * 4 + r;
#pragma unroll
            for (int j = 0; j < 4; ++j) {
                int gn = nb + j * 16 + lr;
                float val = acc[i][j][r];
                if constexpr (SPLITZ) {
                    if (m0 < DI) C[(size_t)gm * N + gn] = val;
                    else         C2[(size_t)gn * DI + (gm - DI)] = val;
                } else if constexpr (TRANS) {
                    C[(size_t)gn * M + gm] = val;
                } else {
                    C[(size_t)gm * N + gn] = val;
                }
            }
        }
    }
}

// ---------------------------------------------------------------------------
// cvt fp32 -> bf16, 8 elems/thread.
// ---------------------------------------------------------------------------
__global__ __launch_bounds__(256)
void cvt_bf16_k(const float* __restrict__ in, __bf16* __restrict__ out)
{
    const size_t i = ((size_t)blockIdx.x * 256 + threadIdx.x) * 8;
    float4 a = *(const float4*)(in + i);
    float4 b = *(const float4*)(in + i + 4);
    bf16x8 p;
    p[0]=(__bf16)a.x; p[1]=(__bf16)a.y; p[2]=(__bf16)a.z; p[3]=(__bf16)a.w;
    p[4]=(__bf16)b.x; p[5]=(__bf16)b.y; p[6]=(__bf16)b.z; p[7]=(__bf16)b.w;
    *(bf16x8*)(out + i) = p;
}

// ---------------------------------------------------------------------------
// ygsum = a + b (bf16), 8 elems/thread.
// ---------------------------------------------------------------------------
__global__ __launch_bounds__(256)
void addbf16_k(const __bf16* __restrict__ a, const __bf16* __restrict__ b,
               __bf16* __restrict__ o)
{
    const size_t i = ((size_t)blockIdx.x * 256 + threadIdx.x) * 8;
    bf16x8 x = *(const bf16x8*)(a + i);
    bf16x8 y = *(const bf16x8*)(b + i);
    bf16x8 s;
#pragma unroll
    for (int e = 0; e < 8; ++e) s[e] = (__bf16)((float)x[e] + (float)y[e]);
    *(bf16x8*)(o + i) = s;
}

// ---------------------------------------------------------------------------
// fp32 SIMT GEMM 128x128, KT=16 (K3 split-K). B is [N][K] (k contiguous).
// Each z writes plain stores into its own partial slab C + z*M*N.
// ---------------------------------------------------------------------------
__global__ __launch_bounds__(256)
void gemm_k3(const float* __restrict__ A, const float* __restrict__ Bm,
             float* __restrict__ C, int M, int N, int K)
{
    __shared__ float As[16][132];
    __shared__ float Bs[16][132];
    const int tid = threadIdx.x;
    const int n0 = blockIdx.x * 128;
    const int m0 = blockIdx.y * 128;
    int ksz  = K / (int)gridDim.z;
    int kbeg = blockIdx.z * ksz;
    int kend = kbeg + ksz;
    C += (size_t)blockIdx.z * M * N;
    const int tx = tid & 15, ty = tid >> 4;

    float acc[8][8];
#pragma unroll
    for (int i = 0; i < 8; ++i)
#pragma unroll
        for (int j = 0; j < 8; ++j) acc[i][j] = 0.f;

    for (int k0 = kbeg; k0 < kend; k0 += 16) {
#pragma unroll
        for (int it = 0; it < 2; ++it) {
            int i = tid + it * 256;
            int m = i >> 2, kq = i & 3;
            float4 v = make_float4(0.f, 0.f, 0.f, 0.f);
            int gm = m0 + m;
            if (gm < M) v = *(const float4*)(A + (size_t)gm * K + (k0 + kq * 4));
            As[kq * 4 + 0][m] = v.x; As[kq * 4 + 1][m] = v.y;
            As[kq * 4 + 2][m] = v.z; As[kq * 4 + 3][m] = v.w;
        }
#pragma unroll
        for (int it = 0; it < 2; ++it) {
            int i = tid + it * 256;
            int n = i >> 2, kq = i & 3;
            float4 v = *(const float4*)(Bm + (size_t)(n0 + n) * K + (k0 + kq * 4));
            Bs[kq * 4 + 0][n] = v.x; Bs[kq * 4 + 1][n] = v.y;
            Bs[kq * 4 + 2][n] = v.z; Bs[kq * 4 + 3][n] = v.w;
        }
        __syncthreads();
#pragma unroll
        for (int kk = 0; kk < 16; ++kk) {
            float av[8], bv[8];
            *(float4*)&av[0] = *(const float4*)&As[kk][ty * 8];
            *(float4*)&av[4] = *(const float4*)&As[kk][ty * 8 + 4];
            *(float4*)&bv[0] = *(const float4*)&Bs[kk][tx * 8];
            *(float4*)&bv[4] = *(const float4*)&Bs[kk][tx * 8 + 4];
#pragma unroll
            for (int i = 0; i < 8; ++i)
#pragma unroll
                for (int j = 0; j < 8; ++j)
                    acc[i][j] = fmaf(av[i], bv[j], acc[i][j]);
        }
        __syncthreads();
    }

#pragma unroll
    for (int i = 0; i < 8; ++i) {
        int gm = m0 + ty * 8 + i;
        if (gm < M) {
            float* cp = C + (size_t)gm * N + n0 + tx * 8;
            *(float4*)cp       = make_float4(acc[i][0], acc[i][1], acc[i][2], acc[i][3]);
            *(float4*)(cp + 4) = make_float4(acc[i][4], acc[i][5], acc[i][6], acc[i][7]);
        }
    }
}

__global__ __launch_bounds__(256)
void reduce8_k(const float* __restrict__ P, float* __restrict__ out, size_t stride)
{
    const size_t i4 = ((size_t)blockIdx.x * 256 + threadIdx.x) * 4;
    float4 s = *(const float4*)(P + i4);
#pragma unroll
    for (int z = 1; z < SPLK; ++z) {
        float4 v = *(const float4*)(P + (size_t)z * stride + i4);
        s.x += v.x; s.y += v.y; s.z += v.z; s.w += v.w;
    }
    *(float4*)(out + i4) = s;
}

// ---------------------------------------------------------------------------
// K4: dlt[n][d] = softplus(dt_proj_w[d][r] @ x_dbl[r][n] + bias[d]).
// ---------------------------------------------------------------------------
__global__ __launch_bounds__(256)
void dtproj_k(const float* __restrict__ dtw_f, const float* __restrict__ dtw_b,
              const float* __restrict__ xdf, const float* __restrict__ xdb,
              const float* __restrict__ dtb_f, const float* __restrict__ dtb_b,
              float* __restrict__ dltf, float* __restrict__ dltb)
{
    __shared__ float As[DTR * 68];    // [r][d]
    __shared__ float Bs[DTR * 68];    // [r][n]
    const int br = blockIdx.z;
    const float* A  = br ? dtw_b : dtw_f;
    const float* Bx = br ? xdb  : xdf;
    const float* bi = br ? dtb_b : dtb_f;
    float* out      = br ? dltb : dltf;

    const int tid = threadIdx.x;
    const int n0 = blockIdx.x * 64;
    const int d0 = blockIdx.y * 64;

#pragma unroll
    for (int it = 0; it < 4; ++it) {
        int s = tid + it * 256;
        int d = s >> 4, rq = s & 15;
        float4 v = *(const float4*)(A + (size_t)(d0 + d) * DTR + rq * 4);
        As[(rq * 4 + 0) * 68 + d] = v.x;
        As[(rq * 4 + 1) * 68 + d] = v.y;
        As[(rq * 4 + 2) * 68 + d] = v.z;
        As[(rq * 4 + 3) * 68 + d] = v.w;
    }
#pragma unroll
    for (int it = 0; it < 4; ++it) {
        int s = tid + it * 256;
        int r = s >> 4, nq = s & 15;
        float4 v = *(const float4*)(Bx + (size_t)r * NTOT + n0 + nq * 4);
        *(float4*)&Bs[r * 68 + nq * 4] = v;
    }
    __syncthreads();

    const int tx = tid & 15;
    const int ty = tid >> 4;
    float acc[4][4];
#pragma unroll
    for (int i = 0; i < 4; ++i)
#pragma unroll
        for (int j = 0; j < 4; ++j) acc[i][j] = 0.f;

#pragma unroll 8
    for (int r = 0; r < DTR; ++r) {
        float4 a  = *(const float4*)&As[r * 68 + tx * 4];
        float4 bv = *(const float4*)&Bs[r * 68 + ty * 4];
        float av[4] = { a.x, a.y, a.z, a.w };
        float bb[4] = { bv.x, bv.y, bv.z, bv.w };
#pragma unroll
        for (int i = 0; i < 4; ++i)
#pragma unroll
            for (int j = 0; j < 4; ++j)
                acc[i][j] = fmaf(av[i], bb[j], acc[i][j]);
    }

    const float4 bia = *(const float4*)(bi + d0 + tx * 4);
    const float bv4[4] = { bia.x, bia.y, bia.z, bia.w };
#pragma unroll
    for (int j = 0; j < 4; ++j) {
        int gn = n0 + ty * 4 + j;
        float o[4];
#pragma unroll
        for (int i = 0; i < 4; ++i) {
            float x = acc[i][j] + bv4[i];
            o[i] = (x > 20.f) ? x : log1pf(expf(x));
        }
        *(float4*)(out + (size_t)gn * DI + d0 + tx * 4) = make_float4(o[0], o[1], o[2], o[3]);
    }
}

// ---------------------------------------------------------------------------
// Causal depthwise conv (K=4) + silu, both directions; x [d][n] -> [n][d].
// ---------------------------------------------------------------------------
__global__ __launch_bounds__(256)
void conv_k(const float* __restrict__ x,
            const float* __restrict__ wf, const float* __restrict__ bf,
            const float* __restrict__ wb, const float* __restrict__ bb,
            float* __restrict__ xcf, float* __restrict__ xcb)
{
    __shared__ float xs[70 * 65];
    const int tid = threadIdx.x;
    const int d0 = blockIdx.x * 64;
    const int n0 = blockIdx.y * 64;
    const int b  = n0 >> 11;
    const int l0 = n0 & (L_SEQ - 1);
    const size_t bbase = (size_t)b << 11;

    for (int i = tid; i < 64 * 70; i += 256) {
        int r = i / 70, c = i % 70;
        int l = l0 - 3 + c;
        float v = 0.f;
        if (l >= 0 && l < L_SEQ) v = x[(size_t)(d0 + r) * NTOT + bbase + l];
        xs[c * 65 + r] = v;
    }
    __syncthreads();

    const int dd = tid & 63;
    const int lq = tid >> 6;
    const int d  = d0 + dd;
    const float w0 = wf[d * 4 + 0], w1 = wf[d * 4 + 1];
    const float w2 = wf[d * 4 + 2], w3 = wf[d * 4 + 3];
    const float v0 = wb[d * 4 + 0], v1 = wb[d * 4 + 1];
    const float v2 = wb[d * 4 + 2], v3 = wb[d * 4 + 3];
    const float bfv = bf[d], bbv = bb[d];

    for (int lr = 0; lr < 64; lr += 4) {
        const int lo = lr + lq;
        const int l  = l0 + lo;
        float x0 = xs[(lo + 0) * 65 + dd];
        float x1 = xs[(lo + 1) * 65 + dd];
        float x2 = xs[(lo + 2) * 65 + dd];
        float x3 = xs[(lo + 3) * 65 + dd];
        float x4 = xs[(lo + 4) * 65 + dd];
        float x5 = xs[(lo + 5) * 65 + dd];
        float x6 = xs[(lo + 6) * 65 + dd];
        float xf = bfv + w0 * x0 + w1 * x1 + w2 * x2 + w3 * x3;
        xcf[((size_t)bbase + l) * DI + d] = silu_f(xf);
        float xb = bbv + v3 * x3 + v2 * x4 + v1 * x5 + v0 * x6;
        xcb[((size_t)bbase + (L_SEQ - 1 - l)) * DI + d] = silu_f(xb);
    }
}

// ---------------------------------------------------------------------------
// Chunked scan phase 1.
// ---------------------------------------------------------------------------
__global__ __launch_bounds__(256)
void scan_part1(const float* __restrict__ xcf, const float* __restrict__ xcb,
                const float* __restrict__ xdf, const float* __restrict__ xdb,
                const float* __restrict__ dltf, const float* __restrict__ dltb,
                const float* __restrict__ Alog_f, const float* __restrict__ Alog_b,
                float* __restrict__ SS, float* __restrict__ HL)
{
    const int d  = blockIdx.x * 256 + threadIdx.x;
    const int c  = blockIdx.y;
    const int bb = blockIdx.z;
    const int b  = bb & 1;
    const int br = bb >> 1;

    const float* u    = br ? xcb : xcf;
    const float* dl   = br ? dltb : dltf;
    const float* xd   = br ? xdb : xdf;
    const float* Alog = br ? Alog_b : Alog_f;

    float Arow[NST], h[NST];
#pragma unroll
    for (int n = 0; n < NST; ++n) {
        Arow[n] = -__expf(Alog[d * NST + n]);
        h[n] = 0.f;
    }
    float S = 0.f;

    const size_t nbase = (size_t)b * L_SEQ + (size_t)c * CHT;
    const float* up  = u  + nbase * DI + d;
    const float* dp  = dl + nbase * DI + d;
    const float* bcB = xd + (size_t)DTR * NTOT + nbase;

    for (int tr = 0; tr < CHT; tr += 4) {
        float dv[4], uv[4];
#pragma unroll
        for (int k = 0; k < 4; ++k) {
            dv[k] = dp[(size_t)(tr + k) * DI];
            uv[k] = up[(size_t)(tr + k) * DI];
        }
        S += (dv[0] + dv[1]) + (dv[2] + dv[3]);
        float du[4] = { dv[0]*uv[0], dv[1]*uv[1], dv[2]*uv[2], dv[3]*uv[3] };
#pragma unroll
        for (int n = 0; n < NST; ++n) {
            float4 Bn = *(const float4*)(bcB + (size_t)n * NTOT + tr);
            float hn = h[n];
            float An = Arow[n];
            hn = hn * __expf(dv[0] * An) + du[0] * Bn.x;
            hn = hn * __expf(dv[1] * An) + du[1] * Bn.y;
            hn = hn * __expf(dv[2] * An) + du[2] * Bn.z;
            hn = hn * __expf(dv[3] * An) + du[3] * Bn.w;
            h[n] = hn;
        }
    }
    SS[((size_t)bb * NCH + c) * DI + d] = S;
#pragma unroll
    for (int n = 0; n < NST; ++n)
        HL[(((size_t)bb * NCH + c) * NST + n) * DI + d] = h[n];
}

__global__ __launch_bounds__(256)
void scan_part2(const float* __restrict__ SS, float* HL,
                const float* __restrict__ Alog_f, const float* __restrict__ Alog_b)
{
    const int d  = blockIdx.x * 256 + threadIdx.x;
    const int n  = blockIdx.y;
    const int bb = blockIdx.z;
    const int br = bb >> 1;
    const float* Alog = br ? Alog_b : Alog_f;
    const float A = -__expf(Alog[d * NST + n]);

    float H = 0.f;
#pragma unroll
    for (int c = 0; c < NCH; ++c) {
        const size_t si = ((size_t)bb * NCH + c) * DI + d;
        const size_t hi = (((size_t)bb * NCH + c) * NST + n) * DI + d;
        float hl = HL[hi];
        HL[hi] = H;
        H = __expf(SS[si] * A) * H + hl;
    }
}

__global__ __launch_bounds__(256)
void scan_part3(const float* __restrict__ zt,
                const float* __restrict__ xcf, const float* __restrict__ xcb,
                const float* __restrict__ xdf, const float* __restrict__ xdb,
                const float* __restrict__ dltf, const float* __restrict__ dltb,
                const float* __restrict__ HIN,
                __bf16* __restrict__ ygtf, __bf16* __restrict__ ygtb,
                const float* __restrict__ Alog_f, const float* __restrict__ Alog_b,
                const float* __restrict__ Df, const float* __restrict__ Db)
{
    const int d  = blockIdx.x * 256 + threadIdx.x;
    const int c  = blockIdx.y;
    const int bb = blockIdx.z;
    const int b  = bb & 1;
    const int br = bb >> 1;

    const float* u    = br ? xcb : xcf;
    const float* dl   = br ? dltb : dltf;
    const float* xd   = br ? xdb : xdf;
    const float* Alog = br ? Alog_b : Alog_f;
    const float* Dv   = br ? Db : Df;
    __bf16*      ygt  = br ? ygtb : ygtf;

    float Arow[NST], h[NST];
#pragma unroll
    for (int n = 0; n < NST; ++n) {
        Arow[n] = -__expf(Alog[d * NST + n]);
        h[n] = HIN[(((size_t)bb * NCH + c) * NST + n) * DI + d];
    }
    const float Dp = Dv[d];

    const size_t nbase = (size_t)b * L_SEQ + (size_t)c * CHT;
    const float* up  = u  + nbase * DI + d;
    const float* dp  = dl + nbase * DI + d;
    const float* bcB = xd + (size_t)DTR * NTOT + nbase;
    const size_t bL = (size_t)b * L_SEQ;
    const int    t0 = c * CHT;

    for (int tr = 0; tr < CHT; tr += 4) {
        float dv[4], uv[4];
#pragma unroll
        for (int k = 0; k < 4; ++k) {
            dv[k] = dp[(size_t)(tr + k) * DI];
            uv[k] = up[(size_t)(tr + k) * DI];
        }
        float du[4] = { dv[0]*uv[0], dv[1]*uv[1], dv[2]*uv[2], dv[3]*uv[3] };
        float y[4] = { 0.f, 0.f, 0.f, 0.f };
#pragma unroll
        for (int n = 0; n < NST; ++n) {
            float4 Bn = *(const float4*)(bcB + (size_t)n * NTOT + tr);
            float4 Cn = *(const float4*)(bcB + (size_t)(NST + n) * NTOT + tr);
            float hn = h[n];
            float An = Arow[n];
            hn = hn * __expf(dv[0] * An) + du[0] * Bn.x;  y[0] = fmaf(hn, Cn.x, y[0]);
            hn = hn * __expf(dv[1] * An) + du[1] * Bn.y;  y[1] = fmaf(hn, Cn.y, y[1]);
            hn = hn * __expf(dv[2] * An) + du[2] * Bn.z;  y[2] = fmaf(hn, Cn.z, y[2]);
            hn = hn * __expf(dv[3] * An) + du[3] * Bn.w;  y[3] = fmaf(hn, Cn.w, y[3]);
            h[n] = hn;
        }
#pragma unroll
        for (int k = 0; k < 4; ++k) {
            int t = t0 + tr + k;
            size_t nn = br ? (bL + (L_SEQ - 1 - t)) : (bL + t);
            float zv = zt[nn * DI + d];
            float yo = (y[k] + uv[k] * Dp) * silu_f(zv);
            ygt[nn * DI + d] = (__bf16)yo;
        }
    }
}

extern "C" void kernel_launch(void* const* d_in, const int* in_sizes, int n_in,
                              void* d_out, int out_size, void* d_ws, size_t ws_size,
                              hipStream_t stream)
{
    const float* hid     = (const float*)d_in[0];
    const float* inw     = (const float*)d_in[1];
    const float* convw   = (const float*)d_in[2];
    const float* convb   = (const float*)d_in[3];
    const float* xpw     = (const float*)d_in[4];
    const float* dtw     = (const float*)d_in[5];
    const float* dtb     = (const float*)d_in[6];
    const float* Alog    = (const float*)d_in[7];
    const float* Dv      = (const float*)d_in[8];
    const float* convw_b = (const float*)d_in[9];
    const float* convb_b = (const float*)d_in[10];
    const float* xpw_b   = (const float*)d_in[11];
    const float* dtw_b   = (const float*)d_in[12];
    const float* dtb_b   = (const float*)d_in[13];
    const float* Alog_b  = (const float*)d_in[14];
    const float* Dv_b    = (const float*)d_in[15];
    const float* outw    = (const float*)d_in[16];
    float* out = (float*)d_out;
    float* ws  = (float*)d_ws;

    if (ws_size < WS_FLOATS * sizeof(float)) return;

    float*  X    = ws + OFF_X;
    float*  ZT   = ws + OFF_ZT;
    float*  XCF  = ws + OFF_XCF;
    float*  XCB  = ws + OFF_XCB;
    float*  DLTB = ws + OFF_DLTB;
    float*  XDF  = ws + OFF_XDF;
    float*  XDB  = ws + OFF_XDB;
    float*  SS   = ws + OFF_SS;
    float*  HLb  = ws + OFF_HL;
    __bf16* YGTF = (__bf16*)(ws + OFF_YGTF);
    __bf16* YGTB = (__bf16*)(ws + OFF_YGTB);
    float*  PF   = ws + OFF_YGTF;   // K3 split-K partials (dead until part3)
    float*  PB   = ws + OFF_YGTB;
    float*  DLTF = X;               // overwrites dead x after conv
    // bf16 weight/activation copies in dead regions:
    __bf16* IW16 = (__bf16*)(ws + OFF_SS);            // dead until scan_part1
    __bf16* HD16 = IW16 + (size_t)ETOT * DM;
    __bf16* OW16 = (__bf16*)(ws + OFF_XCB);           // dead after scan_part3
    __bf16* YGS  = (__bf16*)(ws + OFF_XCF);           // dead after scan_part3

    dim3 blk(256);
    // K0: one-time bf16 conversions of in_proj weights and hidden
    cvt_bf16_k<<<dim3(ETOT * DM / 2048), blk, 0, stream>>>(inw, IW16);
    cvt_bf16_k<<<dim3(NTOT * DM / 2048), blk, 0, stream>>>(hid, HD16);
    // K1: x[d][n] + zt[n][d] = in_proj_w @ hidden^T  (async bf16 MFMA)
    gemm_bf16<128, false, true><<<dim3(32, 32), blk, 0, stream>>>(
        IW16, HD16, X, ZT, ETOT, NTOT, DM);
    // K2: conv + silu both directions -> [n][d]
    conv_k<<<dim3(32, 64), blk, 0, stream>>>(X, convw, convb, convw_b, convb_b, XCF, XCB);
    // K3: split-K partials (plain stores), then reduce
    gemm_k3<<<dim3(32, 1, SPLK), blk, 0, stream>>>(xpw, XCF, PF, RTOT, NTOT, DI);
    gemm_k3<<<dim3(32, 1, SPLK), blk, 0, stream>>>(xpw_b, XCB, PB, RTOT, NTOT, DI);
    reduce8_k<<<dim3(RTOT * NTOT / 1024), blk, 0, stream>>>(PF, XDF, (size_t)RTOT * NTOT);
    reduce8_k<<<dim3(RTOT * NTOT / 1024), blk, 0, stream>>>(PB, XDB, (size_t)RTOT * NTOT);
    // K4: dlt[n][d] = softplus(dt_proj @ dt_r + bias)^T, both branches
    dtproj_k<<<dim3(NTOT / 64, DI / 64, 2), blk, 0, stream>>>(
        dtw, dtw_b, XDF, XDB, dtb, dtb_b, DLTF, DLTB);
    // K5: chunked parallel scan
    scan_part1<<<dim3(DI / 256, NCH, 4), blk, 0, stream>>>(
        XCF, XCB, XDF, XDB, DLTF, DLTB, Alog, Alog_b, SS, HLb);
    scan_part2<<<dim3(DI / 256, NST, 4), blk, 0, stream>>>(
        SS, HLb, Alog, Alog_b);
    scan_part3<<<dim3(DI / 256, NCH, 4), blk, 0, stream>>>(
        ZT, XCF, XCB, XDF, XDB, DLTF, DLTB, HLb, YGTF, YGTB, Alog, Alog_b, Dv, Dv_b);
    // K5b: outw -> bf16; ygsum = ygt_f + ygt_b
    cvt_bf16_k<<<dim3(DM * DI / 2048), blk, 0, stream>>>(outw, OW16);
    addbf16_k<<<dim3(NTOT * DI / 2048), blk, 0, stream>>>(YGTF, YGTB, YGS);
    // K6: out[n][m] = out_proj_w @ ygsum  (async bf16 MFMA, MT=64 -> 512 blocks)
    gemm_bf16<64, true, false><<<dim3(32, 16), blk, 0, stream>>>(
        OW16, YGS, out, nullptr, DM, NTOT, DI);

    (void)in_sizes; (void)n_in; (void)out_size;
}

// Round 10
// 518.444 us; speedup vs baseline: 5.0929x; 1.1095x over previous
//
#include <hip/hip_runtime.h>
#include <hip/hip_bf16.h>
#include <math.h>

// ---------------------------------------------------------------------------
// Bidirectional Mamba (bimamba v2), B=2, L=2048, D_MODEL=1024, D_INNER=2048,
// D_STATE=16, DT_RANK=64, D_CONV=4.
//
//   K0  cvt   : inw/hid/dtw/dtw_b -> bf16 copies (once)
//   K1  mfma  : x[d][n] + zt[n][d] = in_proj_w @ hidden^T   (async bf16 GEMM)
//   K2  conv  : xcf/xcb[n][d] = silu(causal dwconv(x)), LDS transpose
//   K3  gemm  : split-K=8 partials (plain stores) + reduce8t_k (sums z AND
//               emits bf16 transposed dt_r [n][r] for the dt GEMM)
//   K4  mfma  : dlt[n][d] = softplus(dt_r^T @ dtw^T + bias)  (async bf16,
//               K=64, coalesced [n][d] stores)
//   K5  scan  : 3-phase chunked scan (32 chunks x 64)
//   K5b cvt/add: outw -> bf16; ygsum = ygt_f + ygt_b (bf16)
//   K6  mfma  : out[n][m] = out_proj_w @ ygsum  (async bf16 GEMM, MT=64)
//
// gemm_bf16 / dtproj_mfma: m97-style — global_load_lds width=16 staging,
// unpadded 64B LDS rows with XOR-block swizzle -> 2-way bank access only.
//
// Workspace: 55,967,744 floats = 213.5 MiB.
// ---------------------------------------------------------------------------

#define L_SEQ  2048
#define B_SZ   2
#define DM     1024
#define DI     2048
#define NST    16
#define RTOT   96
#define DTR    64
#define NTOT   (B_SZ * L_SEQ)   // 4096
#define ETOT   (2 * DI)         // 4096
#define NCH    32
#define CHT    (L_SEQ / NCH)
#define SPLK   8

// workspace offsets (in floats)
#define OFF_X    ((size_t)0)                        // [DI][NTOT] x; later DLTF [NTOT][DI]
#define OFF_ZT   (OFF_X   + (size_t)DI * NTOT)      // [NTOT][DI] z transposed
#define OFF_XCF  (OFF_ZT  + (size_t)DI * NTOT)      // [NTOT][DI] u fwd; later ygsum (bf16)
#define OFF_XCB  (OFF_XCF + (size_t)DI * NTOT)      // [NTOT][DI] u bwd; later outw bf16
#define OFF_DLTB (OFF_XCB + (size_t)DI * NTOT)      // [NTOT][DI] delta bwd
#define OFF_XDF  (OFF_DLTB + (size_t)DI * NTOT)     // [96][NTOT]
#define OFF_XDB  (OFF_XDF + (size_t)RTOT * NTOT)
#define OFF_SS   (OFF_XDB + (size_t)RTOT * NTOT)    // [4][NCH][DI]; pre-K1: inw/hid bf16
#define OFF_HL   (OFF_SS  + (size_t)4 * NCH * DI)   // [4][NCH][NST][DI]
#define OFF_YGTF (OFF_HL  + (size_t)4 * NCH * NST * DI)   // bf16 [NTOT][DI]; K3 scratch
#define OFF_YGTB (OFF_YGTF + (size_t)NTOT * DI / 2)
#define OFF_XDT16F (OFF_YGTB + (size_t)NTOT * DI / 2)     // bf16 [NTOT][DTR]
#define OFF_XDT16B (OFF_XDT16F + (size_t)NTOT * DTR / 2)
#define OFF_DTW16F (OFF_XDT16B + (size_t)NTOT * DTR / 2)  // bf16 [DI][DTR]
#define OFF_DTW16B (OFF_DTW16F + (size_t)DI * DTR / 2)
#define WS_FLOATS  (OFF_DTW16B + (size_t)DI * DTR / 2)    // 55,967,744

typedef __bf16 bf16x8 __attribute__((ext_vector_type(8)));
typedef float  floatx4 __attribute__((ext_vector_type(4)));

__device__ __forceinline__ float silu_f(float x) {
    return x / (1.f + __expf(-x));
}

// async global(16B/lane) -> LDS; dest = wave-uniform base + lane*16
__device__ __forceinline__ void gl2lds16(const __bf16* g, __bf16* l) {
    __builtin_amdgcn_global_load_lds(
        (const __attribute__((address_space(1))) unsigned int*)g,
        (__attribute__((address_space(3))) unsigned int*)l, 16, 0, 0);
}

// ---------------------------------------------------------------------------
// Async bf16 MFMA GEMM: C[M][N] (fp32) = A[M][K] @ B[N][K]^T, MT x 128 tile,
// 4 waves (2x2), BK=32. LDS rows are 32 bf16 (64 B), XOR-swizzled blocks.
// TRANS: C stored [N][M]. SPLITZ: gm<DI -> C[d][n]; gm>=DI -> C2[n][gm-DI].
// ---------------------------------------------------------------------------
template<int MT, bool TRANS, bool SPLITZ>
__global__ __launch_bounds__(256)
void gemm_bf16(const __bf16* __restrict__ A, const __bf16* __restrict__ B,
               float* __restrict__ C, float* __restrict__ C2,
               int M, int N, int K)
{
    __shared__ __attribute__((aligned(16))) __bf16 As[MT * 32];
    __shared__ __attribute__((aligned(16))) __bf16 Bs[128 * 32];
    const int tid  = threadIdx.x;
    const int m0   = blockIdx.y * MT;
    const int n0   = blockIdx.x * 128;
    const int lane = tid & 63;
    const int wave = tid >> 6;
    const int wy   = wave >> 1, wx = wave & 1;
    const int lr   = lane & 15;
    const int q    = lane >> 4;
    constexpr int MF = MT / 32;

    floatx4 acc[MF][4];
#pragma unroll
    for (int i = 0; i < MF; ++i)
#pragma unroll
        for (int j = 0; j < 4; ++j) acc[i][j] = (floatx4)(0.0f);

    const int rl = lane >> 2;
    const int cp = lane & 3;
    const int sw = (q ^ ((lr >> 2) & 3)) * 8;

    for (int k0 = 0; k0 < K; k0 += 32) {
#pragma unroll
        for (int is = 0; is < MT / 64; ++is) {
            int r0  = wave * (MT / 4) + is * 16;
            int row = r0 + rl;
            int c   = cp ^ ((row >> 2) & 3);
            gl2lds16(A + (size_t)(m0 + row) * K + k0 + c * 8, &As[r0 * 32]);
        }
#pragma unroll
        for (int is = 0; is < 2; ++is) {
            int r0  = wave * 32 + is * 16;
            int row = r0 + rl;
            int c   = cp ^ ((row >> 2) & 3);
            gl2lds16(B + (size_t)(n0 + row) * K + k0 + c * 8, &Bs[r0 * 32]);
        }
        __syncthreads();

        bf16x8 af[MF], bfr[4];
#pragma unroll
        for (int i = 0; i < MF; ++i)
            af[i] = *(const bf16x8*)&As[(wy * (MT / 2) + i * 16 + lr) * 32 + sw];
#pragma unroll
        for (int j = 0; j < 4; ++j)
            bfr[j] = *(const bf16x8*)&Bs[(wx * 64 + j * 16 + lr) * 32 + sw];
#pragma unroll
        for (int i = 0; i < MF; ++i)
#pragma unroll
            for (int j = 0; j < 4; ++j)
                acc[i][j] = __builtin_amdgcn_mfma_f32_16x16x32_bf16(
                    af[i], bfr[j], acc[i][j], 0, 0, 0);
        __syncthreads();
    }

    const int mb = m0 + wy * (MT / 2);
    const int nb = n0 + wx * 64;
#pragma unroll
    for (int i = 0; i < MF; ++i) {
#pragma unroll
        for (int r = 0; r < 4; ++r) {
            int gm = mb + i * 16 + q * 4 + r;
#pragma unroll
            for (int j = 0; j < 4; ++j) {
                int gn = nb + j * 16 + lr;
                float val = acc[i][j][r];
                if constexpr (SPLITZ) {
                    if (m0 < DI) C[(size_t)gm * N + gn] = val;
                    else         C2[(size_t)gn * DI + (gm - DI)] = val;
                } else if constexpr (TRANS) {
                    C[(size_t)gn * M + gm] = val;
                } else {
                    C[(size_t)gm * N + gn] = val;
                }
            }
        }
    }
}

// ---------------------------------------------------------------------------
// K4: dlt[n][d] = softplus(dt_r^T[n][r] @ dtw[d][r]^T + bias[d]).
// Async bf16 MFMA, M=NTOT, N=DI, K=DTR=64 (2 k-iters), 128x128 tile,
// both branches via blockIdx.z. Coalesced [n][d] stores.
// ---------------------------------------------------------------------------
__global__ __launch_bounds__(256)
void dtproj_mfma(const __bf16* __restrict__ Af, const __bf16* __restrict__ Ab,
                 const __bf16* __restrict__ Bwf, const __bf16* __restrict__ Bwb,
                 const float* __restrict__ bif, const float* __restrict__ bib,
                 float* __restrict__ outf, float* __restrict__ outb)
{
    __shared__ __attribute__((aligned(16))) __bf16 As[128 * 32];
    __shared__ __attribute__((aligned(16))) __bf16 Bs[128 * 32];
    const int br = blockIdx.z;
    const __bf16* A  = br ? Ab : Af;     // [NTOT][DTR]
    const __bf16* B  = br ? Bwb : Bwf;   // [DI][DTR]
    const float*  bi = br ? bib : bif;
    float*        C  = br ? outb : outf; // [NTOT][DI]

    const int tid  = threadIdx.x;
    const int m0   = blockIdx.y * 128;   // n dim
    const int n0   = blockIdx.x * 128;   // d dim
    const int lane = tid & 63;
    const int wave = tid >> 6;
    const int wy   = wave >> 1, wx = wave & 1;
    const int lr   = lane & 15;
    const int q    = lane >> 4;

    floatx4 acc[4][4];
#pragma unroll
    for (int i = 0; i < 4; ++i)
#pragma unroll
        for (int j = 0; j < 4; ++j) acc[i][j] = (floatx4)(0.0f);

    const int rl = lane >> 2;
    const int cp = lane & 3;
    const int sw = (q ^ ((lr >> 2) & 3)) * 8;

#pragma unroll
    for (int k0 = 0; k0 < DTR; k0 += 32) {
#pragma unroll
        for (int is = 0; is < 2; ++is) {
            int r0  = wave * 32 + is * 16;
            int row = r0 + rl;
            int c   = cp ^ ((row >> 2) & 3);
            gl2lds16(A + (size_t)(m0 + row) * DTR + k0 + c * 8, &As[r0 * 32]);
            gl2lds16(B + (size_t)(n0 + row) * DTR + k0 + c * 8, &Bs[r0 * 32]);
        }
        __syncthreads();

        bf16x8 af[4], bfr[4];
#pragma unroll
        for (int i = 0; i < 4; ++i)
            af[i] = *(const bf16x8*)&As[(wy * 64 + i * 16 + lr) * 32 + sw];
#pragma unroll
        for (int j = 0; j < 4; ++j)
            bfr[j] = *(const bf16x8*)&Bs[(wx * 64 + j * 16 + lr) * 32 + sw];
#pragma unroll
        for (int i = 0; i < 4; ++i)
#pragma unroll
            for (int j = 0; j < 4; ++j)
                acc[i][j] = __builtin_amdgcn_mfma_f32_16x16x32_bf16(
                    af[i], bfr[j], acc[i][j], 0, 0, 0);
        __syncthreads();
    }

    const int mb = m0 + wy * 64;
    const int nb = n0 + wx * 64;
    float bj[4];
#pragma unroll
    for (int j = 0; j < 4; ++j) bj[j] = bi[nb + j * 16 + lr];
#pragma unroll
    for (int i = 0; i < 4; ++i) {
#pragma unroll
        for (int r = 0; r < 4; ++r) {
            int gm = mb + i * 16 + q * 4 + r;
#pragma unroll
            for (int j = 0; j < 4; ++j) {
                int gn = nb + j * 16 + lr;
                float x = acc[i][j][r] + bj[j];
                float o = (x > 20.f) ? x : __logf(1.f + __expf(x));
                C[(size_t)gm * DI + gn] = o;
            }
        }
    }
}

// ---------------------------------------------------------------------------
// cvt fp32 -> bf16, 8 elems/thread.
// ---------------------------------------------------------------------------
__global__ __launch_bounds__(256)
void cvt_bf16_k(const float* __restrict__ in, __bf16* __restrict__ out)
{
    const size_t i = ((size_t)blockIdx.x * 256 + threadIdx.x) * 8;
    float4 a = *(const float4*)(in + i);
    float4 b = *(const float4*)(in + i + 4);
    bf16x8 p;
    p[0]=(__bf16)a.x; p[1]=(__bf16)a.y; p[2]=(__bf16)a.z; p[3]=(__bf16)a.w;
    p[4]=(__bf16)b.x; p[5]=(__bf16)b.y; p[6]=(__bf16)b.z; p[7]=(__bf16)b.w;
    *(bf16x8*)(out + i) = p;
}

__global__ __launch_bounds__(256)
void addbf16_k(const __bf16* __restrict__ a, const __bf16* __restrict__ b,
               __bf16* __restrict__ o)
{
    const size_t i = ((size_t)blockIdx.x * 256 + threadIdx.x) * 8;
    bf16x8 x = *(const bf16x8*)(a + i);
    bf16x8 y = *(const bf16x8*)(b + i);
    bf16x8 s;
#pragma unroll
    for (int e = 0; e < 8; ++e) s[e] = (__bf16)((float)x[e] + (float)y[e]);
    *(bf16x8*)(o + i) = s;
}

// ---------------------------------------------------------------------------
// fp32 SIMT GEMM 128x128, KT=16 (K3 split-K). B is [N][K] (k contiguous).
// ---------------------------------------------------------------------------
__global__ __launch_bounds__(256)
void gemm_k3(const float* __restrict__ A, const float* __restrict__ Bm,
             float* __restrict__ C, int M, int N, int K)
{
    __shared__ float As[16][132];
    __shared__ float Bs[16][132];
    const int tid = threadIdx.x;
    const int n0 = blockIdx.x * 128;
    const int m0 = blockIdx.y * 128;
    int ksz  = K / (int)gridDim.z;
    int kbeg = blockIdx.z * ksz;
    int kend = kbeg + ksz;
    C += (size_t)blockIdx.z * M * N;
    const int tx = tid & 15, ty = tid >> 4;

    float acc[8][8];
#pragma unroll
    for (int i = 0; i < 8; ++i)
#pragma unroll
        for (int j = 0; j < 8; ++j) acc[i][j] = 0.f;

    for (int k0 = kbeg; k0 < kend; k0 += 16) {
#pragma unroll
        for (int it = 0; it < 2; ++it) {
            int i = tid + it * 256;
            int m = i >> 2, kq = i & 3;
            float4 v = make_float4(0.f, 0.f, 0.f, 0.f);
            int gm = m0 + m;
            if (gm < M) v = *(const float4*)(A + (size_t)gm * K + (k0 + kq * 4));
            As[kq * 4 + 0][m] = v.x; As[kq * 4 + 1][m] = v.y;
            As[kq * 4 + 2][m] = v.z; As[kq * 4 + 3][m] = v.w;
        }
#pragma unroll
        for (int it = 0; it < 2; ++it) {
            int i = tid + it * 256;
            int n = i >> 2, kq = i & 3;
            float4 v = *(const float4*)(Bm + (size_t)(n0 + n) * K + (k0 + kq * 4));
            Bs[kq * 4 + 0][n] = v.x; Bs[kq * 4 + 1][n] = v.y;
            Bs[kq * 4 + 2][n] = v.z; Bs[kq * 4 + 3][n] = v.w;
        }
        __syncthreads();
#pragma unroll
        for (int kk = 0; kk < 16; ++kk) {
            float av[8], bv[8];
            *(float4*)&av[0] = *(const float4*)&As[kk][ty * 8];
            *(float4*)&av[4] = *(const float4*)&As[kk][ty * 8 + 4];
            *(float4*)&bv[0] = *(const float4*)&Bs[kk][tx * 8];
            *(float4*)&bv[4] = *(const float4*)&Bs[kk][tx * 8 + 4];
#pragma unroll
            for (int i = 0; i < 8; ++i)
#pragma unroll
                for (int j = 0; j < 8; ++j)
                    acc[i][j] = fmaf(av[i], bv[j], acc[i][j]);
        }
        __syncthreads();
    }

#pragma unroll
    for (int i = 0; i < 8; ++i) {
        int gm = m0 + ty * 8 + i;
        if (gm < M) {
            float* cp = C + (size_t)gm * N + n0 + tx * 8;
            *(float4*)cp       = make_float4(acc[i][0], acc[i][1], acc[i][2], acc[i][3]);
            *(float4*)(cp + 4) = make_float4(acc[i][4], acc[i][5], acc[i][6], acc[i][7]);
        }
    }
}

// ---------------------------------------------------------------------------
// reduce8t_k: out[i] = sum_z P[z*stride+i]; rows r<DTR also emit bf16
// transposed copy out2[n][r] for the dt GEMM A-operand.
// ---------------------------------------------------------------------------
__global__ __launch_bounds__(256)
void reduce8t_k(const float* __restrict__ P, float* __restrict__ out,
                __bf16* __restrict__ out2, size_t stride)
{
    const size_t i4 = ((size_t)blockIdx.x * 256 + threadIdx.x) * 4;
    float4 s = *(const float4*)(P + i4);
#pragma unroll
    for (int z = 1; z < SPLK; ++z) {
        float4 v = *(const float4*)(P + (size_t)z * stride + i4);
        s.x += v.x; s.y += v.y; s.z += v.z; s.w += v.w;
    }
    *(float4*)(out + i4) = s;
    const int r = (int)(i4 >> 12);          // / NTOT
    if (r < DTR) {
        const int n = (int)(i4 & (NTOT - 1));
        out2[(size_t)(n + 0) * DTR + r] = (__bf16)s.x;
        out2[(size_t)(n + 1) * DTR + r] = (__bf16)s.y;
        out2[(size_t)(n + 2) * DTR + r] = (__bf16)s.z;
        out2[(size_t)(n + 3) * DTR + r] = (__bf16)s.w;
    }
}

// ---------------------------------------------------------------------------
// Causal depthwise conv (K=4) + silu, both directions; x [d][n] -> [n][d].
// ---------------------------------------------------------------------------
__global__ __launch_bounds__(256)
void conv_k(const float* __restrict__ x,
            const float* __restrict__ wf, const float* __restrict__ bf,
            const float* __restrict__ wb, const float* __restrict__ bb,
            float* __restrict__ xcf, float* __restrict__ xcb)
{
    __shared__ float xs[70 * 65];
    const int tid = threadIdx.x;
    const int d0 = blockIdx.x * 64;
    const int n0 = blockIdx.y * 64;
    const int b  = n0 >> 11;
    const int l0 = n0 & (L_SEQ - 1);
    const size_t bbase = (size_t)b << 11;

    for (int i = tid; i < 64 * 70; i += 256) {
        int r = i / 70, c = i % 70;
        int l = l0 - 3 + c;
        float v = 0.f;
        if (l >= 0 && l < L_SEQ) v = x[(size_t)(d0 + r) * NTOT + bbase + l];
        xs[c * 65 + r] = v;
    }
    __syncthreads();

    const int dd = tid & 63;
    const int lq = tid >> 6;
    const int d  = d0 + dd;
    const float w0 = wf[d * 4 + 0], w1 = wf[d * 4 + 1];
    const float w2 = wf[d * 4 + 2], w3 = wf[d * 4 + 3];
    const float v0 = wb[d * 4 + 0], v1 = wb[d * 4 + 1];
    const float v2 = wb[d * 4 + 2], v3 = wb[d * 4 + 3];
    const float bfv = bf[d], bbv = bb[d];

    for (int lr = 0; lr < 64; lr += 4) {
        const int lo = lr + lq;
        const int l  = l0 + lo;
        float x0 = xs[(lo + 0) * 65 + dd];
        float x1 = xs[(lo + 1) * 65 + dd];
        float x2 = xs[(lo + 2) * 65 + dd];
        float x3 = xs[(lo + 3) * 65 + dd];
        float x4 = xs[(lo + 4) * 65 + dd];
        float x5 = xs[(lo + 5) * 65 + dd];
        float x6 = xs[(lo + 6) * 65 + dd];
        float xf = bfv + w0 * x0 + w1 * x1 + w2 * x2 + w3 * x3;
        xcf[((size_t)bbase + l) * DI + d] = silu_f(xf);
        float xb = bbv + v3 * x3 + v2 * x4 + v1 * x5 + v0 * x6;
        xcb[((size_t)bbase + (L_SEQ - 1 - l)) * DI + d] = silu_f(xb);
    }
}

// ---------------------------------------------------------------------------
// Chunked scan phase 1.
// ---------------------------------------------------------------------------
__global__ __launch_bounds__(256)
void scan_part1(const float* __restrict__ xcf, const float* __restrict__ xcb,
                const float* __restrict__ xdf, const float* __restrict__ xdb,
                const float* __restrict__ dltf, const float* __restrict__ dltb,
                const float* __restrict__ Alog_f, const float* __restrict__ Alog_b,
                float* __restrict__ SS, float* __restrict__ HL)
{
    const int d  = blockIdx.x * 256 + threadIdx.x;
    const int c  = blockIdx.y;
    const int bb = blockIdx.z;
    const int b  = bb & 1;
    const int br = bb >> 1;

    const float* u    = br ? xcb : xcf;
    const float* dl   = br ? dltb : dltf;
    const float* xd   = br ? xdb : xdf;
    const float* Alog = br ? Alog_b : Alog_f;

    float Arow[NST], h[NST];
#pragma unroll
    for (int n = 0; n < NST; ++n) {
        Arow[n] = -__expf(Alog[d * NST + n]);
        h[n] = 0.f;
    }
    float S = 0.f;

    const size_t nbase = (size_t)b * L_SEQ + (size_t)c * CHT;
    const float* up  = u  + nbase * DI + d;
    const float* dp  = dl + nbase * DI + d;
    const float* bcB = xd + (size_t)DTR * NTOT + nbase;

    for (int tr = 0; tr < CHT; tr += 4) {
        float dv[4], uv[4];
#pragma unroll
        for (int k = 0; k < 4; ++k) {
            dv[k] = dp[(size_t)(tr + k) * DI];
            uv[k] = up[(size_t)(tr + k) * DI];
        }
        S += (dv[0] + dv[1]) + (dv[2] + dv[3]);
        float du[4] = { dv[0]*uv[0], dv[1]*uv[1], dv[2]*uv[2], dv[3]*uv[3] };
#pragma unroll
        for (int n = 0; n < NST; ++n) {
            float4 Bn = *(const float4*)(bcB + (size_t)n * NTOT + tr);
            float hn = h[n];
            float An = Arow[n];
            hn = hn * __expf(dv[0] * An) + du[0] * Bn.x;
            hn = hn * __expf(dv[1] * An) + du[1] * Bn.y;
            hn = hn * __expf(dv[2] * An) + du[2] * Bn.z;
            hn = hn * __expf(dv[3] * An) + du[3] * Bn.w;
            h[n] = hn;
        }
    }
    SS[((size_t)bb * NCH + c) * DI + d] = S;
#pragma unroll
    for (int n = 0; n < NST; ++n)
        HL[(((size_t)bb * NCH + c) * NST + n) * DI + d] = h[n];
}

__global__ __launch_bounds__(256)
void scan_part2(const float* __restrict__ SS, float* HL,
                const float* __restrict__ Alog_f, const float* __restrict__ Alog_b)
{
    const int d  = blockIdx.x * 256 + threadIdx.x;
    const int n  = blockIdx.y;
    const int bb = blockIdx.z;
    const int br = bb >> 1;
    const float* Alog = br ? Alog_b : Alog_f;
    const float A = -__expf(Alog[d * NST + n]);

    float H = 0.f;
#pragma unroll
    for (int c = 0; c < NCH; ++c) {
        const size_t si = ((size_t)bb * NCH + c) * DI + d;
        const size_t hi = (((size_t)bb * NCH + c) * NST + n) * DI + d;
        float hl = HL[hi];
        HL[hi] = H;
        H = __expf(SS[si] * A) * H + hl;
    }
}

__global__ __launch_bounds__(256)
void scan_part3(const float* __restrict__ zt,
                const float* __restrict__ xcf, const float* __restrict__ xcb,
                const float* __restrict__ xdf, const float* __restrict__ xdb,
                const float* __restrict__ dltf, const float* __restrict__ dltb,
                const float* __restrict__ HIN,
                __bf16* __restrict__ ygtf, __bf16* __restrict__ ygtb,
                const float* __restrict__ Alog_f, const float* __restrict__ Alog_b,
                const float* __restrict__ Df, const float* __restrict__ Db)
{
    const int d  = blockIdx.x * 256 + threadIdx.x;
    const int c  = blockIdx.y;
    const int bb = blockIdx.z;
    const int b  = bb & 1;
    const int br = bb >> 1;

    const float* u    = br ? xcb : xcf;
    const float* dl   = br ? dltb : dltf;
    const float* xd   = br ? xdb : xdf;
    const float* Alog = br ? Alog_b : Alog_f;
    const float* Dv   = br ? Db : Df;
    __bf16*      ygt  = br ? ygtb : ygtf;

    float Arow[NST], h[NST];
#pragma unroll
    for (int n = 0; n < NST; ++n) {
        Arow[n] = -__expf(Alog[d * NST + n]);
        h[n] = HIN[(((size_t)bb * NCH + c) * NST + n) * DI + d];
    }
    const float Dp = Dv[d];

    const size_t nbase = (size_t)b * L_SEQ + (size_t)c * CHT;
    const float* up  = u  + nbase * DI + d;
    const float* dp  = dl + nbase * DI + d;
    const float* bcB = xd + (size_t)DTR * NTOT + nbase;
    const size_t bL = (size_t)b * L_SEQ;
    const int    t0 = c * CHT;

    for (int tr = 0; tr < CHT; tr += 4) {
        float dv[4], uv[4];
#pragma unroll
        for (int k = 0; k < 4; ++k) {
            dv[k] = dp[(size_t)(tr + k) * DI];
            uv[k] = up[(size_t)(tr + k) * DI];
        }
        float du[4] = { dv[0]*uv[0], dv[1]*uv[1], dv[2]*uv[2], dv[3]*uv[3] };
        float y[4] = { 0.f, 0.f, 0.f, 0.f };
#pragma unroll
        for (int n = 0; n < NST; ++n) {
            float4 Bn = *(const float4*)(bcB + (size_t)n * NTOT + tr);
            float4 Cn = *(const float4*)(bcB + (size_t)(NST + n) * NTOT + tr);
            float hn = h[n];
            float An = Arow[n];
            hn = hn * __expf(dv[0] * An) + du[0] * Bn.x;  y[0] = fmaf(hn, Cn.x, y[0]);
            hn = hn * __expf(dv[1] * An) + du[1] * Bn.y;  y[1] = fmaf(hn, Cn.y, y[1]);
            hn = hn * __expf(dv[2] * An) + du[2] * Bn.z;  y[2] = fmaf(hn, Cn.z, y[2]);
            hn = hn * __expf(dv[3] * An) + du[3] * Bn.w;  y[3] = fmaf(hn, Cn.w, y[3]);
            h[n] = hn;
        }
#pragma unroll
        for (int k = 0; k < 4; ++k) {
            int t = t0 + tr + k;
            size_t nn = br ? (bL + (L_SEQ - 1 - t)) : (bL + t);
            float zv = zt[nn * DI + d];
            float yo = (y[k] + uv[k] * Dp) * silu_f(zv);
            ygt[nn * DI + d] = (__bf16)yo;
        }
    }
}

extern "C" void kernel_launch(void* const* d_in, const int* in_sizes, int n_in,
                              void* d_out, int out_size, void* d_ws, size_t ws_size,
                              hipStream_t stream)
{
    const float* hid     = (const float*)d_in[0];
    const float* inw     = (const float*)d_in[1];
    const float* convw   = (const float*)d_in[2];
    const float* convb   = (const float*)d_in[3];
    const float* xpw     = (const float*)d_in[4];
    const float* dtw     = (const float*)d_in[5];
    const float* dtb     = (const float*)d_in[6];
    const float* Alog    = (const float*)d_in[7];
    const float* Dv      = (const float*)d_in[8];
    const float* convw_b = (const float*)d_in[9];
    const float* convb_b = (const float*)d_in[10];
    const float* xpw_b   = (const float*)d_in[11];
    const float* dtw_b   = (const float*)d_in[12];
    const float* dtb_b   = (const float*)d_in[13];
    const float* Alog_b  = (const float*)d_in[14];
    const float* Dv_b    = (const float*)d_in[15];
    const float* outw    = (const float*)d_in[16];
    float* out = (float*)d_out;
    float* ws  = (float*)d_ws;

    if (ws_size < WS_FLOATS * sizeof(float)) return;

    float*  X    = ws + OFF_X;
    float*  ZT   = ws + OFF_ZT;
    float*  XCF  = ws + OFF_XCF;
    float*  XCB  = ws + OFF_XCB;
    float*  DLTB = ws + OFF_DLTB;
    float*  XDF  = ws + OFF_XDF;
    float*  XDB  = ws + OFF_XDB;
    float*  SS   = ws + OFF_SS;
    float*  HLb  = ws + OFF_HL;
    __bf16* YGTF = (__bf16*)(ws + OFF_YGTF);
    __bf16* YGTB = (__bf16*)(ws + OFF_YGTB);
    float*  PF   = ws + OFF_YGTF;   // K3 split-K partials (dead until part3)
    float*  PB   = ws + OFF_YGTB;
    float*  DLTF = X;               // overwrites dead x after conv
    __bf16* IW16 = (__bf16*)(ws + OFF_SS);            // dead until scan_part1
    __bf16* HD16 = IW16 + (size_t)ETOT * DM;
    __bf16* OW16 = (__bf16*)(ws + OFF_XCB);           // dead after scan_part3
    __bf16* YGS  = (__bf16*)(ws + OFF_XCF);           // dead after scan_part3
    __bf16* XDT16F = (__bf16*)(ws + OFF_XDT16F);
    __bf16* XDT16B = (__bf16*)(ws + OFF_XDT16B);
    __bf16* DTW16F = (__bf16*)(ws + OFF_DTW16F);
    __bf16* DTW16B = (__bf16*)(ws + OFF_DTW16B);

    dim3 blk(256);
    // K0: one-time bf16 conversions
    cvt_bf16_k<<<dim3(ETOT * DM / 2048), blk, 0, stream>>>(inw, IW16);
    cvt_bf16_k<<<dim3(NTOT * DM / 2048), blk, 0, stream>>>(hid, HD16);
    cvt_bf16_k<<<dim3(DI * DTR / 2048), blk, 0, stream>>>(dtw, DTW16F);
    cvt_bf16_k<<<dim3(DI * DTR / 2048), blk, 0, stream>>>(dtw_b, DTW16B);
    // K1: x[d][n] + zt[n][d] = in_proj_w @ hidden^T  (async bf16 MFMA)
    gemm_bf16<128, false, true><<<dim3(32, 32), blk, 0, stream>>>(
        IW16, HD16, X, ZT, ETOT, NTOT, DM);
    // K2: conv + silu both directions -> [n][d]
    conv_k<<<dim3(32, 64), blk, 0, stream>>>(X, convw, convb, convw_b, convb_b, XCF, XCB);
    // K3: split-K partials (plain stores), then reduce (+ bf16 dt_r transpose)
    gemm_k3<<<dim3(32, 1, SPLK), blk, 0, stream>>>(xpw, XCF, PF, RTOT, NTOT, DI);
    gemm_k3<<<dim3(32, 1, SPLK), blk, 0, stream>>>(xpw_b, XCB, PB, RTOT, NTOT, DI);
    reduce8t_k<<<dim3(RTOT * NTOT / 1024), blk, 0, stream>>>(PF, XDF, XDT16F, (size_t)RTOT * NTOT);
    reduce8t_k<<<dim3(RTOT * NTOT / 1024), blk, 0, stream>>>(PB, XDB, XDT16B, (size_t)RTOT * NTOT);
    // K4: dlt[n][d] = softplus(dt_r^T @ dtw^T + bias)  (async bf16 MFMA)
    dtproj_mfma<<<dim3(DI / 128, NTOT / 128, 2), blk, 0, stream>>>(
        XDT16F, XDT16B, DTW16F, DTW16B, dtb, dtb_b, DLTF, DLTB);
    // K5: chunked parallel scan
    scan_part1<<<dim3(DI / 256, NCH, 4), blk, 0, stream>>>(
        XCF, XCB, XDF, XDB, DLTF, DLTB, Alog, Alog_b, SS, HLb);
    scan_part2<<<dim3(DI / 256, NST, 4), blk, 0, stream>>>(
        SS, HLb, Alog, Alog_b);
    scan_part3<<<dim3(DI / 256, NCH, 4), blk, 0, stream>>>(
        ZT, XCF, XCB, XDF, XDB, DLTF, DLTB, HLb, YGTF, YGTB, Alog, Alog_b, Dv, Dv_b);
    // K5b: outw -> bf16; ygsum = ygt_f + ygt_b
    cvt_bf16_k<<<dim3(DM * DI / 2048), blk, 0, stream>>>(outw, OW16);
    addbf16_k<<<dim3(NTOT * DI / 2048), blk, 0, stream>>>(YGTF, YGTB, YGS);
    // K6: out[n][m] = out_proj_w @ ygsum  (async bf16 MFMA, MT=64)
    gemm_bf16<64, true, false><<<dim3(32, 16), blk, 0, stream>>>(
        OW16, YGS, out, nullptr, DM, NTOT, DI);

    (void)in_sizes; (void)n_in; (void)out_size;
}